// Round 4
// baseline (320.237 us; speedup 1.0000x reference)
//
#include <hip/hip_runtime.h>
#include <hip/hip_bf16.h>
#include <stdint.h>
#include <math.h>

namespace {

constexpr int kB = 2;
constexpr int kN = 2048;
constexpr int kC = 1024;
constexpr int kH = 16;
constexpr int kD = 64;
constexpr int kTok = kB * kN;               // 4096
constexpr int k3C  = 3 * kC;                // 3072
constexpr size_t kPS = (size_t)kTok * k3C;  // qkv plane elems
constexpr size_t kXE = (size_t)kTok * kC;   // x / VT plane elems
constexpr size_t kWQ = (size_t)k3C * kC;    // qkv_w elems
constexpr size_t kWP = (size_t)kC * kC;     // proj_w elems

using bhalf8 = __attribute__((ext_vector_type(8))) __bf16;
using f32x4  = __attribute__((ext_vector_type(4))) float;

__device__ inline unsigned short f2bf(float f) {
  __hip_bfloat16 h = __float2bfloat16(f);
  return *reinterpret_cast<unsigned short*>(&h);
}
__device__ inline float bf2f(unsigned short u) {
  __hip_bfloat16 h;
  *reinterpret_cast<unsigned short*>(&h) = u;
  return __bfloat162float(h);
}
__device__ inline void split2(float v, unsigned short& h, unsigned short& l) {
  const unsigned short hb = f2bf(v);
  h = hb;
  l = f2bf(v - bf2f(hb));
}

// async global->LDS, 16B per lane; LDS dest must be wave-uniform base + lane*16
__device__ inline void glds16(const unsigned short* g, unsigned short* l) {
  __builtin_amdgcn_global_load_lds(
      (const __attribute__((address_space(1))) void*)g,
      (__attribute__((address_space(3))) void*)l, 16, 0, 0);
}

// ---- split fp32 -> bf16 hi/lo planes ----
__global__ __launch_bounds__(256)
void split_planes(const float* __restrict__ src,
                  unsigned short* __restrict__ H,
                  unsigned short* __restrict__ L, int n4)
{
  const int i = blockIdx.x * 256 + threadIdx.x;
  if (i >= n4) return;
  const float4 v = ((const float4*)src)[i];
  ushort4 hh, ll;
  split2(v.x, hh.x, ll.x); split2(v.y, hh.y, ll.y);
  split2(v.z, hh.z, ll.z); split2(v.w, hh.w, ll.w);
  ((ushort4*)H)[i] = hh;
  ((ushort4*)L)[i] = ll;
}

// ---- pre-transpose V (hi plane only) into VT[bh][d][token] ----
__global__ __launch_bounds__(256)
void vt_transpose(const unsigned short* __restrict__ H,
                  unsigned short* __restrict__ VTH)
{
  const int gw   = blockIdx.x * 4 + (threadIdx.x >> 6);  // 0..8191
  const int lane = threadIdx.x & 63;                     // = d
  const int bh   = gw >> 8;
  const int oct  = gw & 255;
  const int b = bh >> 4, h = bh & 15;
  const int tok0 = oct * 8;
  union { unsigned short u[8]; uint4 v; } ph;
  #pragma unroll
  for (int e = 0; e < 8; ++e) {
    const size_t g = (size_t)(b * kN + tok0 + e) * k3C + 2 * kC + h * kD + lane;
    ph.u[e] = H[g];
  }
  *(uint4*)(&VTH[((size_t)bh * kD + lane) * kN + tok0]) = ph.v;
}

// ============================================================================
// QKV GEMM, 256x256 tile, 8 waves (2x4), BK=32, double-buffered LDS.
// Term-split 3-phase schedule (verified round 2): each phase consumes ONE
// staged plane unit; every vmcnt targets loads issued >=2 phases earlier.
// ============================================================================
__global__ __launch_bounds__(512)
void gemm_qkv256(const unsigned short* __restrict__ AH,
                 const unsigned short* __restrict__ AL,
                 const unsigned short* __restrict__ WH,
                 const unsigned short* __restrict__ WL,
                 const float* __restrict__ bias,
                 unsigned short* __restrict__ OutH,
                 unsigned short* __restrict__ OutL,
                 const float* __restrict__ qn,
                 const float* __restrict__ kn)
{
  constexpr int BK = 32;
  constexpr int NT = kC / BK;   // 32 K-tiles

  // [buf][plane(hi/lo)][256 rows x 32 cols u16] = 128 KiB total
  __shared__ __align__(16) unsigned short sA[2][2][256 * 32];
  __shared__ __align__(16) unsigned short sB[2][2][256 * 32];

  const int tt   = threadIdx.x;        // 0..511
  const int wave = tt >> 6;            // 0..7
  const int lane = tt & 63;
  const int quad = lane >> 4;
  const int l16  = lane & 15;
  const int bm = blockIdx.x * 256;
  const int bn = blockIdx.y * 256;
  const int wm = (wave >> 2) * 128;    // wave row: 0/128
  const int wn = (wave & 3) * 64;      // wave col: 0/64/128/192

  // staging geometry: unit u = r*512 + tt; row = u>>2; swizzled col-group
  int srow[2], scol[2];
  #pragma unroll
  for (int r = 0; r < 2; ++r) {
    const int u = r * 512 + tt;
    srow[r] = u >> 2;
    scol[r] = ((u & 3) ^ ((srow[r] >> 1) & 3)) * 8;
  }

  // unit: 0=AH 1=WH 2=WL 3=AL (issue order!)
  auto stageU = [&](int bf, int k0, int which) {
    const unsigned short* src = (which == 0) ? AH : (which == 1) ? WH
                              : (which == 2) ? WL : AL;
    const int base = (which == 0 || which == 3) ? bm : bn;
    unsigned short* dst = (which == 0) ? &sA[bf][0][0]
                        : (which == 3) ? &sA[bf][1][0]
                        : (which == 1) ? &sB[bf][0][0] : &sB[bf][1][0];
    #pragma unroll
    for (int r = 0; r < 2; ++r)
      glds16(&src[(size_t)(base + srow[r]) * kC + k0 + scol[r]],
             &dst[(r * 512 + tt) * 8]);
  };

  auto rdA = [&](int bf, int pl, int row) -> bhalf8 {
    return *(const bhalf8*)(&sA[bf][pl][row * 32 + ((quad ^ ((row >> 1) & 3)) * 8)]);
  };
  auto rdB = [&](int bf, int pl, int row) -> bhalf8 {
    return *(const bhalf8*)(&sB[bf][pl][row * 32 + ((quad ^ ((row >> 1) & 3)) * 8)]);
  };

  f32x4 acc[8][4] = {};
  bhalf8 ah[8], bh_[4], bl_[4];

  // ---- prologue: stage all 4 units of tile 0; wait AH0,WH0 ----
  stageU(0, 0, 0); stageU(0, 0, 1); stageU(0, 0, 2); stageU(0, 0, 3);
  asm volatile("s_waitcnt vmcnt(4)" ::: "memory");
  __builtin_amdgcn_sched_barrier(0);
  asm volatile("s_barrier" ::: "memory");

  for (int t = 0; t < NT - 1; ++t) {
    const int buf  = t & 1;
    const int nbuf = buf ^ 1;
    const int nk0  = (t + 1) * BK;

    // ---- P01: hh term ----
    #pragma unroll
    for (int i = 0; i < 8; ++i) ah[i]  = rdA(buf, 0, wm + i * 16 + l16);
    #pragma unroll
    for (int j = 0; j < 4; ++j) bh_[j] = rdB(buf, 0, wn + j * 16 + l16);
    stageU(nbuf, nk0, 0);                 // AH(t+1)
    stageU(nbuf, nk0, 1);                 // WH(t+1)
    asm volatile("s_waitcnt vmcnt(6)" ::: "memory");   // drain WL(t)
    __builtin_amdgcn_sched_barrier(0);
    asm volatile("s_barrier" ::: "memory");
    __builtin_amdgcn_s_setprio(1);
    #pragma unroll
    for (int i = 0; i < 8; ++i)
      #pragma unroll
      for (int j = 0; j < 4; ++j)
        acc[i][j] = __builtin_amdgcn_mfma_f32_16x16x32_bf16(ah[i], bh_[j], acc[i][j], 0, 0, 0);
    __builtin_amdgcn_s_setprio(0);

    // ---- P2: hl term ----
    #pragma unroll
    for (int j = 0; j < 4; ++j) bl_[j] = rdB(buf, 1, wn + j * 16 + l16);
    stageU(nbuf, nk0, 2);                 // WL(t+1)
    asm volatile("s_waitcnt vmcnt(6)" ::: "memory");   // drain AL(t)
    __builtin_amdgcn_sched_barrier(0);
    asm volatile("s_barrier" ::: "memory");
    __builtin_amdgcn_s_setprio(1);
    #pragma unroll
    for (int i = 0; i < 8; ++i)
      #pragma unroll
      for (int j = 0; j < 4; ++j)
        acc[i][j] = __builtin_amdgcn_mfma_f32_16x16x32_bf16(ah[i], bl_[j], acc[i][j], 0, 0, 0);
    __builtin_amdgcn_s_setprio(0);

    // ---- P3: lh term ----
    stageU(nbuf, nk0, 3);                 // AL(t+1)
    asm volatile("s_waitcnt vmcnt(4)" ::: "memory");   // drain AH,WH(t+1)
    __builtin_amdgcn_sched_barrier(0);
    asm volatile("s_barrier" ::: "memory");
    __builtin_amdgcn_s_setprio(1);
    {
      bhalf8 al0[4];
      #pragma unroll
      for (int i = 0; i < 4; ++i) al0[i] = rdA(buf, 1, wm + i * 16 + l16);
      #pragma unroll
      for (int i = 0; i < 4; ++i)
        #pragma unroll
        for (int j = 0; j < 4; ++j)
          acc[i][j] = __builtin_amdgcn_mfma_f32_16x16x32_bf16(al0[i], bh_[j], acc[i][j], 0, 0, 0);
      bhalf8 al1[4];
      #pragma unroll
      for (int i = 0; i < 4; ++i) al1[i] = rdA(buf, 1, wm + (4 + i) * 16 + l16);
      #pragma unroll
      for (int i = 0; i < 4; ++i)
        #pragma unroll
        for (int j = 0; j < 4; ++j)
          acc[4 + i][j] = __builtin_amdgcn_mfma_f32_16x16x32_bf16(al1[i], bh_[j], acc[4 + i][j], 0, 0, 0);
    }
    __builtin_amdgcn_s_setprio(0);
    asm volatile("s_barrier" ::: "memory");   // end-of-tile lockstep
  }

  // ---- peeled last tile (no prefetch) ----
  {
    const int buf = (NT - 1) & 1;
    #pragma unroll
    for (int i = 0; i < 8; ++i) ah[i]  = rdA(buf, 0, wm + i * 16 + l16);
    #pragma unroll
    for (int j = 0; j < 4; ++j) bh_[j] = rdB(buf, 0, wn + j * 16 + l16);
    __builtin_amdgcn_s_setprio(1);
    #pragma unroll
    for (int i = 0; i < 8; ++i)
      #pragma unroll
      for (int j = 0; j < 4; ++j)
        acc[i][j] = __builtin_amdgcn_mfma_f32_16x16x32_bf16(ah[i], bh_[j], acc[i][j], 0, 0, 0);
    __builtin_amdgcn_s_setprio(0);

    asm volatile("s_waitcnt vmcnt(2)" ::: "memory");   // drain WL(last)
    __builtin_amdgcn_sched_barrier(0);
    asm volatile("s_barrier" ::: "memory");
    #pragma unroll
    for (int j = 0; j < 4; ++j) bl_[j] = rdB(buf, 1, wn + j * 16 + l16);
    __builtin_amdgcn_s_setprio(1);
    #pragma unroll
    for (int i = 0; i < 8; ++i)
      #pragma unroll
      for (int j = 0; j < 4; ++j)
        acc[i][j] = __builtin_amdgcn_mfma_f32_16x16x32_bf16(ah[i], bl_[j], acc[i][j], 0, 0, 0);
    __builtin_amdgcn_s_setprio(0);

    asm volatile("s_waitcnt vmcnt(0)" ::: "memory");   // drain AL(last)
    __builtin_amdgcn_sched_barrier(0);
    asm volatile("s_barrier" ::: "memory");
    __builtin_amdgcn_s_setprio(1);
    {
      bhalf8 al0[4];
      #pragma unroll
      for (int i = 0; i < 4; ++i) al0[i] = rdA(buf, 1, wm + i * 16 + l16);
      #pragma unroll
      for (int i = 0; i < 4; ++i)
        #pragma unroll
        for (int j = 0; j < 4; ++j)
          acc[i][j] = __builtin_amdgcn_mfma_f32_16x16x32_bf16(al0[i], bh_[j], acc[i][j], 0, 0, 0);
      bhalf8 al1[4];
      #pragma unroll
      for (int i = 0; i < 4; ++i) al1[i] = rdA(buf, 1, wm + (4 + i) * 16 + l16);
      #pragma unroll
      for (int i = 0; i < 4; ++i)
        #pragma unroll
        for (int j = 0; j < 4; ++j)
          acc[4 + i][j] = __builtin_amdgcn_mfma_f32_16x16x32_bf16(al1[i], bh_[j], acc[4 + i][j], 0, 0, 0);
    }
    __builtin_amdgcn_s_setprio(0);
  }

  // epilogue: C/D layout col=lane&15, row=quad*4+reg; fused RMSNorm on q,k
  const int slice = bn >> 10;          // 0=q,1=k,2=v (bn multiple of 256)
  const bool writeL = (slice == 0);
  float bv[4], wv[4];
  #pragma unroll
  for (int j = 0; j < 4; ++j) {
    bv[j] = bias[bn + wn + j * 16 + l16];
    if (slice < 2) wv[j] = (slice ? kn : qn)[j * 16 + l16];  // d = j*16+l16
  }

  #pragma unroll
  for (int i = 0; i < 8; ++i) {
    float val[4][4];
    #pragma unroll
    for (int j = 0; j < 4; ++j)
      #pragma unroll
      for (int r = 0; r < 4; ++r)
        val[j][r] = acc[i][j][r] + bv[j];

    if (slice < 2) {
      #pragma unroll
      for (int r = 0; r < 4; ++r) {
        float ss = val[0][r] * val[0][r];
        #pragma unroll
        for (int j = 1; j < 4; ++j) ss += val[j][r] * val[j][r];
        #pragma unroll
        for (int d = 1; d < 16; d <<= 1) ss += __shfl_xor(ss, d, 64);
        float rinv = rsqrtf(ss * (1.0f / 64.0f) + 1e-6f);
        // q * D^-0.5 * log2(e): attn uses exp2f (v_exp_f32 = 2^x)
        if (slice == 0) rinv *= 0.18033688011112042f;
        #pragma unroll
        for (int j = 0; j < 4; ++j) val[j][r] = wv[j] * (val[j][r] * rinv);
      }
    }

    #pragma unroll
    for (int j = 0; j < 4; ++j) {
      const int n = bn + wn + j * 16 + l16;
      #pragma unroll
      for (int r = 0; r < 4; ++r) {
        const int m = bm + wm + i * 16 + quad * 4 + r;
        unsigned short hh, ll;
        split2(val[j][r], hh, ll);
        OutH[(size_t)m * k3C + n] = hh;
        if (writeL) OutL[(size_t)m * k3C + n] = ll;
      }
    }
  }
}

// ---- plane GEMM (128^2, m97-structure): kept for the proj projection ----
template<bool OUTF32, bool FUSE_NORM>
__global__ __launch_bounds__(256)
void gemm_planes(const unsigned short* __restrict__ AH,
                 const unsigned short* __restrict__ AL, int lda,
                 const unsigned short* __restrict__ WH,
                 const unsigned short* __restrict__ WL,
                 const float* __restrict__ bias,
                 float* __restrict__ OutF,
                 unsigned short* __restrict__ OutH,
                 unsigned short* __restrict__ OutL,
                 const float* __restrict__ qn,
                 const float* __restrict__ kn,
                 int Nn, int K)
{
  __shared__ __align__(16) unsigned short AsH[128 * 32], AsL[128 * 32];
  __shared__ __align__(16) unsigned short BsH[128 * 32], BsL[128 * 32];

  const int t    = threadIdx.x;
  const int wave = t >> 6;
  const int lane = t & 63;
  const int quad = lane >> 4;
  const int l16  = lane & 15;
  const int bm = blockIdx.x * 128;
  const int bn = blockIdx.y * 128;
  const int wm = (wave >> 1) * 64;
  const int wn = (wave & 1) * 64;

  f32x4 acc[4][4] = {};

  for (int k0 = 0; k0 < K; k0 += 32) {
    #pragma unroll
    for (int r = 0; r < 2; ++r) {
      const int c   = r * 256 + t;
      const int row = c >> 2;
      const int col = (c & 3) * 8;
      glds16(&AH[(size_t)(bm + row) * lda + k0 + col], &AsH[c * 8]);
      glds16(&AL[(size_t)(bm + row) * lda + k0 + col], &AsL[c * 8]);
      glds16(&WH[(size_t)(bn + row) * K + k0 + col], &BsH[c * 8]);
      glds16(&WL[(size_t)(bn + row) * K + k0 + col], &BsL[c * 8]);
    }
    __syncthreads();

    bhalf8 afh[4], afl[4], bgh[4], bgl[4];
    #pragma unroll
    for (int i = 0; i < 4; ++i) {
      afh[i] = *(const bhalf8*)(&AsH[(wm + i * 16 + l16) * 32 + quad * 8]);
      afl[i] = *(const bhalf8*)(&AsL[(wm + i * 16 + l16) * 32 + quad * 8]);
      bgh[i] = *(const bhalf8*)(&BsH[(wn + i * 16 + l16) * 32 + quad * 8]);
      bgl[i] = *(const bhalf8*)(&BsL[(wn + i * 16 + l16) * 32 + quad * 8]);
    }
    #pragma unroll
    for (int i = 0; i < 4; ++i)
      #pragma unroll
      for (int j = 0; j < 4; ++j) {
        f32x4 a = acc[i][j];
        a = __builtin_amdgcn_mfma_f32_16x16x32_bf16(afh[i], bgh[j], a, 0, 0, 0);
        a = __builtin_amdgcn_mfma_f32_16x16x32_bf16(afh[i], bgl[j], a, 0, 0, 0);
        a = __builtin_amdgcn_mfma_f32_16x16x32_bf16(afl[i], bgh[j], a, 0, 0, 0);
        acc[i][j] = a;
      }
    __syncthreads();
  }

  // epilogue: C/D layout col=lane&15, row=quad*4+reg
  float bv[4], wv[4];
  const int slice = FUSE_NORM ? (bn >> 10) : 0;   // 0=q,1=k,2=v
  const bool writeL = !FUSE_NORM || slice == 0;
  #pragma unroll
  for (int j = 0; j < 4; ++j) {
    bv[j] = bias[bn + wn + j * 16 + l16];
    if (FUSE_NORM && slice < 2)
      wv[j] = (slice ? kn : qn)[j * 16 + l16];    // d = j*16+l16
  }

  #pragma unroll
  for (int i = 0; i < 4; ++i) {
    float val[4][4];
    #pragma unroll
    for (int j = 0; j < 4; ++j)
      #pragma unroll
      for (int r = 0; r < 4; ++r)
        val[j][r] = acc[i][j][r] + bv[j];

    if (FUSE_NORM && slice < 2) {
      #pragma unroll
      for (int r = 0; r < 4; ++r) {
        float ss = val[0][r] * val[0][r];
        #pragma unroll
        for (int j = 1; j < 4; ++j) ss += val[j][r] * val[j][r];
        #pragma unroll
        for (int d = 1; d < 16; d <<= 1) ss += __shfl_xor(ss, d, 64);
        float rinv = rsqrtf(ss * (1.0f / 64.0f) + 1e-6f);
        if (slice == 0) rinv *= 0.125f;           // q * D^-0.5
        #pragma unroll
        for (int j = 0; j < 4; ++j) val[j][r] = wv[j] * (val[j][r] * rinv);
      }
    }

    #pragma unroll
    for (int j = 0; j < 4; ++j) {
      const int n = bn + wn + j * 16 + l16;
      #pragma unroll
      for (int r = 0; r < 4; ++r) {
        const int m = bm + wm + i * 16 + quad * 4 + r;
        if (OUTF32) {
          OutF[(size_t)m * Nn + n] = val[j][r];
        } else {
          unsigned short hh, ll;
          split2(val[j][r], hh, ll);
          OutH[(size_t)m * Nn + n] = hh;
          if (writeL) OutL[(size_t)m * Nn + n] = ll;
        }
      }
    }
  }
}

// ---- flash attention v7: 16 q-rows/wave, grid 1024 (4 blocks/CU, 16 waves/CU),
// XOR-swizzled Kt/Vt stores+reads (T2; reg-staged so rule #21 doesn't bind),
// exp2f (log2e folded into q-scale upstream). ----
__global__ __launch_bounds__(256)
void attn_kernel(unsigned short* __restrict__ H, unsigned short* __restrict__ L,
                 const unsigned short* __restrict__ VTH,
                 const int* __restrict__ mask)
{
  constexpr int P = 72;
  __shared__ __align__(16) unsigned short KtH[64 * P];   //  9.2 KB [key][d]
  __shared__ __align__(16) unsigned short VtH[64 * P];   //  9.2 KB [d][key]
  __shared__ __align__(16) unsigned short Pt[4][16 * P]; //  9.2 KB per-wave [q][key]

  const int t    = threadIdx.x;
  const int wave = t >> 6;
  const int lane = t & 63;
  const int quad = lane >> 4;
  const int l16  = lane & 15;

  // XCD swizzle: lin%8 = XCD (dispatch round-robin); 4 bh per XCD, 32 qblk each.
  const int lin  = blockIdx.x;          // 0..1023
  const int xcd  = lin & 7;
  const int slot = lin >> 3;            // 0..127
  const int bh   = xcd + 8 * (slot >> 5);
  const int qblk = slot & 31;
  const int b  = bh >> 4;
  const int h  = bh & 15;
  const int q0 = qblk * 64 + wave * 16;   // 16 q-rows/wave

  // staging geometry: 2 chunks of 8 u16 per thread per tile; rows 0..31 / 32..63
  const int row0 = t >> 3, col0 = (t & 7) * 8;
  const int row1 = row0 + 32;
  const int sw0  = (row0 & 7) << 3;      // == (row1 & 7) << 3
  const int sc0  = col0 ^ sw0;           // swizzled LDS column

  // Q fragments (A-layout: m=l16, k=quad*8+j); 16 rows only
  bhalf8 qfh[2], qfl[2];
  {
    const size_t qrow = (size_t)(b * kN + q0 + l16) * k3C + h * kD;
    qfh[0] = *(const bhalf8*)(&H[qrow + quad * 8]);
    qfh[1] = *(const bhalf8*)(&H[qrow + 32 + quad * 8]);
    qfl[0] = *(const bhalf8*)(&L[qrow + quad * 8]);
    qfl[1] = *(const bhalf8*)(&L[qrow + 32 + quad * 8]);
  }

  f32x4 acc_o[4] = {};
  float lpart[4] = {};

  uint4 sk0, sk1, sv0, sv1;            // staging regs
  int mcur[4], mnext[4];

  auto pref = [&](int kt) {
    sk0 = *(const uint4*)(&H[(size_t)(b * kN + kt + row0) * k3C + kC + h * kD + col0]);
    sk1 = *(const uint4*)(&H[(size_t)(b * kN + kt + row1) * k3C + kC + h * kD + col0]);
    sv0 = *(const uint4*)(&VTH[((size_t)bh * kD + row0) * kN + kt + col0]);
    sv1 = *(const uint4*)(&VTH[((size_t)bh * kD + row1) * kN + kt + col0]);
  };
  auto loadM = [&](int kt, int* m) {
    #pragma unroll
    for (int nt = 0; nt < 4; ++nt) m[nt] = mask[b * kN + kt + nt * 16 + l16];
  };

  pref(0);
  loadM(0, mcur);
  #pragma unroll
  for (int nt = 0; nt < 4; ++nt) mnext[nt] = mcur[nt];

  for (int i = 0; i < 32; ++i) {
    const int kt = i * 64;
    // drain staged regs into LDS (store col XOR-swizzled by row&7)
    *(uint4*)(&KtH[row0 * P + sc0]) = sk0;
    *(uint4*)(&KtH[row1 * P + sc0]) = sk1;
    *(uint4*)(&VtH[row0 * P + sc0]) = sv0;
    *(uint4*)(&VtH[row1 * P + sc0]) = sv1;
    __syncthreads();

    // issue next tile's global loads early; consumed next iter
    if (i < 31) { pref(kt + 64); loadM(kt + 64, mnext); }

    // S = (Qh+Ql)Kh ; p = flag*2^s -> Pt (C-layout -> A-layout)
    const int rsw = (l16 & 7) << 3;    // read-side row swizzle (row&7 == l16&7)
    #pragma unroll
    for (int nt = 0; nt < 4; ++nt) {
      const int kr = (nt * 16 + l16) * P;
      const bhalf8 kh0 = *(const bhalf8*)(&KtH[kr + ((quad * 8) ^ rsw)]);
      const bhalf8 kh1 = *(const bhalf8*)(&KtH[kr + ((32 + quad * 8) ^ rsw)]);
      const float flag = mcur[nt] ? 1.0f : 0.0f;
      f32x4 s = {};
      s = __builtin_amdgcn_mfma_f32_16x16x32_bf16(qfh[0], kh0, s, 0, 0, 0);
      s = __builtin_amdgcn_mfma_f32_16x16x32_bf16(qfh[1], kh1, s, 0, 0, 0);
      s = __builtin_amdgcn_mfma_f32_16x16x32_bf16(qfl[0], kh0, s, 0, 0, 0);
      s = __builtin_amdgcn_mfma_f32_16x16x32_bf16(qfl[1], kh1, s, 0, 0, 0);
      #pragma unroll
      for (int r = 0; r < 4; ++r) {
        const float p = flag * exp2f(s[r]);   // s pre-scaled by log2e
        lpart[r] += p;
        Pt[wave][(quad * 4 + r) * P + nt * 16 + l16] = f2bf(p);
      }
    }

    // O += P * Vh  (Pt per-wave: same-wave DS ordering, no barrier needed)
    #pragma unroll
    for (int kk = 0; kk < 2; ++kk) {
      const bhalf8 pa = *(const bhalf8*)(&Pt[wave][l16 * P + kk * 32 + quad * 8]);
      #pragma unroll
      for (int dt = 0; dt < 4; ++dt) {
        const bhalf8 vb = *(const bhalf8*)(&VtH[(dt * 16 + l16) * P + ((kk * 32 + quad * 8) ^ rsw)]);
        acc_o[dt] = __builtin_amdgcn_mfma_f32_16x16x32_bf16(pa, vb, acc_o[dt], 0, 0, 0);
      }
    }

    #pragma unroll
    for (int nt = 0; nt < 4; ++nt) mcur[nt] = mnext[nt];
    __syncthreads();     // Kt/Vt readers done; next iter may overwrite
  }

  // final l reduction + normalize + store hi/lo into q-slice
  #pragma unroll
  for (int r = 0; r < 4; ++r) {
    float s = lpart[r];
    #pragma unroll
    for (int d = 1; d < 16; d <<= 1) s += __shfl_xor(s, d, 64);
    lpart[r] = s;
  }
  #pragma unroll
  for (int dt = 0; dt < 4; ++dt)
    #pragma unroll
    for (int r = 0; r < 4; ++r) {
      const int qrow = q0 + quad * 4 + r;
      const float inv = 1.0f / fmaxf(lpart[r], 1.0e-30f);
      const size_t off = (size_t)(b * kN + qrow) * k3C + h * kD + dt * 16 + l16;
      unsigned short hh, ll;
      split2(acc_o[dt][r] * inv, hh, ll);
      H[off] = hh; L[off] = ll;
    }
}

} // anonymous namespace

extern "C" void kernel_launch(void* const* d_in, const int* in_sizes, int n_in,
                              void* d_out, int out_size, void* d_ws, size_t ws_size,
                              hipStream_t stream)
{
  const float* x      = (const float*)d_in[0];
  const int*   maskp  = (const int*)d_in[1];
  const float* qkv_w  = (const float*)d_in[2];
  const float* qkv_b  = (const float*)d_in[3];
  const float* proj_w = (const float*)d_in[4];
  const float* proj_b = (const float*)d_in[5];
  const float* qn_w   = (const float*)d_in[6];
  const float* kn_w   = (const float*)d_in[7];
  float* out = (float*)d_out;

  unsigned short* qH = (unsigned short*)d_ws;      // qkv hi plane
  unsigned short* qL = qH + kPS;                   // qkv lo plane
  unsigned short* R1 = qL + kPS;                   // x planes -> later VT plane
  unsigned short* R2 = R1 + 2 * kXE;               // qkv_w planes -> later proj_w planes
  unsigned short* xH = R1,  *xL = R1 + kXE;
  unsigned short* VTH = R1;                        // reuse after gemm1
  unsigned short* wqH = R2, *wqL = R2 + kWQ;
  unsigned short* wpH = R2, *wpL = R2 + kWP;

  split_planes<<<(int)(kXE / 4 / 256), 256, 0, stream>>>(x, xH, xL, (int)(kXE / 4));
  split_planes<<<(int)(kWQ / 4 / 256), 256, 0, stream>>>(qkv_w, wqH, wqL, (int)(kWQ / 4));

  // 1) qkv = x @ qkv_w^T + qkv_b, RMSNorm(q,k) fused; lo written for q only
  //    256^2 pipelined kernel: grid (4096/256, 3072/256) = (16, 12)
  gemm_qkv256<<<dim3(kTok / 256, k3C / 256), 512, 0, stream>>>(
      xH, xL, wqH, wqL, qkv_b, qH, qL, qn_w, kn_w);

  // 2) pre-transpose V hi (overwrites x planes); pre-split proj_w
  vt_transpose<<<2048, 256, 0, stream>>>(qH, VTH);
  split_planes<<<(int)(kWP / 4 / 256), 256, 0, stream>>>(proj_w, wpH, wpL, (int)(kWP / 4));

  // 3) masked flash attention (XCD-swizzled 1-D grid, 1024 blocks)
  attn_kernel<<<dim3(1024), 256, 0, stream>>>(qH, qL, VTH, maskp);

  // 4) out = attn @ proj_w^T + proj_b
  gemm_planes<true, false><<<dim3(kTok / 128, kC / 128), 256, 0, stream>>>(
      qH, qL, k3C, wpH, wpL, proj_b, out, nullptr, nullptr, nullptr, nullptr, kC, kC);
}

// Round 5
// 307.583 us; speedup vs baseline: 1.0411x; 1.0411x over previous
//
#include <hip/hip_runtime.h>
#include <hip/hip_bf16.h>
#include <stdint.h>
#include <math.h>

namespace {

constexpr int kB = 2;
constexpr int kN = 2048;
constexpr int kC = 1024;
constexpr int kH = 16;
constexpr int kD = 64;
constexpr int kTok = kB * kN;               // 4096
constexpr int k3C  = 3 * kC;                // 3072
constexpr size_t kPS = (size_t)kTok * k3C;  // qkv plane elems
constexpr size_t kXE = (size_t)kTok * kC;   // x / VT plane elems
constexpr size_t kWQ = (size_t)k3C * kC;    // qkv_w elems
constexpr size_t kWP = (size_t)kC * kC;     // proj_w elems

using bhalf8 = __attribute__((ext_vector_type(8))) __bf16;
using f32x4  = __attribute__((ext_vector_type(4))) float;

__device__ inline unsigned short f2bf(float f) {
  __hip_bfloat16 h = __float2bfloat16(f);
  return *reinterpret_cast<unsigned short*>(&h);
}
__device__ inline float bf2f(unsigned short u) {
  __hip_bfloat16 h;
  *reinterpret_cast<unsigned short*>(&h) = u;
  return __bfloat162float(h);
}
__device__ inline void split2(float v, unsigned short& h, unsigned short& l) {
  const unsigned short hb = f2bf(v);
  h = hb;
  l = f2bf(v - bf2f(hb));
}

// async global->LDS, 16B per lane; LDS dest must be wave-uniform base + lane*16
__device__ inline void glds16(const unsigned short* g, unsigned short* l) {
  __builtin_amdgcn_global_load_lds(
      (const __attribute__((address_space(1))) void*)g,
      (__attribute__((address_space(3))) void*)l, 16, 0, 0);
}

// ---- split fp32 -> bf16 hi/lo planes ----
__global__ __launch_bounds__(256)
void split_planes(const float* __restrict__ src,
                  unsigned short* __restrict__ H,
                  unsigned short* __restrict__ L, int n4)
{
  const int i = blockIdx.x * 256 + threadIdx.x;
  if (i >= n4) return;
  const float4 v = ((const float4*)src)[i];
  ushort4 hh, ll;
  split2(v.x, hh.x, ll.x); split2(v.y, hh.y, ll.y);
  split2(v.z, hh.z, ll.z); split2(v.w, hh.w, ll.w);
  ((ushort4*)H)[i] = hh;
  ((ushort4*)L)[i] = ll;
}

// ---- pre-transpose V (hi plane only) into VT[bh][d][token] ----
__global__ __launch_bounds__(256)
void vt_transpose(const unsigned short* __restrict__ H,
                  unsigned short* __restrict__ VTH)
{
  const int gw   = blockIdx.x * 4 + (threadIdx.x >> 6);  // 0..8191
  const int lane = threadIdx.x & 63;                     // = d
  const int bh   = gw >> 8;
  const int oct  = gw & 255;
  const int b = bh >> 4, h = bh & 15;
  const int tok0 = oct * 8;
  union { unsigned short u[8]; uint4 v; } ph;
  #pragma unroll
  for (int e = 0; e < 8; ++e) {
    const size_t g = (size_t)(b * kN + tok0 + e) * k3C + 2 * kC + h * kD + lane;
    ph.u[e] = H[g];
  }
  *(uint4*)(&VTH[((size_t)bh * kD + lane) * kN + tok0]) = ph.v;
}

// ============================================================================
// QKV GEMM, 256x256 tile, 8 waves (2x4), BK=32, double-buffered LDS.
// Term-split 3-phase schedule (verified round 2): each phase consumes ONE
// staged plane unit; every vmcnt targets loads issued >=2 phases earlier.
// ============================================================================
__global__ __launch_bounds__(512)
void gemm_qkv256(const unsigned short* __restrict__ AH,
                 const unsigned short* __restrict__ AL,
                 const unsigned short* __restrict__ WH,
                 const unsigned short* __restrict__ WL,
                 const float* __restrict__ bias,
                 unsigned short* __restrict__ OutH,
                 unsigned short* __restrict__ OutL,
                 const float* __restrict__ qn,
                 const float* __restrict__ kn)
{
  constexpr int BK = 32;
  constexpr int NT = kC / BK;   // 32 K-tiles

  // [buf][plane(hi/lo)][256 rows x 32 cols u16] = 128 KiB total
  __shared__ __align__(16) unsigned short sA[2][2][256 * 32];
  __shared__ __align__(16) unsigned short sB[2][2][256 * 32];

  const int tt   = threadIdx.x;        // 0..511
  const int wave = tt >> 6;            // 0..7
  const int lane = tt & 63;
  const int quad = lane >> 4;
  const int l16  = lane & 15;
  const int bm = blockIdx.x * 256;
  const int bn = blockIdx.y * 256;
  const int wm = (wave >> 2) * 128;    // wave row: 0/128
  const int wn = (wave & 3) * 64;      // wave col: 0/64/128/192

  // staging geometry: unit u = r*512 + tt; row = u>>2; swizzled col-group
  int srow[2], scol[2];
  #pragma unroll
  for (int r = 0; r < 2; ++r) {
    const int u = r * 512 + tt;
    srow[r] = u >> 2;
    scol[r] = ((u & 3) ^ ((srow[r] >> 1) & 3)) * 8;
  }

  // unit: 0=AH 1=WH 2=WL 3=AL (issue order!)
  auto stageU = [&](int bf, int k0, int which) {
    const unsigned short* src = (which == 0) ? AH : (which == 1) ? WH
                              : (which == 2) ? WL : AL;
    const int base = (which == 0 || which == 3) ? bm : bn;
    unsigned short* dst = (which == 0) ? &sA[bf][0][0]
                        : (which == 3) ? &sA[bf][1][0]
                        : (which == 1) ? &sB[bf][0][0] : &sB[bf][1][0];
    #pragma unroll
    for (int r = 0; r < 2; ++r)
      glds16(&src[(size_t)(base + srow[r]) * kC + k0 + scol[r]],
             &dst[(r * 512 + tt) * 8]);
  };

  auto rdA = [&](int bf, int pl, int row) -> bhalf8 {
    return *(const bhalf8*)(&sA[bf][pl][row * 32 + ((quad ^ ((row >> 1) & 3)) * 8)]);
  };
  auto rdB = [&](int bf, int pl, int row) -> bhalf8 {
    return *(const bhalf8*)(&sB[bf][pl][row * 32 + ((quad ^ ((row >> 1) & 3)) * 8)]);
  };

  f32x4 acc[8][4] = {};
  bhalf8 ah[8], bh_[4], bl_[4];

  // ---- prologue: stage all 4 units of tile 0; wait AH0,WH0 ----
  stageU(0, 0, 0); stageU(0, 0, 1); stageU(0, 0, 2); stageU(0, 0, 3);
  asm volatile("s_waitcnt vmcnt(4)" ::: "memory");
  __builtin_amdgcn_sched_barrier(0);
  asm volatile("s_barrier" ::: "memory");

  for (int t = 0; t < NT - 1; ++t) {
    const int buf  = t & 1;
    const int nbuf = buf ^ 1;
    const int nk0  = (t + 1) * BK;

    // ---- P01: hh term ----
    #pragma unroll
    for (int i = 0; i < 8; ++i) ah[i]  = rdA(buf, 0, wm + i * 16 + l16);
    #pragma unroll
    for (int j = 0; j < 4; ++j) bh_[j] = rdB(buf, 0, wn + j * 16 + l16);
    stageU(nbuf, nk0, 0);                 // AH(t+1)
    stageU(nbuf, nk0, 1);                 // WH(t+1)
    asm volatile("s_waitcnt vmcnt(6)" ::: "memory");   // drain WL(t)
    __builtin_amdgcn_sched_barrier(0);
    asm volatile("s_barrier" ::: "memory");
    __builtin_amdgcn_s_setprio(1);
    #pragma unroll
    for (int i = 0; i < 8; ++i)
      #pragma unroll
      for (int j = 0; j < 4; ++j)
        acc[i][j] = __builtin_amdgcn_mfma_f32_16x16x32_bf16(ah[i], bh_[j], acc[i][j], 0, 0, 0);
    __builtin_amdgcn_s_setprio(0);

    // ---- P2: hl term ----
    #pragma unroll
    for (int j = 0; j < 4; ++j) bl_[j] = rdB(buf, 1, wn + j * 16 + l16);
    stageU(nbuf, nk0, 2);                 // WL(t+1)
    asm volatile("s_waitcnt vmcnt(6)" ::: "memory");   // drain AL(t)
    __builtin_amdgcn_sched_barrier(0);
    asm volatile("s_barrier" ::: "memory");
    __builtin_amdgcn_s_setprio(1);
    #pragma unroll
    for (int i = 0; i < 8; ++i)
      #pragma unroll
      for (int j = 0; j < 4; ++j)
        acc[i][j] = __builtin_amdgcn_mfma_f32_16x16x32_bf16(ah[i], bl_[j], acc[i][j], 0, 0, 0);
    __builtin_amdgcn_s_setprio(0);

    // ---- P3: lh term ----
    stageU(nbuf, nk0, 3);                 // AL(t+1)
    asm volatile("s_waitcnt vmcnt(4)" ::: "memory");   // drain AH,WH(t+1)
    __builtin_amdgcn_sched_barrier(0);
    asm volatile("s_barrier" ::: "memory");
    __builtin_amdgcn_s_setprio(1);
    {
      bhalf8 al0[4];
      #pragma unroll
      for (int i = 0; i < 4; ++i) al0[i] = rdA(buf, 1, wm + i * 16 + l16);
      #pragma unroll
      for (int i = 0; i < 4; ++i)
        #pragma unroll
        for (int j = 0; j < 4; ++j)
          acc[i][j] = __builtin_amdgcn_mfma_f32_16x16x32_bf16(al0[i], bh_[j], acc[i][j], 0, 0, 0);
      bhalf8 al1[4];
      #pragma unroll
      for (int i = 0; i < 4; ++i) al1[i] = rdA(buf, 1, wm + (4 + i) * 16 + l16);
      #pragma unroll
      for (int i = 0; i < 4; ++i)
        #pragma unroll
        for (int j = 0; j < 4; ++j)
          acc[4 + i][j] = __builtin_amdgcn_mfma_f32_16x16x32_bf16(al1[i], bh_[j], acc[4 + i][j], 0, 0, 0);
    }
    __builtin_amdgcn_s_setprio(0);
    asm volatile("s_barrier" ::: "memory");   // end-of-tile lockstep
  }

  // ---- peeled last tile (no prefetch) ----
  {
    const int buf = (NT - 1) & 1;
    #pragma unroll
    for (int i = 0; i < 8; ++i) ah[i]  = rdA(buf, 0, wm + i * 16 + l16);
    #pragma unroll
    for (int j = 0; j < 4; ++j) bh_[j] = rdB(buf, 0, wn + j * 16 + l16);
    __builtin_amdgcn_s_setprio(1);
    #pragma unroll
    for (int i = 0; i < 8; ++i)
      #pragma unroll
      for (int j = 0; j < 4; ++j)
        acc[i][j] = __builtin_amdgcn_mfma_f32_16x16x32_bf16(ah[i], bh_[j], acc[i][j], 0, 0, 0);
    __builtin_amdgcn_s_setprio(0);

    asm volatile("s_waitcnt vmcnt(2)" ::: "memory");   // drain WL(last)
    __builtin_amdgcn_sched_barrier(0);
    asm volatile("s_barrier" ::: "memory");
    #pragma unroll
    for (int j = 0; j < 4; ++j) bl_[j] = rdB(buf, 1, wn + j * 16 + l16);
    __builtin_amdgcn_s_setprio(1);
    #pragma unroll
    for (int i = 0; i < 8; ++i)
      #pragma unroll
      for (int j = 0; j < 4; ++j)
        acc[i][j] = __builtin_amdgcn_mfma_f32_16x16x32_bf16(ah[i], bl_[j], acc[i][j], 0, 0, 0);
    __builtin_amdgcn_s_setprio(0);

    asm volatile("s_waitcnt vmcnt(0)" ::: "memory");   // drain AL(last)
    __builtin_amdgcn_sched_barrier(0);
    asm volatile("s_barrier" ::: "memory");
    __builtin_amdgcn_s_setprio(1);
    {
      bhalf8 al0[4];
      #pragma unroll
      for (int i = 0; i < 4; ++i) al0[i] = rdA(buf, 1, wm + i * 16 + l16);
      #pragma unroll
      for (int i = 0; i < 4; ++i)
        #pragma unroll
        for (int j = 0; j < 4; ++j)
          acc[i][j] = __builtin_amdgcn_mfma_f32_16x16x32_bf16(al0[i], bh_[j], acc[i][j], 0, 0, 0);
      bhalf8 al1[4];
      #pragma unroll
      for (int i = 0; i < 4; ++i) al1[i] = rdA(buf, 1, wm + (4 + i) * 16 + l16);
      #pragma unroll
      for (int i = 0; i < 4; ++i)
        #pragma unroll
        for (int j = 0; j < 4; ++j)
          acc[4 + i][j] = __builtin_amdgcn_mfma_f32_16x16x32_bf16(al1[i], bh_[j], acc[4 + i][j], 0, 0, 0);
    }
    __builtin_amdgcn_s_setprio(0);
  }

  // epilogue: C/D layout col=lane&15, row=quad*4+reg; fused RMSNorm on q,k
  const int slice = bn >> 10;          // 0=q,1=k,2=v (bn multiple of 256)
  const bool writeL = (slice == 0);
  float bv[4], wv[4];
  #pragma unroll
  for (int j = 0; j < 4; ++j) {
    bv[j] = bias[bn + wn + j * 16 + l16];
    if (slice < 2) wv[j] = (slice ? kn : qn)[j * 16 + l16];  // d = j*16+l16
  }

  #pragma unroll
  for (int i = 0; i < 8; ++i) {
    float val[4][4];
    #pragma unroll
    for (int j = 0; j < 4; ++j)
      #pragma unroll
      for (int r = 0; r < 4; ++r)
        val[j][r] = acc[i][j][r] + bv[j];

    if (slice < 2) {
      #pragma unroll
      for (int r = 0; r < 4; ++r) {
        float ss = val[0][r] * val[0][r];
        #pragma unroll
        for (int j = 1; j < 4; ++j) ss += val[j][r] * val[j][r];
        #pragma unroll
        for (int d = 1; d < 16; d <<= 1) ss += __shfl_xor(ss, d, 64);
        float rinv = rsqrtf(ss * (1.0f / 64.0f) + 1e-6f);
        // q * D^-0.5 * log2(e): attn uses exp2f (v_exp_f32 = 2^x)
        if (slice == 0) rinv *= 0.18033688011112042f;
        #pragma unroll
        for (int j = 0; j < 4; ++j) val[j][r] = wv[j] * (val[j][r] * rinv);
      }
    }

    #pragma unroll
    for (int j = 0; j < 4; ++j) {
      const int n = bn + wn + j * 16 + l16;
      #pragma unroll
      for (int r = 0; r < 4; ++r) {
        const int m = bm + wm + i * 16 + quad * 4 + r;
        unsigned short hh, ll;
        split2(val[j][r], hh, ll);
        OutH[(size_t)m * k3C + n] = hh;
        if (writeL) OutL[(size_t)m * k3C + n] = ll;
      }
    }
  }
}

// ---- plane GEMM (128^2, m97-structure): kept for the proj projection ----
template<bool OUTF32, bool FUSE_NORM>
__global__ __launch_bounds__(256)
void gemm_planes(const unsigned short* __restrict__ AH,
                 const unsigned short* __restrict__ AL, int lda,
                 const unsigned short* __restrict__ WH,
                 const unsigned short* __restrict__ WL,
                 const float* __restrict__ bias,
                 float* __restrict__ OutF,
                 unsigned short* __restrict__ OutH,
                 unsigned short* __restrict__ OutL,
                 const float* __restrict__ qn,
                 const float* __restrict__ kn,
                 int Nn, int K)
{
  __shared__ __align__(16) unsigned short AsH[128 * 32], AsL[128 * 32];
  __shared__ __align__(16) unsigned short BsH[128 * 32], BsL[128 * 32];

  const int t    = threadIdx.x;
  const int wave = t >> 6;
  const int lane = t & 63;
  const int quad = lane >> 4;
  const int l16  = lane & 15;
  const int bm = blockIdx.x * 128;
  const int bn = blockIdx.y * 128;
  const int wm = (wave >> 1) * 64;
  const int wn = (wave & 1) * 64;

  f32x4 acc[4][4] = {};

  for (int k0 = 0; k0 < K; k0 += 32) {
    #pragma unroll
    for (int r = 0; r < 2; ++r) {
      const int c   = r * 256 + t;
      const int row = c >> 2;
      const int col = (c & 3) * 8;
      glds16(&AH[(size_t)(bm + row) * lda + k0 + col], &AsH[c * 8]);
      glds16(&AL[(size_t)(bm + row) * lda + k0 + col], &AsL[c * 8]);
      glds16(&WH[(size_t)(bn + row) * K + k0 + col], &BsH[c * 8]);
      glds16(&WL[(size_t)(bn + row) * K + k0 + col], &BsL[c * 8]);
    }
    __syncthreads();

    bhalf8 afh[4], afl[4], bgh[4], bgl[4];
    #pragma unroll
    for (int i = 0; i < 4; ++i) {
      afh[i] = *(const bhalf8*)(&AsH[(wm + i * 16 + l16) * 32 + quad * 8]);
      afl[i] = *(const bhalf8*)(&AsL[(wm + i * 16 + l16) * 32 + quad * 8]);
      bgh[i] = *(const bhalf8*)(&BsH[(wn + i * 16 + l16) * 32 + quad * 8]);
      bgl[i] = *(const bhalf8*)(&BsL[(wn + i * 16 + l16) * 32 + quad * 8]);
    }
    #pragma unroll
    for (int i = 0; i < 4; ++i)
      #pragma unroll
      for (int j = 0; j < 4; ++j) {
        f32x4 a = acc[i][j];
        a = __builtin_amdgcn_mfma_f32_16x16x32_bf16(afh[i], bgh[j], a, 0, 0, 0);
        a = __builtin_amdgcn_mfma_f32_16x16x32_bf16(afh[i], bgl[j], a, 0, 0, 0);
        a = __builtin_amdgcn_mfma_f32_16x16x32_bf16(afl[i], bgh[j], a, 0, 0, 0);
        acc[i][j] = a;
      }
    __syncthreads();
  }

  // epilogue: C/D layout col=lane&15, row=quad*4+reg
  float bv[4], wv[4];
  const int slice = FUSE_NORM ? (bn >> 10) : 0;   // 0=q,1=k,2=v
  const bool writeL = !FUSE_NORM || slice == 0;
  #pragma unroll
  for (int j = 0; j < 4; ++j) {
    bv[j] = bias[bn + wn + j * 16 + l16];
    if (FUSE_NORM && slice < 2)
      wv[j] = (slice ? kn : qn)[j * 16 + l16];    // d = j*16+l16
  }

  #pragma unroll
  for (int i = 0; i < 4; ++i) {
    float val[4][4];
    #pragma unroll
    for (int j = 0; j < 4; ++j)
      #pragma unroll
      for (int r = 0; r < 4; ++r)
        val[j][r] = acc[i][j][r] + bv[j];

    if (FUSE_NORM && slice < 2) {
      #pragma unroll
      for (int r = 0; r < 4; ++r) {
        float ss = val[0][r] * val[0][r];
        #pragma unroll
        for (int j = 1; j < 4; ++j) ss += val[j][r] * val[j][r];
        #pragma unroll
        for (int d = 1; d < 16; d <<= 1) ss += __shfl_xor(ss, d, 64);
        float rinv = rsqrtf(ss * (1.0f / 64.0f) + 1e-6f);
        if (slice == 0) rinv *= 0.125f;           // q * D^-0.5
        #pragma unroll
        for (int j = 0; j < 4; ++j) val[j][r] = wv[j] * (val[j][r] * rinv);
      }
    }

    #pragma unroll
    for (int j = 0; j < 4; ++j) {
      const int n = bn + wn + j * 16 + l16;
      #pragma unroll
      for (int r = 0; r < 4; ++r) {
        const int m = bm + wm + i * 16 + quad * 4 + r;
        if (OUTF32) {
          OutF[(size_t)m * Nn + n] = val[j][r];
        } else {
          unsigned short hh, ll;
          split2(val[j][r], hh, ll);
          OutH[(size_t)m * Nn + n] = hh;
          if (writeL) OutL[(size_t)m * Nn + n] = ll;
        }
      }
    }
  }
}

// ---- flash attention v9: 16 q-rows/wave, grid 1024; K/V LDS uses the P=72
// odd-pitch natural skew (verified conflict-free store+read by bank math;
// round-4's added XOR swizzle DOUBLE-swizzled and broke reads). Pt uses
// pitch 68 so rows 8 apart don't alias a bank (8*68*2/4 mod 32 = 16). ----
__global__ __launch_bounds__(256)
void attn_kernel(unsigned short* __restrict__ H, unsigned short* __restrict__ L,
                 const unsigned short* __restrict__ VTH,
                 const int* __restrict__ mask)
{
  constexpr int P   = 72;  // K/V pitch: bank-start 4*((row+col16)%8) — balanced
  constexpr int Ppt = 68;  // Pt pitch: row-8 alias broken, store = dword pairs
  __shared__ __align__(16) unsigned short KtH[64 * P];     //  9.2 KB [key][d]
  __shared__ __align__(16) unsigned short VtH[64 * P];     //  9.2 KB [d][key]
  __shared__ __align__(16) unsigned short Pt[4][16 * Ppt]; //  8.7 KB per-wave [q][key]

  const int t    = threadIdx.x;
  const int wave = t >> 6;
  const int lane = t & 63;
  const int quad = lane >> 4;
  const int l16  = lane & 15;

  // XCD swizzle: lin%8 = XCD (dispatch round-robin); 4 bh per XCD, 32 qblk each.
  const int lin  = blockIdx.x;          // 0..1023
  const int xcd  = lin & 7;
  const int slot = lin >> 3;            // 0..127
  const int bh   = xcd + 8 * (slot >> 5);
  const int qblk = slot & 31;
  const int b  = bh >> 4;
  const int h  = bh & 15;
  const int q0 = qblk * 64 + wave * 16;   // 16 q-rows/wave

  // staging geometry: 2 chunks of 8 u16 per thread per tile; rows 0..31 / 32..63
  const int row0 = t >> 3, col0 = (t & 7) * 8;
  const int row1 = row0 + 32;

  // Q fragments (A-layout: m=l16, k=quad*8+j); 16 rows only
  bhalf8 qfh[2], qfl[2];
  {
    const size_t qrow = (size_t)(b * kN + q0 + l16) * k3C + h * kD;
    qfh[0] = *(const bhalf8*)(&H[qrow + quad * 8]);
    qfh[1] = *(const bhalf8*)(&H[qrow + 32 + quad * 8]);
    qfl[0] = *(const bhalf8*)(&L[qrow + quad * 8]);
    qfl[1] = *(const bhalf8*)(&L[qrow + 32 + quad * 8]);
  }

  f32x4 acc_o[4] = {};
  float lpart[4] = {};

  uint4 sk0, sk1, sv0, sv1;            // staging regs
  int mcur[4], mnext[4];

  auto pref = [&](int kt) {
    sk0 = *(const uint4*)(&H[(size_t)(b * kN + kt + row0) * k3C + kC + h * kD + col0]);
    sk1 = *(const uint4*)(&H[(size_t)(b * kN + kt + row1) * k3C + kC + h * kD + col0]);
    sv0 = *(const uint4*)(&VTH[((size_t)bh * kD + row0) * kN + kt + col0]);
    sv1 = *(const uint4*)(&VTH[((size_t)bh * kD + row1) * kN + kt + col0]);
  };
  auto loadM = [&](int kt, int* m) {
    #pragma unroll
    for (int nt = 0; nt < 4; ++nt) m[nt] = mask[b * kN + kt + nt * 16 + l16];
  };

  pref(0);
  loadM(0, mcur);
  #pragma unroll
  for (int nt = 0; nt < 4; ++nt) mnext[nt] = mcur[nt];

  for (int i = 0; i < 32; ++i) {
    const int kt = i * 64;
    // drain staged regs into LDS (P=72 pitch provides the bank skew)
    *(uint4*)(&KtH[row0 * P + col0]) = sk0;
    *(uint4*)(&KtH[row1 * P + col0]) = sk1;
    *(uint4*)(&VtH[row0 * P + col0]) = sv0;
    *(uint4*)(&VtH[row1 * P + col0]) = sv1;
    __syncthreads();

    // issue next tile's global loads early; consumed next iter
    if (i < 31) { pref(kt + 64); loadM(kt + 64, mnext); }

    // S = (Qh+Ql)Kh ; p = flag*2^s -> Pt (C-layout -> A-layout)
    #pragma unroll
    for (int nt = 0; nt < 4; ++nt) {
      const int kr = (nt * 16 + l16) * P + quad * 8;
      const bhalf8 kh0 = *(const bhalf8*)(&KtH[kr]);
      const bhalf8 kh1 = *(const bhalf8*)(&KtH[kr + 32]);
      const float flag = mcur[nt] ? 1.0f : 0.0f;
      f32x4 s = {};
      s = __builtin_amdgcn_mfma_f32_16x16x32_bf16(qfh[0], kh0, s, 0, 0, 0);
      s = __builtin_amdgcn_mfma_f32_16x16x32_bf16(qfh[1], kh1, s, 0, 0, 0);
      s = __builtin_amdgcn_mfma_f32_16x16x32_bf16(qfl[0], kh0, s, 0, 0, 0);
      s = __builtin_amdgcn_mfma_f32_16x16x32_bf16(qfl[1], kh1, s, 0, 0, 0);
      #pragma unroll
      for (int r = 0; r < 4; ++r) {
        const float p = flag * exp2f(s[r]);   // s pre-scaled by log2e
        lpart[r] += p;
        Pt[wave][(quad * 4 + r) * Ppt + nt * 16 + l16] = f2bf(p);
      }
    }

    // O += P * Vh  (Pt per-wave: same-wave DS ordering, no barrier needed)
    #pragma unroll
    for (int kk = 0; kk < 2; ++kk) {
      const bhalf8 pa = *(const bhalf8*)(&Pt[wave][l16 * Ppt + kk * 32 + quad * 8]);
      #pragma unroll
      for (int dt = 0; dt < 4; ++dt) {
        const bhalf8 vb = *(const bhalf8*)(&VtH[(dt * 16 + l16) * P + kk * 32 + quad * 8]);
        acc_o[dt] = __builtin_amdgcn_mfma_f32_16x16x32_bf16(pa, vb, acc_o[dt], 0, 0, 0);
      }
    }

    #pragma unroll
    for (int nt = 0; nt < 4; ++nt) mcur[nt] = mnext[nt];
    __syncthreads();     // Kt/Vt readers done; next iter may overwrite
  }

  // final l reduction + normalize + store hi/lo into q-slice
  #pragma unroll
  for (int r = 0; r < 4; ++r) {
    float s = lpart[r];
    #pragma unroll
    for (int d = 1; d < 16; d <<= 1) s += __shfl_xor(s, d, 64);
    lpart[r] = s;
  }
  #pragma unroll
  for (int dt = 0; dt < 4; ++dt)
    #pragma unroll
    for (int r = 0; r < 4; ++r) {
      const int qrow = q0 + quad * 4 + r;
      const float inv = 1.0f / fmaxf(lpart[r], 1.0e-30f);
      const size_t off = (size_t)(b * kN + qrow) * k3C + h * kD + dt * 16 + l16;
      unsigned short hh, ll;
      split2(acc_o[dt][r] * inv, hh, ll);
      H[off] = hh; L[off] = ll;
    }
}

} // anonymous namespace

extern "C" void kernel_launch(void* const* d_in, const int* in_sizes, int n_in,
                              void* d_out, int out_size, void* d_ws, size_t ws_size,
                              hipStream_t stream)
{
  const float* x      = (const float*)d_in[0];
  const int*   maskp  = (const int*)d_in[1];
  const float* qkv_w  = (const float*)d_in[2];
  const float* qkv_b  = (const float*)d_in[3];
  const float* proj_w = (const float*)d_in[4];
  const float* proj_b = (const float*)d_in[5];
  const float* qn_w   = (const float*)d_in[6];
  const float* kn_w   = (const float*)d_in[7];
  float* out = (float*)d_out;

  unsigned short* qH = (unsigned short*)d_ws;      // qkv hi plane
  unsigned short* qL = qH + kPS;                   // qkv lo plane
  unsigned short* R1 = qL + kPS;                   // x planes -> later VT plane
  unsigned short* R2 = R1 + 2 * kXE;               // qkv_w planes -> later proj_w planes
  unsigned short* xH = R1,  *xL = R1 + kXE;
  unsigned short* VTH = R1;                        // reuse after gemm1
  unsigned short* wqH = R2, *wqL = R2 + kWQ;
  unsigned short* wpH = R2, *wpL = R2 + kWP;

  split_planes<<<(int)(kXE / 4 / 256), 256, 0, stream>>>(x, xH, xL, (int)(kXE / 4));
  split_planes<<<(int)(kWQ / 4 / 256), 256, 0, stream>>>(qkv_w, wqH, wqL, (int)(kWQ / 4));

  // 1) qkv = x @ qkv_w^T + qkv_b, RMSNorm(q,k) fused; lo written for q only
  //    256^2 pipelined kernel: grid (4096/256, 3072/256) = (16, 12)
  gemm_qkv256<<<dim3(kTok / 256, k3C / 256), 512, 0, stream>>>(
      xH, xL, wqH, wqL, qkv_b, qH, qL, qn_w, kn_w);

  // 2) pre-transpose V hi (overwrites x planes); pre-split proj_w
  vt_transpose<<<2048, 256, 0, stream>>>(qH, VTH);
  split_planes<<<(int)(kWP / 4 / 256), 256, 0, stream>>>(proj_w, wpH, wpL, (int)(kWP / 4));

  // 3) masked flash attention (XCD-swizzled 1-D grid, 1024 blocks)
  attn_kernel<<<dim3(1024), 256, 0, stream>>>(qH, qL, VTH, maskp);

  // 4) out = attn @ proj_w^T + proj_b
  gemm_planes<true, false><<<dim3(kTok / 128, kC / 128), 256, 0, stream>>>(
      qH, qL, k3C, wpH, wpL, proj_b, out, nullptr, nullptr, nullptr, nullptr, kC, kC);
}

// Round 6
// 306.030 us; speedup vs baseline: 1.0464x; 1.0051x over previous
//
#include <hip/hip_runtime.h>
#include <hip/hip_bf16.h>
#include <stdint.h>
#include <math.h>

namespace {

constexpr int kB = 2;
constexpr int kN = 2048;
constexpr int kC = 1024;
constexpr int kH = 16;
constexpr int kD = 64;
constexpr int kTok = kB * kN;               // 4096
constexpr int k3C  = 3 * kC;                // 3072
constexpr size_t kPS = (size_t)kTok * k3C;  // qkv plane elems
constexpr size_t kXE = (size_t)kTok * kC;   // x / VT plane elems
constexpr size_t kWQ = (size_t)k3C * kC;    // qkv_w elems
constexpr size_t kWP = (size_t)kC * kC;     // proj_w elems

using bhalf8 = __attribute__((ext_vector_type(8))) __bf16;
using f32x4  = __attribute__((ext_vector_type(4))) float;

__device__ inline unsigned short f2bf(float f) {
  __hip_bfloat16 h = __float2bfloat16(f);
  return *reinterpret_cast<unsigned short*>(&h);
}
__device__ inline float bf2f(unsigned short u) {
  __hip_bfloat16 h;
  *reinterpret_cast<unsigned short*>(&h) = u;
  return __bfloat162float(h);
}
__device__ inline void split2(float v, unsigned short& h, unsigned short& l) {
  const unsigned short hb = f2bf(v);
  h = hb;
  l = f2bf(v - bf2f(hb));
}

// async global->LDS, 16B per lane; LDS dest must be wave-uniform base + lane*16
__device__ inline void glds16(const unsigned short* g, unsigned short* l) {
  __builtin_amdgcn_global_load_lds(
      (const __attribute__((address_space(1))) void*)g,
      (__attribute__((address_space(3))) void*)l, 16, 0, 0);
}

// ---- split fp32 -> bf16 hi/lo planes ----
__global__ __launch_bounds__(256)
void split_planes(const float* __restrict__ src,
                  unsigned short* __restrict__ H,
                  unsigned short* __restrict__ L, int n4)
{
  const int i = blockIdx.x * 256 + threadIdx.x;
  if (i >= n4) return;
  const float4 v = ((const float4*)src)[i];
  ushort4 hh, ll;
  split2(v.x, hh.x, ll.x); split2(v.y, hh.y, ll.y);
  split2(v.z, hh.z, ll.z); split2(v.w, hh.w, ll.w);
  ((ushort4*)H)[i] = hh;
  ((ushort4*)L)[i] = ll;
}

// ---- pre-transpose V (hi plane only) into VT[bh][d][token] ----
__global__ __launch_bounds__(256)
void vt_transpose(const unsigned short* __restrict__ H,
                  unsigned short* __restrict__ VTH)
{
  const int gw   = blockIdx.x * 4 + (threadIdx.x >> 6);  // 0..8191
  const int lane = threadIdx.x & 63;                     // = d
  const int bh   = gw >> 8;
  const int oct  = gw & 255;
  const int b = bh >> 4, h = bh & 15;
  const int tok0 = oct * 8;
  union { unsigned short u[8]; uint4 v; } ph;
  #pragma unroll
  for (int e = 0; e < 8; ++e) {
    const size_t g = (size_t)(b * kN + tok0 + e) * k3C + 2 * kC + h * kD + lane;
    ph.u[e] = H[g];
  }
  *(uint4*)(&VTH[((size_t)bh * kD + lane) * kN + tok0]) = ph.v;
}

// ============================================================================
// QKV GEMM, 256x256 tile, 8 waves (2x4), BK=32, double-buffered LDS.
// Term-split 3-phase schedule (verified round 2): each phase consumes ONE
// staged plane unit; every vmcnt targets loads issued >=2 phases earlier.
// ============================================================================
__global__ __launch_bounds__(512)
void gemm_qkv256(const unsigned short* __restrict__ AH,
                 const unsigned short* __restrict__ AL,
                 const unsigned short* __restrict__ WH,
                 const unsigned short* __restrict__ WL,
                 const float* __restrict__ bias,
                 unsigned short* __restrict__ OutH,
                 unsigned short* __restrict__ OutL,
                 const float* __restrict__ qn,
                 const float* __restrict__ kn)
{
  constexpr int BK = 32;
  constexpr int NT = kC / BK;   // 32 K-tiles

  // [buf][plane(hi/lo)][256 rows x 32 cols u16] = 128 KiB total
  __shared__ __align__(16) unsigned short sA[2][2][256 * 32];
  __shared__ __align__(16) unsigned short sB[2][2][256 * 32];

  const int tt   = threadIdx.x;        // 0..511
  const int wave = tt >> 6;            // 0..7
  const int lane = tt & 63;
  const int quad = lane >> 4;
  const int l16  = lane & 15;
  const int bm = blockIdx.x * 256;
  const int bn = blockIdx.y * 256;
  const int wm = (wave >> 2) * 128;    // wave row: 0/128
  const int wn = (wave & 3) * 64;      // wave col: 0/64/128/192

  // staging geometry: unit u = r*512 + tt; row = u>>2; swizzled col-group
  int srow[2], scol[2];
  #pragma unroll
  for (int r = 0; r < 2; ++r) {
    const int u = r * 512 + tt;
    srow[r] = u >> 2;
    scol[r] = ((u & 3) ^ ((srow[r] >> 1) & 3)) * 8;
  }

  // unit: 0=AH 1=WH 2=WL 3=AL (issue order!)
  auto stageU = [&](int bf, int k0, int which) {
    const unsigned short* src = (which == 0) ? AH : (which == 1) ? WH
                              : (which == 2) ? WL : AL;
    const int base = (which == 0 || which == 3) ? bm : bn;
    unsigned short* dst = (which == 0) ? &sA[bf][0][0]
                        : (which == 3) ? &sA[bf][1][0]
                        : (which == 1) ? &sB[bf][0][0] : &sB[bf][1][0];
    #pragma unroll
    for (int r = 0; r < 2; ++r)
      glds16(&src[(size_t)(base + srow[r]) * kC + k0 + scol[r]],
             &dst[(r * 512 + tt) * 8]);
  };

  auto rdA = [&](int bf, int pl, int row) -> bhalf8 {
    return *(const bhalf8*)(&sA[bf][pl][row * 32 + ((quad ^ ((row >> 1) & 3)) * 8)]);
  };
  auto rdB = [&](int bf, int pl, int row) -> bhalf8 {
    return *(const bhalf8*)(&sB[bf][pl][row * 32 + ((quad ^ ((row >> 1) & 3)) * 8)]);
  };

  f32x4 acc[8][4] = {};
  bhalf8 ah[8], bh_[4], bl_[4];

  // ---- prologue: stage all 4 units of tile 0; wait AH0,WH0 ----
  stageU(0, 0, 0); stageU(0, 0, 1); stageU(0, 0, 2); stageU(0, 0, 3);
  asm volatile("s_waitcnt vmcnt(4)" ::: "memory");
  __builtin_amdgcn_sched_barrier(0);
  asm volatile("s_barrier" ::: "memory");

  for (int t = 0; t < NT - 1; ++t) {
    const int buf  = t & 1;
    const int nbuf = buf ^ 1;
    const int nk0  = (t + 1) * BK;

    // ---- P01: hh term ----
    #pragma unroll
    for (int i = 0; i < 8; ++i) ah[i]  = rdA(buf, 0, wm + i * 16 + l16);
    #pragma unroll
    for (int j = 0; j < 4; ++j) bh_[j] = rdB(buf, 0, wn + j * 16 + l16);
    stageU(nbuf, nk0, 0);                 // AH(t+1)
    stageU(nbuf, nk0, 1);                 // WH(t+1)
    asm volatile("s_waitcnt vmcnt(6)" ::: "memory");   // drain WL(t)
    __builtin_amdgcn_sched_barrier(0);
    asm volatile("s_barrier" ::: "memory");
    __builtin_amdgcn_s_setprio(1);
    #pragma unroll
    for (int i = 0; i < 8; ++i)
      #pragma unroll
      for (int j = 0; j < 4; ++j)
        acc[i][j] = __builtin_amdgcn_mfma_f32_16x16x32_bf16(ah[i], bh_[j], acc[i][j], 0, 0, 0);
    __builtin_amdgcn_s_setprio(0);

    // ---- P2: hl term ----
    #pragma unroll
    for (int j = 0; j < 4; ++j) bl_[j] = rdB(buf, 1, wn + j * 16 + l16);
    stageU(nbuf, nk0, 2);                 // WL(t+1)
    asm volatile("s_waitcnt vmcnt(6)" ::: "memory");   // drain AL(t)
    __builtin_amdgcn_sched_barrier(0);
    asm volatile("s_barrier" ::: "memory");
    __builtin_amdgcn_s_setprio(1);
    #pragma unroll
    for (int i = 0; i < 8; ++i)
      #pragma unroll
      for (int j = 0; j < 4; ++j)
        acc[i][j] = __builtin_amdgcn_mfma_f32_16x16x32_bf16(ah[i], bl_[j], acc[i][j], 0, 0, 0);
    __builtin_amdgcn_s_setprio(0);

    // ---- P3: lh term ----
    stageU(nbuf, nk0, 3);                 // AL(t+1)
    asm volatile("s_waitcnt vmcnt(4)" ::: "memory");   // drain AH,WH(t+1)
    __builtin_amdgcn_sched_barrier(0);
    asm volatile("s_barrier" ::: "memory");
    __builtin_amdgcn_s_setprio(1);
    {
      bhalf8 al0[4];
      #pragma unroll
      for (int i = 0; i < 4; ++i) al0[i] = rdA(buf, 1, wm + i * 16 + l16);
      #pragma unroll
      for (int i = 0; i < 4; ++i)
        #pragma unroll
        for (int j = 0; j < 4; ++j)
          acc[i][j] = __builtin_amdgcn_mfma_f32_16x16x32_bf16(al0[i], bh_[j], acc[i][j], 0, 0, 0);
      bhalf8 al1[4];
      #pragma unroll
      for (int i = 0; i < 4; ++i) al1[i] = rdA(buf, 1, wm + (4 + i) * 16 + l16);
      #pragma unroll
      for (int i = 0; i < 4; ++i)
        #pragma unroll
        for (int j = 0; j < 4; ++j)
          acc[4 + i][j] = __builtin_amdgcn_mfma_f32_16x16x32_bf16(al1[i], bh_[j], acc[4 + i][j], 0, 0, 0);
    }
    __builtin_amdgcn_s_setprio(0);
    asm volatile("s_barrier" ::: "memory");   // end-of-tile lockstep
  }

  // ---- peeled last tile (no prefetch) ----
  {
    const int buf = (NT - 1) & 1;
    #pragma unroll
    for (int i = 0; i < 8; ++i) ah[i]  = rdA(buf, 0, wm + i * 16 + l16);
    #pragma unroll
    for (int j = 0; j < 4; ++j) bh_[j] = rdB(buf, 0, wn + j * 16 + l16);
    __builtin_amdgcn_s_setprio(1);
    #pragma unroll
    for (int i = 0; i < 8; ++i)
      #pragma unroll
      for (int j = 0; j < 4; ++j)
        acc[i][j] = __builtin_amdgcn_mfma_f32_16x16x32_bf16(ah[i], bh_[j], acc[i][j], 0, 0, 0);
    __builtin_amdgcn_s_setprio(0);

    asm volatile("s_waitcnt vmcnt(2)" ::: "memory");   // drain WL(last)
    __builtin_amdgcn_sched_barrier(0);
    asm volatile("s_barrier" ::: "memory");
    #pragma unroll
    for (int j = 0; j < 4; ++j) bl_[j] = rdB(buf, 1, wn + j * 16 + l16);
    __builtin_amdgcn_s_setprio(1);
    #pragma unroll
    for (int i = 0; i < 8; ++i)
      #pragma unroll
      for (int j = 0; j < 4; ++j)
        acc[i][j] = __builtin_amdgcn_mfma_f32_16x16x32_bf16(ah[i], bl_[j], acc[i][j], 0, 0, 0);
    __builtin_amdgcn_s_setprio(0);

    asm volatile("s_waitcnt vmcnt(0)" ::: "memory");   // drain AL(last)
    __builtin_amdgcn_sched_barrier(0);
    asm volatile("s_barrier" ::: "memory");
    __builtin_amdgcn_s_setprio(1);
    {
      bhalf8 al0[4];
      #pragma unroll
      for (int i = 0; i < 4; ++i) al0[i] = rdA(buf, 1, wm + i * 16 + l16);
      #pragma unroll
      for (int i = 0; i < 4; ++i)
        #pragma unroll
        for (int j = 0; j < 4; ++j)
          acc[i][j] = __builtin_amdgcn_mfma_f32_16x16x32_bf16(al0[i], bh_[j], acc[i][j], 0, 0, 0);
      bhalf8 al1[4];
      #pragma unroll
      for (int i = 0; i < 4; ++i) al1[i] = rdA(buf, 1, wm + (4 + i) * 16 + l16);
      #pragma unroll
      for (int i = 0; i < 4; ++i)
        #pragma unroll
        for (int j = 0; j < 4; ++j)
          acc[4 + i][j] = __builtin_amdgcn_mfma_f32_16x16x32_bf16(al1[i], bh_[j], acc[4 + i][j], 0, 0, 0);
    }
    __builtin_amdgcn_s_setprio(0);
  }

  // epilogue: C/D layout col=lane&15, row=quad*4+reg; fused RMSNorm on q,k
  const int slice = bn >> 10;          // 0=q,1=k,2=v (bn multiple of 256)
  const bool writeL = (slice == 0);
  float bv[4], wv[4];
  #pragma unroll
  for (int j = 0; j < 4; ++j) {
    bv[j] = bias[bn + wn + j * 16 + l16];
    if (slice < 2) wv[j] = (slice ? kn : qn)[j * 16 + l16];  // d = j*16+l16
  }

  #pragma unroll
  for (int i = 0; i < 8; ++i) {
    float val[4][4];
    #pragma unroll
    for (int j = 0; j < 4; ++j)
      #pragma unroll
      for (int r = 0; r < 4; ++r)
        val[j][r] = acc[i][j][r] + bv[j];

    if (slice < 2) {
      #pragma unroll
      for (int r = 0; r < 4; ++r) {
        float ss = val[0][r] * val[0][r];
        #pragma unroll
        for (int j = 1; j < 4; ++j) ss += val[j][r] * val[j][r];
        #pragma unroll
        for (int d = 1; d < 16; d <<= 1) ss += __shfl_xor(ss, d, 64);
        float rinv = rsqrtf(ss * (1.0f / 64.0f) + 1e-6f);
        // q * D^-0.5 * log2(e): attn uses exp2f (v_exp_f32 = 2^x)
        if (slice == 0) rinv *= 0.18033688011112042f;
        #pragma unroll
        for (int j = 0; j < 4; ++j) val[j][r] = wv[j] * (val[j][r] * rinv);
      }
    }

    #pragma unroll
    for (int j = 0; j < 4; ++j) {
      const int n = bn + wn + j * 16 + l16;
      #pragma unroll
      for (int r = 0; r < 4; ++r) {
        const int m = bm + wm + i * 16 + quad * 4 + r;
        unsigned short hh, ll;
        split2(val[j][r], hh, ll);
        OutH[(size_t)m * k3C + n] = hh;
        if (writeL) OutL[(size_t)m * k3C + n] = ll;
      }
    }
  }
}

// ---- plane GEMM (128^2, m97-structure): kept for the proj projection ----
template<bool OUTF32, bool FUSE_NORM>
__global__ __launch_bounds__(256)
void gemm_planes(const unsigned short* __restrict__ AH,
                 const unsigned short* __restrict__ AL, int lda,
                 const unsigned short* __restrict__ WH,
                 const unsigned short* __restrict__ WL,
                 const float* __restrict__ bias,
                 float* __restrict__ OutF,
                 unsigned short* __restrict__ OutH,
                 unsigned short* __restrict__ OutL,
                 const float* __restrict__ qn,
                 const float* __restrict__ kn,
                 int Nn, int K)
{
  __shared__ __align__(16) unsigned short AsH[128 * 32], AsL[128 * 32];
  __shared__ __align__(16) unsigned short BsH[128 * 32], BsL[128 * 32];

  const int t    = threadIdx.x;
  const int wave = t >> 6;
  const int lane = t & 63;
  const int quad = lane >> 4;
  const int l16  = lane & 15;
  const int bm = blockIdx.x * 128;
  const int bn = blockIdx.y * 128;
  const int wm = (wave >> 1) * 64;
  const int wn = (wave & 1) * 64;

  f32x4 acc[4][4] = {};

  for (int k0 = 0; k0 < K; k0 += 32) {
    #pragma unroll
    for (int r = 0; r < 2; ++r) {
      const int c   = r * 256 + t;
      const int row = c >> 2;
      const int col = (c & 3) * 8;
      glds16(&AH[(size_t)(bm + row) * lda + k0 + col], &AsH[c * 8]);
      glds16(&AL[(size_t)(bm + row) * lda + k0 + col], &AsL[c * 8]);
      glds16(&WH[(size_t)(bn + row) * K + k0 + col], &BsH[c * 8]);
      glds16(&WL[(size_t)(bn + row) * K + k0 + col], &BsL[c * 8]);
    }
    __syncthreads();

    bhalf8 afh[4], afl[4], bgh[4], bgl[4];
    #pragma unroll
    for (int i = 0; i < 4; ++i) {
      afh[i] = *(const bhalf8*)(&AsH[(wm + i * 16 + l16) * 32 + quad * 8]);
      afl[i] = *(const bhalf8*)(&AsL[(wm + i * 16 + l16) * 32 + quad * 8]);
      bgh[i] = *(const bhalf8*)(&BsH[(wn + i * 16 + l16) * 32 + quad * 8]);
      bgl[i] = *(const bhalf8*)(&BsL[(wn + i * 16 + l16) * 32 + quad * 8]);
    }
    #pragma unroll
    for (int i = 0; i < 4; ++i)
      #pragma unroll
      for (int j = 0; j < 4; ++j) {
        f32x4 a = acc[i][j];
        a = __builtin_amdgcn_mfma_f32_16x16x32_bf16(afh[i], bgh[j], a, 0, 0, 0);
        a = __builtin_amdgcn_mfma_f32_16x16x32_bf16(afh[i], bgl[j], a, 0, 0, 0);
        a = __builtin_amdgcn_mfma_f32_16x16x32_bf16(afl[i], bgh[j], a, 0, 0, 0);
        acc[i][j] = a;
      }
    __syncthreads();
  }

  // epilogue: C/D layout col=lane&15, row=quad*4+reg
  float bv[4], wv[4];
  const int slice = FUSE_NORM ? (bn >> 10) : 0;   // 0=q,1=k,2=v
  const bool writeL = !FUSE_NORM || slice == 0;
  #pragma unroll
  for (int j = 0; j < 4; ++j) {
    bv[j] = bias[bn + wn + j * 16 + l16];
    if (FUSE_NORM && slice < 2)
      wv[j] = (slice ? kn : qn)[j * 16 + l16];    // d = j*16+l16
  }

  #pragma unroll
  for (int i = 0; i < 4; ++i) {
    float val[4][4];
    #pragma unroll
    for (int j = 0; j < 4; ++j)
      #pragma unroll
      for (int r = 0; r < 4; ++r)
        val[j][r] = acc[i][j][r] + bv[j];

    if (FUSE_NORM && slice < 2) {
      #pragma unroll
      for (int r = 0; r < 4; ++r) {
        float ss = val[0][r] * val[0][r];
        #pragma unroll
        for (int j = 1; j < 4; ++j) ss += val[j][r] * val[j][r];
        #pragma unroll
        for (int d = 1; d < 16; d <<= 1) ss += __shfl_xor(ss, d, 64);
        float rinv = rsqrtf(ss * (1.0f / 64.0f) + 1e-6f);
        if (slice == 0) rinv *= 0.125f;           // q * D^-0.5
        #pragma unroll
        for (int j = 0; j < 4; ++j) val[j][r] = wv[j] * (val[j][r] * rinv);
      }
    }

    #pragma unroll
    for (int j = 0; j < 4; ++j) {
      const int n = bn + wn + j * 16 + l16;
      #pragma unroll
      for (int r = 0; r < 4; ++r) {
        const int m = bm + wm + i * 16 + quad * 4 + r;
        if (OUTF32) {
          OutF[(size_t)m * Nn + n] = val[j][r];
        } else {
          unsigned short hh, ll;
          split2(val[j][r], hh, ll);
          OutH[(size_t)m * Nn + n] = hh;
          if (writeL) OutL[(size_t)m * Nn + n] = ll;
        }
      }
    }
  }
}

// ---- flash attention v10: round-2 dense shape (512 blocks, 4 waves, 32 q/wave)
// + K/V LDS DOUBLE-BUFFER with ONE barrier per iter (stores overlap compute)
// + Pt pitch 68 (kills quad-aliasing on P stores) + exp2f (scale folded). ----
__global__ __launch_bounds__(256)
void attn_kernel(unsigned short* __restrict__ H, unsigned short* __restrict__ L,
                 const unsigned short* __restrict__ VTH,
                 const int* __restrict__ mask)
{
  constexpr int P   = 72;  // K/V pitch: bank-start 4*((row+col16)%8) — balanced
  constexpr int Ppt = 68;  // Pt pitch: quad groups land on distinct banks
  __shared__ __align__(16) unsigned short KtH[2][64 * P];   // 18.4 KB dbuf
  __shared__ __align__(16) unsigned short VtH[2][64 * P];   // 18.4 KB dbuf
  __shared__ __align__(16) unsigned short Pt[4][32 * Ppt];  // 17.4 KB per-wave

  const int t    = threadIdx.x;
  const int wave = t >> 6;
  const int lane = t & 63;
  const int quad = lane >> 4;
  const int l16  = lane & 15;

  // XCD swizzle: lin%8 = XCD (dispatch round-robin); 4 bh per XCD.
  const int lin  = blockIdx.x;          // 0..511
  const int xcd  = lin & 7;
  const int slot = lin >> 3;            // 0..63
  const int bh   = xcd + 8 * (slot >> 4);
  const int qblk = slot & 15;
  const int b  = bh >> 4;
  const int h  = bh & 15;
  const int q0 = qblk * 128 + wave * 32;  // 32 q-rows/wave

  // staging geometry: 2 chunks of 8 u16 per thread per tile
  const int row0 = t >> 3,         col0 = (t & 7) * 8;
  const int row1 = (256 + t) >> 3, col1 = ((256 + t) & 7) * 8;

  // Q fragments, both groups (A-layout: m=l16, k=quad*8+j)
  bhalf8 qfh[2][2], qfl[2][2];
  #pragma unroll
  for (int g = 0; g < 2; ++g) {
    const size_t qrow = (size_t)(b * kN + q0 + g * 16 + l16) * k3C + h * kD;
    qfh[g][0] = *(const bhalf8*)(&H[qrow + quad * 8]);
    qfh[g][1] = *(const bhalf8*)(&H[qrow + 32 + quad * 8]);
    qfl[g][0] = *(const bhalf8*)(&L[qrow + quad * 8]);
    qfl[g][1] = *(const bhalf8*)(&L[qrow + 32 + quad * 8]);
  }

  f32x4 acc_o[2][4] = {};
  float lpart[2][4] = {};

  uint4 sk0, sk1, sv0, sv1;            // staging regs
  int mcur[4], mnext[4];

  auto pref = [&](int kt) {
    sk0 = *(const uint4*)(&H[(size_t)(b * kN + kt + row0) * k3C + kC + h * kD + col0]);
    sk1 = *(const uint4*)(&H[(size_t)(b * kN + kt + row1) * k3C + kC + h * kD + col1]);
    sv0 = *(const uint4*)(&VTH[((size_t)bh * kD + row0) * kN + kt + col0]);
    sv1 = *(const uint4*)(&VTH[((size_t)bh * kD + row1) * kN + kt + col1]);
  };
  auto store_tile = [&](int bf) {
    *(uint4*)(&KtH[bf][row0 * P + col0]) = sk0;
    *(uint4*)(&KtH[bf][row1 * P + col1]) = sk1;
    *(uint4*)(&VtH[bf][row0 * P + col0]) = sv0;
    *(uint4*)(&VtH[bf][row1 * P + col1]) = sv1;
  };
  auto loadM = [&](int kt, int* m) {
    #pragma unroll
    for (int nt = 0; nt < 4; ++nt) m[nt] = mask[b * kN + kt + nt * 16 + l16];
  };

  // prologue: tile 0 -> buf0; issue tile 1 loads; one barrier
  pref(0);
  loadM(0, mcur);
  #pragma unroll
  for (int nt = 0; nt < 4; ++nt) mnext[nt] = mcur[nt];
  store_tile(0);                       // compiler inserts vmcnt for sk/sv deps
  pref(64);                            // tile 1 in flight across the barrier
  __syncthreads();

  for (int i = 0; i < 32; ++i) {
    const int cur = i & 1;
    const int kt = i * 64;
    if (i < 31) loadM(kt + 64, mnext);

    // S = (Qh+Ql)Kh ; p = flag*2^s -> Pt (C-layout -> A-layout)
    #pragma unroll
    for (int nt = 0; nt < 4; ++nt) {
      const int kr = (nt * 16 + l16) * P + quad * 8;
      const bhalf8 kh0 = *(const bhalf8*)(&KtH[cur][kr]);
      const bhalf8 kh1 = *(const bhalf8*)(&KtH[cur][kr + 32]);
      const float flag = mcur[nt] ? 1.0f : 0.0f;
      #pragma unroll
      for (int g = 0; g < 2; ++g) {
        f32x4 s = {};
        s = __builtin_amdgcn_mfma_f32_16x16x32_bf16(qfh[g][0], kh0, s, 0, 0, 0);
        s = __builtin_amdgcn_mfma_f32_16x16x32_bf16(qfh[g][1], kh1, s, 0, 0, 0);
        s = __builtin_amdgcn_mfma_f32_16x16x32_bf16(qfl[g][0], kh0, s, 0, 0, 0);
        s = __builtin_amdgcn_mfma_f32_16x16x32_bf16(qfl[g][1], kh1, s, 0, 0, 0);
        #pragma unroll
        for (int r = 0; r < 4; ++r) {
          const float p = flag * exp2f(s[r]);   // s pre-scaled by log2e
          lpart[g][r] += p;
          Pt[wave][(g * 16 + quad * 4 + r) * Ppt + nt * 16 + l16] = f2bf(p);
        }
      }
    }

    // O += P * Vh  (Pt per-wave: same-wave DS ordering, no barrier needed)
    #pragma unroll
    for (int kk = 0; kk < 2; ++kk) {
      const bhalf8 pa0 = *(const bhalf8*)(&Pt[wave][l16 * Ppt + kk * 32 + quad * 8]);
      const bhalf8 pa1 = *(const bhalf8*)(&Pt[wave][(16 + l16) * Ppt + kk * 32 + quad * 8]);
      #pragma unroll
      for (int dt = 0; dt < 4; ++dt) {
        const bhalf8 vb = *(const bhalf8*)(&VtH[cur][(dt * 16 + l16) * P + kk * 32 + quad * 8]);
        acc_o[0][dt] = __builtin_amdgcn_mfma_f32_16x16x32_bf16(pa0, vb, acc_o[0][dt], 0, 0, 0);
        acc_o[1][dt] = __builtin_amdgcn_mfma_f32_16x16x32_bf16(pa1, vb, acc_o[1][dt], 0, 0, 0);
      }
    }

    if (i < 31) {
      store_tile(cur ^ 1);             // tile i+1 into the other buffer
      if (i < 30) pref(kt + 128);      // tile i+2 in flight across barrier
      __syncthreads();                 // single barrier per iteration
      #pragma unroll
      for (int nt = 0; nt < 4; ++nt) mcur[nt] = mnext[nt];
    }
  }

  // final l reduction + normalize + store hi/lo into q-slice
  #pragma unroll
  for (int g = 0; g < 2; ++g)
    #pragma unroll
    for (int r = 0; r < 4; ++r) {
      float s = lpart[g][r];
      #pragma unroll
      for (int d = 1; d < 16; d <<= 1) s += __shfl_xor(s, d, 64);
      lpart[g][r] = s;
    }
  #pragma unroll
  for (int g = 0; g < 2; ++g)
    #pragma unroll
    for (int dt = 0; dt < 4; ++dt)
      #pragma unroll
      for (int r = 0; r < 4; ++r) {
        const int qrow = q0 + g * 16 + quad * 4 + r;
        const float inv = 1.0f / fmaxf(lpart[g][r], 1.0e-30f);
        const size_t off = (size_t)(b * kN + qrow) * k3C + h * kD + dt * 16 + l16;
        unsigned short hh, ll;
        split2(acc_o[g][dt][r] * inv, hh, ll);
        H[off] = hh; L[off] = ll;
      }
}

} // anonymous namespace

extern "C" void kernel_launch(void* const* d_in, const int* in_sizes, int n_in,
                              void* d_out, int out_size, void* d_ws, size_t ws_size,
                              hipStream_t stream)
{
  const float* x      = (const float*)d_in[0];
  const int*   maskp  = (const int*)d_in[1];
  const float* qkv_w  = (const float*)d_in[2];
  const float* qkv_b  = (const float*)d_in[3];
  const float* proj_w = (const float*)d_in[4];
  const float* proj_b = (const float*)d_in[5];
  const float* qn_w   = (const float*)d_in[6];
  const float* kn_w   = (const float*)d_in[7];
  float* out = (float*)d_out;

  unsigned short* qH = (unsigned short*)d_ws;      // qkv hi plane
  unsigned short* qL = qH + kPS;                   // qkv lo plane
  unsigned short* R1 = qL + kPS;                   // x planes -> later VT plane
  unsigned short* R2 = R1 + 2 * kXE;               // qkv_w planes -> later proj_w planes
  unsigned short* xH = R1,  *xL = R1 + kXE;
  unsigned short* VTH = R1;                        // reuse after gemm1
  unsigned short* wqH = R2, *wqL = R2 + kWQ;
  unsigned short* wpH = R2, *wpL = R2 + kWP;

  split_planes<<<(int)(kXE / 4 / 256), 256, 0, stream>>>(x, xH, xL, (int)(kXE / 4));
  split_planes<<<(int)(kWQ / 4 / 256), 256, 0, stream>>>(qkv_w, wqH, wqL, (int)(kWQ / 4));

  // 1) qkv = x @ qkv_w^T + qkv_b, RMSNorm(q,k) fused; lo written for q only
  //    256^2 pipelined kernel: grid (4096/256, 3072/256) = (16, 12)
  gemm_qkv256<<<dim3(kTok / 256, k3C / 256), 512, 0, stream>>>(
      xH, xL, wqH, wqL, qkv_b, qH, qL, qn_w, kn_w);

  // 2) pre-transpose V hi (overwrites x planes); pre-split proj_w
  vt_transpose<<<2048, 256, 0, stream>>>(qH, VTH);
  split_planes<<<(int)(kWP / 4 / 256), 256, 0, stream>>>(proj_w, wpH, wpL, (int)(kWP / 4));

  // 3) masked flash attention (XCD-swizzled 1-D grid, 512 blocks)
  attn_kernel<<<dim3(512), 256, 0, stream>>>(qH, qL, VTH, maskp);

  // 4) out = attn @ proj_w^T + proj_b
  gemm_planes<true, false><<<dim3(kTok / 128, kC / 128), 256, 0, stream>>>(
      qH, qL, k3C, wpH, wpL, proj_b, out, nullptr, nullptr, nullptr, nullptr, kC, kC);
}

// Round 7
// 294.158 us; speedup vs baseline: 1.0887x; 1.0404x over previous
//
#include <hip/hip_runtime.h>
#include <hip/hip_bf16.h>
#include <stdint.h>
#include <math.h>

namespace {

constexpr int kB = 2;
constexpr int kN = 2048;
constexpr int kC = 1024;
constexpr int kH = 16;
constexpr int kD = 64;
constexpr int kTok = kB * kN;               // 4096
constexpr int k3C  = 3 * kC;                // 3072
constexpr size_t kPS = (size_t)kTok * k3C;  // qkv plane elems
constexpr size_t kXE = (size_t)kTok * kC;   // x / VT plane elems
constexpr size_t kWQ = (size_t)k3C * kC;    // qkv_w elems
constexpr size_t kWP = (size_t)kC * kC;     // proj_w elems

using bhalf8 = __attribute__((ext_vector_type(8))) __bf16;
using f32x4  = __attribute__((ext_vector_type(4))) float;

__device__ inline unsigned short f2bf(float f) {
  __hip_bfloat16 h = __float2bfloat16(f);
  return *reinterpret_cast<unsigned short*>(&h);
}
__device__ inline float bf2f(unsigned short u) {
  __hip_bfloat16 h;
  *reinterpret_cast<unsigned short*>(&h) = u;
  return __bfloat162float(h);
}
__device__ inline void split2(float v, unsigned short& h, unsigned short& l) {
  const unsigned short hb = f2bf(v);
  h = hb;
  l = f2bf(v - bf2f(hb));
}

// raw hardware 2^x. __builtin_amdgcn_exp2f lowers to v_exp_f32 with the
// compiler inserting the required TRANS-result hazard waits (unlike inline
// asm). libm exp2f (round-6) took the precise OCML path: ~10 extra VALU
// ops x 32 exps/iter = the +10pt VALUBusy regression.
#if __has_builtin(__builtin_amdgcn_exp2f)
__device__ inline float fexp2(float x) { return __builtin_amdgcn_exp2f(x); }
#else
__device__ inline float fexp2(float x) { return __expf(x * 0.6931471805599453f); }
#endif

// async global->LDS, 16B per lane; LDS dest must be wave-uniform base + lane*16
__device__ inline void glds16(const unsigned short* g, unsigned short* l) {
  __builtin_amdgcn_global_load_lds(
      (const __attribute__((address_space(1))) void*)g,
      (__attribute__((address_space(3))) void*)l, 16, 0, 0);
}

// ---- split fp32 -> bf16 hi/lo planes ----
__global__ __launch_bounds__(256)
void split_planes(const float* __restrict__ src,
                  unsigned short* __restrict__ H,
                  unsigned short* __restrict__ L, int n4)
{
  const int i = blockIdx.x * 256 + threadIdx.x;
  if (i >= n4) return;
  const float4 v = ((const float4*)src)[i];
  ushort4 hh, ll;
  split2(v.x, hh.x, ll.x); split2(v.y, hh.y, ll.y);
  split2(v.z, hh.z, ll.z); split2(v.w, hh.w, ll.w);
  ((ushort4*)H)[i] = hh;
  ((ushort4*)L)[i] = ll;
}

// ---- pre-transpose V (hi plane only) into VT[bh][d][token] ----
__global__ __launch_bounds__(256)
void vt_transpose(const unsigned short* __restrict__ H,
                  unsigned short* __restrict__ VTH)
{
  const int gw   = blockIdx.x * 4 + (threadIdx.x >> 6);  // 0..8191
  const int lane = threadIdx.x & 63;                     // = d
  const int bh   = gw >> 8;
  const int oct  = gw & 255;
  const int b = bh >> 4, h = bh & 15;
  const int tok0 = oct * 8;
  union { unsigned short u[8]; uint4 v; } ph;
  #pragma unroll
  for (int e = 0; e < 8; ++e) {
    const size_t g = (size_t)(b * kN + tok0 + e) * k3C + 2 * kC + h * kD + lane;
    ph.u[e] = H[g];
  }
  *(uint4*)(&VTH[((size_t)bh * kD + lane) * kN + tok0]) = ph.v;
}

// ============================================================================
// QKV GEMM, 256x256 tile, 8 waves (2x4), BK=32, double-buffered LDS.
// Term-split 3-phase schedule (verified round 2): each phase consumes ONE
// staged plane unit; every vmcnt targets loads issued >=2 phases earlier.
// ============================================================================
__global__ __launch_bounds__(512)
void gemm_qkv256(const unsigned short* __restrict__ AH,
                 const unsigned short* __restrict__ AL,
                 const unsigned short* __restrict__ WH,
                 const unsigned short* __restrict__ WL,
                 const float* __restrict__ bias,
                 unsigned short* __restrict__ OutH,
                 unsigned short* __restrict__ OutL,
                 const float* __restrict__ qn,
                 const float* __restrict__ kn)
{
  constexpr int BK = 32;
  constexpr int NT = kC / BK;   // 32 K-tiles

  // [buf][plane(hi/lo)][256 rows x 32 cols u16] = 128 KiB total
  __shared__ __align__(16) unsigned short sA[2][2][256 * 32];
  __shared__ __align__(16) unsigned short sB[2][2][256 * 32];

  const int tt   = threadIdx.x;        // 0..511
  const int wave = tt >> 6;            // 0..7
  const int lane = tt & 63;
  const int quad = lane >> 4;
  const int l16  = lane & 15;
  const int bm = blockIdx.x * 256;
  const int bn = blockIdx.y * 256;
  const int wm = (wave >> 2) * 128;    // wave row: 0/128
  const int wn = (wave & 3) * 64;      // wave col: 0/64/128/192

  // staging geometry: unit u = r*512 + tt; row = u>>2; swizzled col-group
  int srow[2], scol[2];
  #pragma unroll
  for (int r = 0; r < 2; ++r) {
    const int u = r * 512 + tt;
    srow[r] = u >> 2;
    scol[r] = ((u & 3) ^ ((srow[r] >> 1) & 3)) * 8;
  }

  // unit: 0=AH 1=WH 2=WL 3=AL (issue order!)
  auto stageU = [&](int bf, int k0, int which) {
    const unsigned short* src = (which == 0) ? AH : (which == 1) ? WH
                              : (which == 2) ? WL : AL;
    const int base = (which == 0 || which == 3) ? bm : bn;
    unsigned short* dst = (which == 0) ? &sA[bf][0][0]
                        : (which == 3) ? &sA[bf][1][0]
                        : (which == 1) ? &sB[bf][0][0] : &sB[bf][1][0];
    #pragma unroll
    for (int r = 0; r < 2; ++r)
      glds16(&src[(size_t)(base + srow[r]) * kC + k0 + scol[r]],
             &dst[(r * 512 + tt) * 8]);
  };

  auto rdA = [&](int bf, int pl, int row) -> bhalf8 {
    return *(const bhalf8*)(&sA[bf][pl][row * 32 + ((quad ^ ((row >> 1) & 3)) * 8)]);
  };
  auto rdB = [&](int bf, int pl, int row) -> bhalf8 {
    return *(const bhalf8*)(&sB[bf][pl][row * 32 + ((quad ^ ((row >> 1) & 3)) * 8)]);
  };

  f32x4 acc[8][4] = {};
  bhalf8 ah[8], bh_[4], bl_[4];

  // ---- prologue: stage all 4 units of tile 0; wait AH0,WH0 ----
  stageU(0, 0, 0); stageU(0, 0, 1); stageU(0, 0, 2); stageU(0, 0, 3);
  asm volatile("s_waitcnt vmcnt(4)" ::: "memory");
  __builtin_amdgcn_sched_barrier(0);
  asm volatile("s_barrier" ::: "memory");

  for (int t = 0; t < NT - 1; ++t) {
    const int buf  = t & 1;
    const int nbuf = buf ^ 1;
    const int nk0  = (t + 1) * BK;

    // ---- P01: hh term ----
    #pragma unroll
    for (int i = 0; i < 8; ++i) ah[i]  = rdA(buf, 0, wm + i * 16 + l16);
    #pragma unroll
    for (int j = 0; j < 4; ++j) bh_[j] = rdB(buf, 0, wn + j * 16 + l16);
    stageU(nbuf, nk0, 0);                 // AH(t+1)
    stageU(nbuf, nk0, 1);                 // WH(t+1)
    asm volatile("s_waitcnt vmcnt(6)" ::: "memory");   // drain WL(t)
    __builtin_amdgcn_sched_barrier(0);
    asm volatile("s_barrier" ::: "memory");
    __builtin_amdgcn_s_setprio(1);
    #pragma unroll
    for (int i = 0; i < 8; ++i)
      #pragma unroll
      for (int j = 0; j < 4; ++j)
        acc[i][j] = __builtin_amdgcn_mfma_f32_16x16x32_bf16(ah[i], bh_[j], acc[i][j], 0, 0, 0);
    __builtin_amdgcn_s_setprio(0);

    // ---- P2: hl term ----
    #pragma unroll
    for (int j = 0; j < 4; ++j) bl_[j] = rdB(buf, 1, wn + j * 16 + l16);
    stageU(nbuf, nk0, 2);                 // WL(t+1)
    asm volatile("s_waitcnt vmcnt(6)" ::: "memory");   // drain AL(t)
    __builtin_amdgcn_sched_barrier(0);
    asm volatile("s_barrier" ::: "memory");
    __builtin_amdgcn_s_setprio(1);
    #pragma unroll
    for (int i = 0; i < 8; ++i)
      #pragma unroll
      for (int j = 0; j < 4; ++j)
        acc[i][j] = __builtin_amdgcn_mfma_f32_16x16x32_bf16(ah[i], bl_[j], acc[i][j], 0, 0, 0);
    __builtin_amdgcn_s_setprio(0);

    // ---- P3: lh term ----
    stageU(nbuf, nk0, 3);                 // AL(t+1)
    asm volatile("s_waitcnt vmcnt(4)" ::: "memory");   // drain AH,WH(t+1)
    __builtin_amdgcn_sched_barrier(0);
    asm volatile("s_barrier" ::: "memory");
    __builtin_amdgcn_s_setprio(1);
    {
      bhalf8 al0[4];
      #pragma unroll
      for (int i = 0; i < 4; ++i) al0[i] = rdA(buf, 1, wm + i * 16 + l16);
      #pragma unroll
      for (int i = 0; i < 4; ++i)
        #pragma unroll
        for (int j = 0; j < 4; ++j)
          acc[i][j] = __builtin_amdgcn_mfma_f32_16x16x32_bf16(al0[i], bh_[j], acc[i][j], 0, 0, 0);
      bhalf8 al1[4];
      #pragma unroll
      for (int i = 0; i < 4; ++i) al1[i] = rdA(buf, 1, wm + (4 + i) * 16 + l16);
      #pragma unroll
      for (int i = 0; i < 4; ++i)
        #pragma unroll
        for (int j = 0; j < 4; ++j)
          acc[4 + i][j] = __builtin_amdgcn_mfma_f32_16x16x32_bf16(al1[i], bh_[j], acc[4 + i][j], 0, 0, 0);
    }
    __builtin_amdgcn_s_setprio(0);
    asm volatile("s_barrier" ::: "memory");   // end-of-tile lockstep
  }

  // ---- peeled last tile (no prefetch) ----
  {
    const int buf = (NT - 1) & 1;
    #pragma unroll
    for (int i = 0; i < 8; ++i) ah[i]  = rdA(buf, 0, wm + i * 16 + l16);
    #pragma unroll
    for (int j = 0; j < 4; ++j) bh_[j] = rdB(buf, 0, wn + j * 16 + l16);
    __builtin_amdgcn_s_setprio(1);
    #pragma unroll
    for (int i = 0; i < 8; ++i)
      #pragma unroll
      for (int j = 0; j < 4; ++j)
        acc[i][j] = __builtin_amdgcn_mfma_f32_16x16x32_bf16(ah[i], bh_[j], acc[i][j], 0, 0, 0);
    __builtin_amdgcn_s_setprio(0);

    asm volatile("s_waitcnt vmcnt(2)" ::: "memory");   // drain WL(last)
    __builtin_amdgcn_sched_barrier(0);
    asm volatile("s_barrier" ::: "memory");
    #pragma unroll
    for (int j = 0; j < 4; ++j) bl_[j] = rdB(buf, 1, wn + j * 16 + l16);
    __builtin_amdgcn_s_setprio(1);
    #pragma unroll
    for (int i = 0; i < 8; ++i)
      #pragma unroll
      for (int j = 0; j < 4; ++j)
        acc[i][j] = __builtin_amdgcn_mfma_f32_16x16x32_bf16(ah[i], bl_[j], acc[i][j], 0, 0, 0);
    __builtin_amdgcn_s_setprio(0);

    asm volatile("s_waitcnt vmcnt(0)" ::: "memory");   // drain AL(last)
    __builtin_amdgcn_sched_barrier(0);
    asm volatile("s_barrier" ::: "memory");
    __builtin_amdgcn_s_setprio(1);
    {
      bhalf8 al0[4];
      #pragma unroll
      for (int i = 0; i < 4; ++i) al0[i] = rdA(buf, 1, wm + i * 16 + l16);
      #pragma unroll
      for (int i = 0; i < 4; ++i)
        #pragma unroll
        for (int j = 0; j < 4; ++j)
          acc[i][j] = __builtin_amdgcn_mfma_f32_16x16x32_bf16(al0[i], bh_[j], acc[i][j], 0, 0, 0);
      bhalf8 al1[4];
      #pragma unroll
      for (int i = 0; i < 4; ++i) al1[i] = rdA(buf, 1, wm + (4 + i) * 16 + l16);
      #pragma unroll
      for (int i = 0; i < 4; ++i)
        #pragma unroll
        for (int j = 0; j < 4; ++j)
          acc[4 + i][j] = __builtin_amdgcn_mfma_f32_16x16x32_bf16(al1[i], bh_[j], acc[4 + i][j], 0, 0, 0);
    }
    __builtin_amdgcn_s_setprio(0);
  }

  // epilogue: C/D layout col=lane&15, row=quad*4+reg; fused RMSNorm on q,k
  const int slice = bn >> 10;          // 0=q,1=k,2=v (bn multiple of 256)
  const bool writeL = (slice == 0);
  float bv[4], wv[4];
  #pragma unroll
  for (int j = 0; j < 4; ++j) {
    bv[j] = bias[bn + wn + j * 16 + l16];
    if (slice < 2) wv[j] = (slice ? kn : qn)[j * 16 + l16];  // d = j*16+l16
  }

  #pragma unroll
  for (int i = 0; i < 8; ++i) {
    float val[4][4];
    #pragma unroll
    for (int j = 0; j < 4; ++j)
      #pragma unroll
      for (int r = 0; r < 4; ++r)
        val[j][r] = acc[i][j][r] + bv[j];

    if (slice < 2) {
      #pragma unroll
      for (int r = 0; r < 4; ++r) {
        float ss = val[0][r] * val[0][r];
        #pragma unroll
        for (int j = 1; j < 4; ++j) ss += val[j][r] * val[j][r];
        #pragma unroll
        for (int d = 1; d < 16; d <<= 1) ss += __shfl_xor(ss, d, 64);
        float rinv = rsqrtf(ss * (1.0f / 64.0f) + 1e-6f);
        // q * D^-0.5 * log2(e): attn uses hardware 2^x
        if (slice == 0) rinv *= 0.18033688011112042f;
        #pragma unroll
        for (int j = 0; j < 4; ++j) val[j][r] = wv[j] * (val[j][r] * rinv);
      }
    }

    #pragma unroll
    for (int j = 0; j < 4; ++j) {
      const int n = bn + wn + j * 16 + l16;
      #pragma unroll
      for (int r = 0; r < 4; ++r) {
        const int m = bm + wm + i * 16 + quad * 4 + r;
        unsigned short hh, ll;
        split2(val[j][r], hh, ll);
        OutH[(size_t)m * k3C + n] = hh;
        if (writeL) OutL[(size_t)m * k3C + n] = ll;
      }
    }
  }
}

// ---- plane GEMM (128^2, m97-structure): kept for the proj projection ----
template<bool OUTF32, bool FUSE_NORM>
__global__ __launch_bounds__(256)
void gemm_planes(const unsigned short* __restrict__ AH,
                 const unsigned short* __restrict__ AL, int lda,
                 const unsigned short* __restrict__ WH,
                 const unsigned short* __restrict__ WL,
                 const float* __restrict__ bias,
                 float* __restrict__ OutF,
                 unsigned short* __restrict__ OutH,
                 unsigned short* __restrict__ OutL,
                 const float* __restrict__ qn,
                 const float* __restrict__ kn,
                 int Nn, int K)
{
  __shared__ __align__(16) unsigned short AsH[128 * 32], AsL[128 * 32];
  __shared__ __align__(16) unsigned short BsH[128 * 32], BsL[128 * 32];

  const int t    = threadIdx.x;
  const int wave = t >> 6;
  const int lane = t & 63;
  const int quad = lane >> 4;
  const int l16  = lane & 15;
  const int bm = blockIdx.x * 128;
  const int bn = blockIdx.y * 128;
  const int wm = (wave >> 1) * 64;
  const int wn = (wave & 1) * 64;

  f32x4 acc[4][4] = {};

  for (int k0 = 0; k0 < K; k0 += 32) {
    #pragma unroll
    for (int r = 0; r < 2; ++r) {
      const int c   = r * 256 + t;
      const int row = c >> 2;
      const int col = (c & 3) * 8;
      glds16(&AH[(size_t)(bm + row) * lda + k0 + col], &AsH[c * 8]);
      glds16(&AL[(size_t)(bm + row) * lda + k0 + col], &AsL[c * 8]);
      glds16(&WH[(size_t)(bn + row) * K + k0 + col], &BsH[c * 8]);
      glds16(&WL[(size_t)(bn + row) * K + k0 + col], &BsL[c * 8]);
    }
    __syncthreads();

    bhalf8 afh[4], afl[4], bgh[4], bgl[4];
    #pragma unroll
    for (int i = 0; i < 4; ++i) {
      afh[i] = *(const bhalf8*)(&AsH[(wm + i * 16 + l16) * 32 + quad * 8]);
      afl[i] = *(const bhalf8*)(&AsL[(wm + i * 16 + l16) * 32 + quad * 8]);
      bgh[i] = *(const bhalf8*)(&BsH[(wn + i * 16 + l16) * 32 + quad * 8]);
      bgl[i] = *(const bhalf8*)(&BsL[(wn + i * 16 + l16) * 32 + quad * 8]);
    }
    #pragma unroll
    for (int i = 0; i < 4; ++i)
      #pragma unroll
      for (int j = 0; j < 4; ++j) {
        f32x4 a = acc[i][j];
        a = __builtin_amdgcn_mfma_f32_16x16x32_bf16(afh[i], bgh[j], a, 0, 0, 0);
        a = __builtin_amdgcn_mfma_f32_16x16x32_bf16(afh[i], bgl[j], a, 0, 0, 0);
        a = __builtin_amdgcn_mfma_f32_16x16x32_bf16(afl[i], bgh[j], a, 0, 0, 0);
        acc[i][j] = a;
      }
    __syncthreads();
  }

  // epilogue: C/D layout col=lane&15, row=quad*4+reg
  float bv[4], wv[4];
  const int slice = FUSE_NORM ? (bn >> 10) : 0;   // 0=q,1=k,2=v
  const bool writeL = !FUSE_NORM || slice == 0;
  #pragma unroll
  for (int j = 0; j < 4; ++j) {
    bv[j] = bias[bn + wn + j * 16 + l16];
    if (FUSE_NORM && slice < 2)
      wv[j] = (slice ? kn : qn)[j * 16 + l16];    // d = j*16+l16
  }

  #pragma unroll
  for (int i = 0; i < 4; ++i) {
    float val[4][4];
    #pragma unroll
    for (int j = 0; j < 4; ++j)
      #pragma unroll
      for (int r = 0; r < 4; ++r)
        val[j][r] = acc[i][j][r] + bv[j];

    if (FUSE_NORM && slice < 2) {
      #pragma unroll
      for (int r = 0; r < 4; ++r) {
        float ss = val[0][r] * val[0][r];
        #pragma unroll
        for (int j = 1; j < 4; ++j) ss += val[j][r] * val[j][r];
        #pragma unroll
        for (int d = 1; d < 16; d <<= 1) ss += __shfl_xor(ss, d, 64);
        float rinv = rsqrtf(ss * (1.0f / 64.0f) + 1e-6f);
        if (slice == 0) rinv *= 0.125f;           // q * D^-0.5
        #pragma unroll
        for (int j = 0; j < 4; ++j) val[j][r] = wv[j] * (val[j][r] * rinv);
      }
    }

    #pragma unroll
    for (int j = 0; j < 4; ++j) {
      const int n = bn + wn + j * 16 + l16;
      #pragma unroll
      for (int r = 0; r < 4; ++r) {
        const int m = bm + wm + i * 16 + quad * 4 + r;
        if (OUTF32) {
          OutF[(size_t)m * Nn + n] = val[j][r];
        } else {
          unsigned short hh, ll;
          split2(val[j][r], hh, ll);
          OutH[(size_t)m * Nn + n] = hh;
          if (writeL) OutL[(size_t)m * Nn + n] = ll;
        }
      }
    }
  }
}

// ---- flash attention v11: round-6 structure (dbuf K/V, one barrier/iter,
// Pt pitch 68) with hardware v_exp_f32 via builtin (round-6's libm exp2f
// cost +10pt VALUBusy). ----
__global__ __launch_bounds__(256)
void attn_kernel(unsigned short* __restrict__ H, unsigned short* __restrict__ L,
                 const unsigned short* __restrict__ VTH,
                 const int* __restrict__ mask)
{
  constexpr int P   = 72;  // K/V pitch: bank-start 4*((row+col16)%8) — balanced
  constexpr int Ppt = 68;  // Pt pitch: quad groups land on distinct banks
  __shared__ __align__(16) unsigned short KtH[2][64 * P];   // 18.4 KB dbuf
  __shared__ __align__(16) unsigned short VtH[2][64 * P];   // 18.4 KB dbuf
  __shared__ __align__(16) unsigned short Pt[4][32 * Ppt];  // 17.4 KB per-wave

  const int t    = threadIdx.x;
  const int wave = t >> 6;
  const int lane = t & 63;
  const int quad = lane >> 4;
  const int l16  = lane & 15;

  // XCD swizzle: lin%8 = XCD (dispatch round-robin); 4 bh per XCD.
  const int lin  = blockIdx.x;          // 0..511
  const int xcd  = lin & 7;
  const int slot = lin >> 3;            // 0..63
  const int bh   = xcd + 8 * (slot >> 4);
  const int qblk = slot & 15;
  const int b  = bh >> 4;
  const int h  = bh & 15;
  const int q0 = qblk * 128 + wave * 32;  // 32 q-rows/wave

  // staging geometry: 2 chunks of 8 u16 per thread per tile
  const int row0 = t >> 3,         col0 = (t & 7) * 8;
  const int row1 = (256 + t) >> 3, col1 = ((256 + t) & 7) * 8;

  // Q fragments, both groups (A-layout: m=l16, k=quad*8+j)
  bhalf8 qfh[2][2], qfl[2][2];
  #pragma unroll
  for (int g = 0; g < 2; ++g) {
    const size_t qrow = (size_t)(b * kN + q0 + g * 16 + l16) * k3C + h * kD;
    qfh[g][0] = *(const bhalf8*)(&H[qrow + quad * 8]);
    qfh[g][1] = *(const bhalf8*)(&H[qrow + 32 + quad * 8]);
    qfl[g][0] = *(const bhalf8*)(&L[qrow + quad * 8]);
    qfl[g][1] = *(const bhalf8*)(&L[qrow + 32 + quad * 8]);
  }

  f32x4 acc_o[2][4] = {};
  float lpart[2][4] = {};

  uint4 sk0, sk1, sv0, sv1;            // staging regs
  int mcur[4], mnext[4];

  auto pref = [&](int kt) {
    sk0 = *(const uint4*)(&H[(size_t)(b * kN + kt + row0) * k3C + kC + h * kD + col0]);
    sk1 = *(const uint4*)(&H[(size_t)(b * kN + kt + row1) * k3C + kC + h * kD + col1]);
    sv0 = *(const uint4*)(&VTH[((size_t)bh * kD + row0) * kN + kt + col0]);
    sv1 = *(const uint4*)(&VTH[((size_t)bh * kD + row1) * kN + kt + col1]);
  };
  auto store_tile = [&](int bf) {
    *(uint4*)(&KtH[bf][row0 * P + col0]) = sk0;
    *(uint4*)(&KtH[bf][row1 * P + col1]) = sk1;
    *(uint4*)(&VtH[bf][row0 * P + col0]) = sv0;
    *(uint4*)(&VtH[bf][row1 * P + col1]) = sv1;
  };
  auto loadM = [&](int kt, int* m) {
    #pragma unroll
    for (int nt = 0; nt < 4; ++nt) m[nt] = mask[b * kN + kt + nt * 16 + l16];
  };

  // prologue: tile 0 -> buf0; issue tile 1 loads; one barrier
  pref(0);
  loadM(0, mcur);
  #pragma unroll
  for (int nt = 0; nt < 4; ++nt) mnext[nt] = mcur[nt];
  store_tile(0);                       // compiler inserts vmcnt for sk/sv deps
  pref(64);                            // tile 1 in flight across the barrier
  __syncthreads();

  for (int i = 0; i < 32; ++i) {
    const int cur = i & 1;
    const int kt = i * 64;
    if (i < 31) loadM(kt + 64, mnext);

    // S = (Qh+Ql)Kh ; p = flag*2^s -> Pt (C-layout -> A-layout)
    #pragma unroll
    for (int nt = 0; nt < 4; ++nt) {
      const int kr = (nt * 16 + l16) * P + quad * 8;
      const bhalf8 kh0 = *(const bhalf8*)(&KtH[cur][kr]);
      const bhalf8 kh1 = *(const bhalf8*)(&KtH[cur][kr + 32]);
      const float flag = mcur[nt] ? 1.0f : 0.0f;
      #pragma unroll
      for (int g = 0; g < 2; ++g) {
        f32x4 s = {};
        s = __builtin_amdgcn_mfma_f32_16x16x32_bf16(qfh[g][0], kh0, s, 0, 0, 0);
        s = __builtin_amdgcn_mfma_f32_16x16x32_bf16(qfh[g][1], kh1, s, 0, 0, 0);
        s = __builtin_amdgcn_mfma_f32_16x16x32_bf16(qfl[g][0], kh0, s, 0, 0, 0);
        s = __builtin_amdgcn_mfma_f32_16x16x32_bf16(qfl[g][1], kh1, s, 0, 0, 0);
        #pragma unroll
        for (int r = 0; r < 4; ++r) {
          const float p = flag * fexp2(s[r]);   // s pre-scaled by log2e
          lpart[g][r] += p;
          Pt[wave][(g * 16 + quad * 4 + r) * Ppt + nt * 16 + l16] = f2bf(p);
        }
      }
    }

    // O += P * Vh  (Pt per-wave: same-wave DS ordering, no barrier needed)
    #pragma unroll
    for (int kk = 0; kk < 2; ++kk) {
      const bhalf8 pa0 = *(const bhalf8*)(&Pt[wave][l16 * Ppt + kk * 32 + quad * 8]);
      const bhalf8 pa1 = *(const bhalf8*)(&Pt[wave][(16 + l16) * Ppt + kk * 32 + quad * 8]);
      #pragma unroll
      for (int dt = 0; dt < 4; ++dt) {
        const bhalf8 vb = *(const bhalf8*)(&VtH[cur][(dt * 16 + l16) * P + kk * 32 + quad * 8]);
        acc_o[0][dt] = __builtin_amdgcn_mfma_f32_16x16x32_bf16(pa0, vb, acc_o[0][dt], 0, 0, 0);
        acc_o[1][dt] = __builtin_amdgcn_mfma_f32_16x16x32_bf16(pa1, vb, acc_o[1][dt], 0, 0, 0);
      }
    }

    if (i < 31) {
      store_tile(cur ^ 1);             // tile i+1 into the other buffer
      if (i < 30) pref(kt + 128);      // tile i+2 in flight across barrier
      __syncthreads();                 // single barrier per iteration
      #pragma unroll
      for (int nt = 0; nt < 4; ++nt) mcur[nt] = mnext[nt];
    }
  }

  // final l reduction + normalize + store hi/lo into q-slice
  #pragma unroll
  for (int g = 0; g < 2; ++g)
    #pragma unroll
    for (int r = 0; r < 4; ++r) {
      float s = lpart[g][r];
      #pragma unroll
      for (int d = 1; d < 16; d <<= 1) s += __shfl_xor(s, d, 64);
      lpart[g][r] = s;
    }
  #pragma unroll
  for (int g = 0; g < 2; ++g)
    #pragma unroll
    for (int dt = 0; dt < 4; ++dt)
      #pragma unroll
      for (int r = 0; r < 4; ++r) {
        const int qrow = q0 + g * 16 + quad * 4 + r;
        const float inv = 1.0f / fmaxf(lpart[g][r], 1.0e-30f);
        const size_t off = (size_t)(b * kN + qrow) * k3C + h * kD + dt * 16 + l16;
        unsigned short hh, ll;
        split2(acc_o[g][dt][r] * inv, hh, ll);
        H[off] = hh; L[off] = ll;
      }
}

} // anonymous namespace

extern "C" void kernel_launch(void* const* d_in, const int* in_sizes, int n_in,
                              void* d_out, int out_size, void* d_ws, size_t ws_size,
                              hipStream_t stream)
{
  const float* x      = (const float*)d_in[0];
  const int*   maskp  = (const int*)d_in[1];
  const float* qkv_w  = (const float*)d_in[2];
  const float* qkv_b  = (const float*)d_in[3];
  const float* proj_w = (const float*)d_in[4];
  const float* proj_b = (const float*)d_in[5];
  const float* qn_w   = (const float*)d_in[6];
  const float* kn_w   = (const float*)d_in[7];
  float* out = (float*)d_out;

  unsigned short* qH = (unsigned short*)d_ws;      // qkv hi plane
  unsigned short* qL = qH + kPS;                   // qkv lo plane
  unsigned short* R1 = qL + kPS;                   // x planes -> later VT plane
  unsigned short* R2 = R1 + 2 * kXE;               // qkv_w planes -> later proj_w planes
  unsigned short* xH = R1,  *xL = R1 + kXE;
  unsigned short* VTH = R1;                        // reuse after gemm1
  unsigned short* wqH = R2, *wqL = R2 + kWQ;
  unsigned short* wpH = R2, *wpL = R2 + kWP;

  split_planes<<<(int)(kXE / 4 / 256), 256, 0, stream>>>(x, xH, xL, (int)(kXE / 4));
  split_planes<<<(int)(kWQ / 4 / 256), 256, 0, stream>>>(qkv_w, wqH, wqL, (int)(kWQ / 4));

  // 1) qkv = x @ qkv_w^T + qkv_b, RMSNorm(q,k) fused; lo written for q only
  //    256^2 pipelined kernel: grid (4096/256, 3072/256) = (16, 12)
  gemm_qkv256<<<dim3(kTok / 256, k3C / 256), 512, 0, stream>>>(
      xH, xL, wqH, wqL, qkv_b, qH, qL, qn_w, kn_w);

  // 2) pre-transpose V hi (overwrites x planes); pre-split proj_w
  vt_transpose<<<2048, 256, 0, stream>>>(qH, VTH);
  split_planes<<<(int)(kWP / 4 / 256), 256, 0, stream>>>(proj_w, wpH, wpL, (int)(kWP / 4));

  // 3) masked flash attention (XCD-swizzled 1-D grid, 512 blocks)
  attn_kernel<<<dim3(512), 256, 0, stream>>>(qH, qL, VTH, maskp);

  // 4) out = attn @ proj_w^T + proj_b
  gemm_planes<true, false><<<dim3(kTok / 128, kC / 128), 256, 0, stream>>>(
      qH, qL, k3C, wpH, wpL, proj_b, out, nullptr, nullptr, nullptr, nullptr, kC, kC);
}

// Round 8
// 289.372 us; speedup vs baseline: 1.1067x; 1.0165x over previous
//
#include <hip/hip_runtime.h>
#include <hip/hip_bf16.h>
#include <stdint.h>
#include <math.h>

namespace {

constexpr int kB = 2;
constexpr int kN = 2048;
constexpr int kC = 1024;
constexpr int kH = 16;
constexpr int kD = 64;
constexpr int kTok = kB * kN;               // 4096
constexpr int k3C  = 3 * kC;                // 3072
constexpr size_t kPS = (size_t)kTok * k3C;  // qkv plane elems
constexpr size_t kXE = (size_t)kTok * kC;   // x / VT plane elems
constexpr size_t kWQ = (size_t)k3C * kC;    // qkv_w elems
constexpr size_t kWP = (size_t)kC * kC;     // proj_w elems

using bhalf8 = __attribute__((ext_vector_type(8))) __bf16;
using f32x4  = __attribute__((ext_vector_type(4))) float;

__device__ inline unsigned short f2bf(float f) {
  __hip_bfloat16 h = __float2bfloat16(f);
  return *reinterpret_cast<unsigned short*>(&h);
}
__device__ inline float bf2f(unsigned short u) {
  __hip_bfloat16 h;
  *reinterpret_cast<unsigned short*>(&h) = u;
  return __bfloat162float(h);
}
__device__ inline void split2(float v, unsigned short& h, unsigned short& l) {
  const unsigned short hb = f2bf(v);
  h = hb;
  l = f2bf(v - bf2f(hb));
}

// raw hardware 2^x (compiler-managed TRANS hazards). Verified round 7:
// libm exp2f's OCML path cost +10pt VALUBusy / +10us on attn.
#if __has_builtin(__builtin_amdgcn_exp2f)
__device__ inline float fexp2(float x) { return __builtin_amdgcn_exp2f(x); }
#else
__device__ inline float fexp2(float x) { return __expf(x * 0.6931471805599453f); }
#endif

// async global->LDS, 16B per lane; LDS dest must be wave-uniform base + lane*16
__device__ inline void glds16(const unsigned short* g, unsigned short* l) {
  __builtin_amdgcn_global_load_lds(
      (const __attribute__((address_space(1))) void*)g,
      (__attribute__((address_space(3))) void*)l, 16, 0, 0);
}

__device__ inline void split4(const float4 v, ushort4& hh, ushort4& ll) {
  split2(v.x, hh.x, ll.x); split2(v.y, hh.y, ll.y);
  split2(v.z, hh.z, ll.z); split2(v.w, hh.w, ll.w);
}

// ---- fused prep: split x AND qkv_w fp32 -> bf16 hi/lo planes (1 launch) ----
// Region boundaries are block-aligned: x = 4096 blocks, qkv_w = 3072 blocks.
__global__ __launch_bounds__(256)
void prep_split(const float* __restrict__ x, const float* __restrict__ wq,
                unsigned short* __restrict__ xH, unsigned short* __restrict__ xL,
                unsigned short* __restrict__ wqH, unsigned short* __restrict__ wqL)
{
  constexpr int nX = (int)(kXE / 4);       // 1048576 f4 units (4096 blocks)
  int i = blockIdx.x * 256 + threadIdx.x;
  const float* src;
  unsigned short *H, *L;
  if (i < nX) { src = x;  H = xH;  L = xL; }
  else        { i -= nX; src = wq; H = wqH; L = wqL; }
  const float4 v = ((const float4*)src)[i];
  ushort4 hh, ll;
  split4(v, hh, ll);
  ((ushort4*)H)[i] = hh;
  ((ushort4*)L)[i] = ll;
}

// ---- fused: V^T pre-transpose (blocks 0..2047) + proj_w split (2048..3071) ----
// proj_w planes overwrite the (now-dead) qkv_w planes — gemm1 has completed.
__global__ __launch_bounds__(256)
void vt_and_split(const unsigned short* __restrict__ H,
                  unsigned short* __restrict__ VTH,
                  const float* __restrict__ wp,
                  unsigned short* __restrict__ wpH,
                  unsigned short* __restrict__ wpL)
{
  if (blockIdx.x < 2048) {
    const int gw   = blockIdx.x * 4 + (threadIdx.x >> 6);  // 0..8191
    const int lane = threadIdx.x & 63;                     // = d
    const int bh   = gw >> 8;
    const int oct  = gw & 255;
    const int b = bh >> 4, h = bh & 15;
    const int tok0 = oct * 8;
    union { unsigned short u[8]; uint4 v; } ph;
    #pragma unroll
    for (int e = 0; e < 8; ++e) {
      const size_t g = (size_t)(b * kN + tok0 + e) * k3C + 2 * kC + h * kD + lane;
      ph.u[e] = H[g];
    }
    *(uint4*)(&VTH[((size_t)bh * kD + lane) * kN + tok0]) = ph.v;
  } else {
    const int i = (blockIdx.x - 2048) * 256 + threadIdx.x;  // < kWP/4 = 262144
    const float4 v = ((const float4*)wp)[i];
    ushort4 hh, ll;
    split4(v, hh, ll);
    ((ushort4*)wpH)[i] = hh;
    ((ushort4*)wpL)[i] = ll;
  }
}

// ============================================================================
// QKV GEMM, 256x256 tile, 8 waves (2x4), BK=32, double-buffered LDS.
// Term-split 3-phase schedule (verified round 2): each phase consumes ONE
// staged plane unit; every vmcnt targets loads issued >=2 phases earlier.
// At 897 TF effective (3-term), this is the coarse-phase structure ceiling.
// ============================================================================
__global__ __launch_bounds__(512)
void gemm_qkv256(const unsigned short* __restrict__ AH,
                 const unsigned short* __restrict__ AL,
                 const unsigned short* __restrict__ WH,
                 const unsigned short* __restrict__ WL,
                 const float* __restrict__ bias,
                 unsigned short* __restrict__ OutH,
                 unsigned short* __restrict__ OutL,
                 const float* __restrict__ qn,
                 const float* __restrict__ kn)
{
  constexpr int BK = 32;
  constexpr int NT = kC / BK;   // 32 K-tiles

  // [buf][plane(hi/lo)][256 rows x 32 cols u16] = 128 KiB total
  __shared__ __align__(16) unsigned short sA[2][2][256 * 32];
  __shared__ __align__(16) unsigned short sB[2][2][256 * 32];

  const int tt   = threadIdx.x;        // 0..511
  const int wave = tt >> 6;            // 0..7
  const int lane = tt & 63;
  const int quad = lane >> 4;
  const int l16  = lane & 15;
  const int bm = blockIdx.x * 256;
  const int bn = blockIdx.y * 256;
  const int wm = (wave >> 2) * 128;    // wave row: 0/128
  const int wn = (wave & 3) * 64;      // wave col: 0/64/128/192

  // staging geometry: unit u = r*512 + tt; row = u>>2; swizzled col-group
  int srow[2], scol[2];
  #pragma unroll
  for (int r = 0; r < 2; ++r) {
    const int u = r * 512 + tt;
    srow[r] = u >> 2;
    scol[r] = ((u & 3) ^ ((srow[r] >> 1) & 3)) * 8;
  }

  // unit: 0=AH 1=WH 2=WL 3=AL (issue order!)
  auto stageU = [&](int bf, int k0, int which) {
    const unsigned short* src = (which == 0) ? AH : (which == 1) ? WH
                              : (which == 2) ? WL : AL;
    const int base = (which == 0 || which == 3) ? bm : bn;
    unsigned short* dst = (which == 0) ? &sA[bf][0][0]
                        : (which == 3) ? &sA[bf][1][0]
                        : (which == 1) ? &sB[bf][0][0] : &sB[bf][1][0];
    #pragma unroll
    for (int r = 0; r < 2; ++r)
      glds16(&src[(size_t)(base + srow[r]) * kC + k0 + scol[r]],
             &dst[(r * 512 + tt) * 8]);
  };

  auto rdA = [&](int bf, int pl, int row) -> bhalf8 {
    return *(const bhalf8*)(&sA[bf][pl][row * 32 + ((quad ^ ((row >> 1) & 3)) * 8)]);
  };
  auto rdB = [&](int bf, int pl, int row) -> bhalf8 {
    return *(const bhalf8*)(&sB[bf][pl][row * 32 + ((quad ^ ((row >> 1) & 3)) * 8)]);
  };

  f32x4 acc[8][4] = {};
  bhalf8 ah[8], bh_[4], bl_[4];

  // ---- prologue: stage all 4 units of tile 0; wait AH0,WH0 ----
  stageU(0, 0, 0); stageU(0, 0, 1); stageU(0, 0, 2); stageU(0, 0, 3);
  asm volatile("s_waitcnt vmcnt(4)" ::: "memory");
  __builtin_amdgcn_sched_barrier(0);
  asm volatile("s_barrier" ::: "memory");

  for (int t = 0; t < NT - 1; ++t) {
    const int buf  = t & 1;
    const int nbuf = buf ^ 1;
    const int nk0  = (t + 1) * BK;

    // ---- P01: hh term ----
    #pragma unroll
    for (int i = 0; i < 8; ++i) ah[i]  = rdA(buf, 0, wm + i * 16 + l16);
    #pragma unroll
    for (int j = 0; j < 4; ++j) bh_[j] = rdB(buf, 0, wn + j * 16 + l16);
    stageU(nbuf, nk0, 0);                 // AH(t+1)
    stageU(nbuf, nk0, 1);                 // WH(t+1)
    asm volatile("s_waitcnt vmcnt(6)" ::: "memory");   // drain WL(t)
    __builtin_amdgcn_sched_barrier(0);
    asm volatile("s_barrier" ::: "memory");
    __builtin_amdgcn_s_setprio(1);
    #pragma unroll
    for (int i = 0; i < 8; ++i)
      #pragma unroll
      for (int j = 0; j < 4; ++j)
        acc[i][j] = __builtin_amdgcn_mfma_f32_16x16x32_bf16(ah[i], bh_[j], acc[i][j], 0, 0, 0);
    __builtin_amdgcn_s_setprio(0);

    // ---- P2: hl term ----
    #pragma unroll
    for (int j = 0; j < 4; ++j) bl_[j] = rdB(buf, 1, wn + j * 16 + l16);
    stageU(nbuf, nk0, 2);                 // WL(t+1)
    asm volatile("s_waitcnt vmcnt(6)" ::: "memory");   // drain AL(t)
    __builtin_amdgcn_sched_barrier(0);
    asm volatile("s_barrier" ::: "memory");
    __builtin_amdgcn_s_setprio(1);
    #pragma unroll
    for (int i = 0; i < 8; ++i)
      #pragma unroll
      for (int j = 0; j < 4; ++j)
        acc[i][j] = __builtin_amdgcn_mfma_f32_16x16x32_bf16(ah[i], bl_[j], acc[i][j], 0, 0, 0);
    __builtin_amdgcn_s_setprio(0);

    // ---- P3: lh term ----
    stageU(nbuf, nk0, 3);                 // AL(t+1)
    asm volatile("s_waitcnt vmcnt(4)" ::: "memory");   // drain AH,WH(t+1)
    __builtin_amdgcn_sched_barrier(0);
    asm volatile("s_barrier" ::: "memory");
    __builtin_amdgcn_s_setprio(1);
    {
      bhalf8 al0[4];
      #pragma unroll
      for (int i = 0; i < 4; ++i) al0[i] = rdA(buf, 1, wm + i * 16 + l16);
      #pragma unroll
      for (int i = 0; i < 4; ++i)
        #pragma unroll
        for (int j = 0; j < 4; ++j)
          acc[i][j] = __builtin_amdgcn_mfma_f32_16x16x32_bf16(al0[i], bh_[j], acc[i][j], 0, 0, 0);
      bhalf8 al1[4];
      #pragma unroll
      for (int i = 0; i < 4; ++i) al1[i] = rdA(buf, 1, wm + (4 + i) * 16 + l16);
      #pragma unroll
      for (int i = 0; i < 4; ++i)
        #pragma unroll
        for (int j = 0; j < 4; ++j)
          acc[4 + i][j] = __builtin_amdgcn_mfma_f32_16x16x32_bf16(al1[i], bh_[j], acc[4 + i][j], 0, 0, 0);
    }
    __builtin_amdgcn_s_setprio(0);
    asm volatile("s_barrier" ::: "memory");   // end-of-tile lockstep
  }

  // ---- peeled last tile (no prefetch) ----
  {
    const int buf = (NT - 1) & 1;
    #pragma unroll
    for (int i = 0; i < 8; ++i) ah[i]  = rdA(buf, 0, wm + i * 16 + l16);
    #pragma unroll
    for (int j = 0; j < 4; ++j) bh_[j] = rdB(buf, 0, wn + j * 16 + l16);
    __builtin_amdgcn_s_setprio(1);
    #pragma unroll
    for (int i = 0; i < 8; ++i)
      #pragma unroll
      for (int j = 0; j < 4; ++j)
        acc[i][j] = __builtin_amdgcn_mfma_f32_16x16x32_bf16(ah[i], bh_[j], acc[i][j], 0, 0, 0);
    __builtin_amdgcn_s_setprio(0);

    asm volatile("s_waitcnt vmcnt(2)" ::: "memory");   // drain WL(last)
    __builtin_amdgcn_sched_barrier(0);
    asm volatile("s_barrier" ::: "memory");
    #pragma unroll
    for (int j = 0; j < 4; ++j) bl_[j] = rdB(buf, 1, wn + j * 16 + l16);
    __builtin_amdgcn_s_setprio(1);
    #pragma unroll
    for (int i = 0; i < 8; ++i)
      #pragma unroll
      for (int j = 0; j < 4; ++j)
        acc[i][j] = __builtin_amdgcn_mfma_f32_16x16x32_bf16(ah[i], bl_[j], acc[i][j], 0, 0, 0);
    __builtin_amdgcn_s_setprio(0);

    asm volatile("s_waitcnt vmcnt(0)" ::: "memory");   // drain AL(last)
    __builtin_amdgcn_sched_barrier(0);
    asm volatile("s_barrier" ::: "memory");
    __builtin_amdgcn_s_setprio(1);
    {
      bhalf8 al0[4];
      #pragma unroll
      for (int i = 0; i < 4; ++i) al0[i] = rdA(buf, 1, wm + i * 16 + l16);
      #pragma unroll
      for (int i = 0; i < 4; ++i)
        #pragma unroll
        for (int j = 0; j < 4; ++j)
          acc[i][j] = __builtin_amdgcn_mfma_f32_16x16x32_bf16(al0[i], bh_[j], acc[i][j], 0, 0, 0);
      bhalf8 al1[4];
      #pragma unroll
      for (int i = 0; i < 4; ++i) al1[i] = rdA(buf, 1, wm + (4 + i) * 16 + l16);
      #pragma unroll
      for (int i = 0; i < 4; ++i)
        #pragma unroll
        for (int j = 0; j < 4; ++j)
          acc[4 + i][j] = __builtin_amdgcn_mfma_f32_16x16x32_bf16(al1[i], bh_[j], acc[4 + i][j], 0, 0, 0);
    }
    __builtin_amdgcn_s_setprio(0);
  }

  // epilogue: C/D layout col=lane&15, row=quad*4+reg; fused RMSNorm on q,k
  const int slice = bn >> 10;          // 0=q,1=k,2=v (bn multiple of 256)
  const bool writeL = (slice == 0);
  float bv[4], wv[4];
  #pragma unroll
  for (int j = 0; j < 4; ++j) {
    bv[j] = bias[bn + wn + j * 16 + l16];
    if (slice < 2) wv[j] = (slice ? kn : qn)[j * 16 + l16];  // d = j*16+l16
  }

  #pragma unroll
  for (int i = 0; i < 8; ++i) {
    float val[4][4];
    #pragma unroll
    for (int j = 0; j < 4; ++j)
      #pragma unroll
      for (int r = 0; r < 4; ++r)
        val[j][r] = acc[i][j][r] + bv[j];

    if (slice < 2) {
      #pragma unroll
      for (int r = 0; r < 4; ++r) {
        float ss = val[0][r] * val[0][r];
        #pragma unroll
        for (int j = 1; j < 4; ++j) ss += val[j][r] * val[j][r];
        #pragma unroll
        for (int d = 1; d < 16; d <<= 1) ss += __shfl_xor(ss, d, 64);
        float rinv = rsqrtf(ss * (1.0f / 64.0f) + 1e-6f);
        // q * D^-0.5 * log2(e): attn uses hardware 2^x
        if (slice == 0) rinv *= 0.18033688011112042f;
        #pragma unroll
        for (int j = 0; j < 4; ++j) val[j][r] = wv[j] * (val[j][r] * rinv);
      }
    }

    #pragma unroll
    for (int j = 0; j < 4; ++j) {
      const int n = bn + wn + j * 16 + l16;
      #pragma unroll
      for (int r = 0; r < 4; ++r) {
        const int m = bm + wm + i * 16 + quad * 4 + r;
        unsigned short hh, ll;
        split2(val[j][r], hh, ll);
        OutH[(size_t)m * k3C + n] = hh;
        if (writeL) OutL[(size_t)m * k3C + n] = ll;
      }
    }
  }
}

// ---- plane GEMM (128^2, m97-structure): kept for the proj projection ----
template<bool OUTF32, bool FUSE_NORM>
__global__ __launch_bounds__(256)
void gemm_planes(const unsigned short* __restrict__ AH,
                 const unsigned short* __restrict__ AL, int lda,
                 const unsigned short* __restrict__ WH,
                 const unsigned short* __restrict__ WL,
                 const float* __restrict__ bias,
                 float* __restrict__ OutF,
                 unsigned short* __restrict__ OutH,
                 unsigned short* __restrict__ OutL,
                 const float* __restrict__ qn,
                 const float* __restrict__ kn,
                 int Nn, int K)
{
  __shared__ __align__(16) unsigned short AsH[128 * 32], AsL[128 * 32];
  __shared__ __align__(16) unsigned short BsH[128 * 32], BsL[128 * 32];

  const int t    = threadIdx.x;
  const int wave = t >> 6;
  const int lane = t & 63;
  const int quad = lane >> 4;
  const int l16  = lane & 15;
  const int bm = blockIdx.x * 128;
  const int bn = blockIdx.y * 128;
  const int wm = (wave >> 1) * 64;
  const int wn = (wave & 1) * 64;

  f32x4 acc[4][4] = {};

  for (int k0 = 0; k0 < K; k0 += 32) {
    #pragma unroll
    for (int r = 0; r < 2; ++r) {
      const int c   = r * 256 + t;
      const int row = c >> 2;
      const int col = (c & 3) * 8;
      glds16(&AH[(size_t)(bm + row) * lda + k0 + col], &AsH[c * 8]);
      glds16(&AL[(size_t)(bm + row) * lda + k0 + col], &AsL[c * 8]);
      glds16(&WH[(size_t)(bn + row) * K + k0 + col], &BsH[c * 8]);
      glds16(&WL[(size_t)(bn + row) * K + k0 + col], &BsL[c * 8]);
    }
    __syncthreads();

    bhalf8 afh[4], afl[4], bgh[4], bgl[4];
    #pragma unroll
    for (int i = 0; i < 4; ++i) {
      afh[i] = *(const bhalf8*)(&AsH[(wm + i * 16 + l16) * 32 + quad * 8]);
      afl[i] = *(const bhalf8*)(&AsL[(wm + i * 16 + l16) * 32 + quad * 8]);
      bgh[i] = *(const bhalf8*)(&BsH[(wn + i * 16 + l16) * 32 + quad * 8]);
      bgl[i] = *(const bhalf8*)(&BsL[(wn + i * 16 + l16) * 32 + quad * 8]);
    }
    #pragma unroll
    for (int i = 0; i < 4; ++i)
      #pragma unroll
      for (int j = 0; j < 4; ++j) {
        f32x4 a = acc[i][j];
        a = __builtin_amdgcn_mfma_f32_16x16x32_bf16(afh[i], bgh[j], a, 0, 0, 0);
        a = __builtin_amdgcn_mfma_f32_16x16x32_bf16(afh[i], bgl[j], a, 0, 0, 0);
        a = __builtin_amdgcn_mfma_f32_16x16x32_bf16(afl[i], bgh[j], a, 0, 0, 0);
        acc[i][j] = a;
      }
    __syncthreads();
  }

  // epilogue: C/D layout col=lane&15, row=quad*4+reg
  float bv[4], wv[4];
  const int slice = FUSE_NORM ? (bn >> 10) : 0;   // 0=q,1=k,2=v
  const bool writeL = !FUSE_NORM || slice == 0;
  #pragma unroll
  for (int j = 0; j < 4; ++j) {
    bv[j] = bias[bn + wn + j * 16 + l16];
    if (FUSE_NORM && slice < 2)
      wv[j] = (slice ? kn : qn)[j * 16 + l16];    // d = j*16+l16
  }

  #pragma unroll
  for (int i = 0; i < 4; ++i) {
    float val[4][4];
    #pragma unroll
    for (int j = 0; j < 4; ++j)
      #pragma unroll
      for (int r = 0; r < 4; ++r)
        val[j][r] = acc[i][j][r] + bv[j];

    if (FUSE_NORM && slice < 2) {
      #pragma unroll
      for (int r = 0; r < 4; ++r) {
        float ss = val[0][r] * val[0][r];
        #pragma unroll
        for (int j = 1; j < 4; ++j) ss += val[j][r] * val[j][r];
        #pragma unroll
        for (int d = 1; d < 16; d <<= 1) ss += __shfl_xor(ss, d, 64);
        float rinv = rsqrtf(ss * (1.0f / 64.0f) + 1e-6f);
        if (slice == 0) rinv *= 0.125f;           // q * D^-0.5
        #pragma unroll
        for (int j = 0; j < 4; ++j) val[j][r] = wv[j] * (val[j][r] * rinv);
      }
    }

    #pragma unroll
    for (int j = 0; j < 4; ++j) {
      const int n = bn + wn + j * 16 + l16;
      #pragma unroll
      for (int r = 0; r < 4; ++r) {
        const int m = bm + wm + i * 16 + quad * 4 + r;
        if (OUTF32) {
          OutF[(size_t)m * Nn + n] = val[j][r];
        } else {
          unsigned short hh, ll;
          split2(val[j][r], hh, ll);
          OutH[(size_t)m * Nn + n] = hh;
          if (writeL) OutL[(size_t)m * Nn + n] = ll;
        }
      }
    }
  }
}

// ---- flash attention v11 (verified round 7): dbuf K/V, one barrier/iter,
// Pt pitch 68, hardware v_exp_f32 via builtin. ----
__global__ __launch_bounds__(256)
void attn_kernel(unsigned short* __restrict__ H, unsigned short* __restrict__ L,
                 const unsigned short* __restrict__ VTH,
                 const int* __restrict__ mask)
{
  constexpr int P   = 72;  // K/V pitch: bank-start 4*((row+col16)%8) — balanced
  constexpr int Ppt = 68;  // Pt pitch: quad groups land on distinct banks
  __shared__ __align__(16) unsigned short KtH[2][64 * P];   // 18.4 KB dbuf
  __shared__ __align__(16) unsigned short VtH[2][64 * P];   // 18.4 KB dbuf
  __shared__ __align__(16) unsigned short Pt[4][32 * Ppt];  // 17.4 KB per-wave

  const int t    = threadIdx.x;
  const int wave = t >> 6;
  const int lane = t & 63;
  const int quad = lane >> 4;
  const int l16  = lane & 15;

  // XCD swizzle: lin%8 = XCD (dispatch round-robin); 4 bh per XCD.
  const int lin  = blockIdx.x;          // 0..511
  const int xcd  = lin & 7;
  const int slot = lin >> 3;            // 0..63
  const int bh   = xcd + 8 * (slot >> 4);
  const int qblk = slot & 15;
  const int b  = bh >> 4;
  const int h  = bh & 15;
  const int q0 = qblk * 128 + wave * 32;  // 32 q-rows/wave

  // staging geometry: 2 chunks of 8 u16 per thread per tile
  const int row0 = t >> 3,         col0 = (t & 7) * 8;
  const int row1 = (256 + t) >> 3, col1 = ((256 + t) & 7) * 8;

  // Q fragments, both groups (A-layout: m=l16, k=quad*8+j)
  bhalf8 qfh[2][2], qfl[2][2];
  #pragma unroll
  for (int g = 0; g < 2; ++g) {
    const size_t qrow = (size_t)(b * kN + q0 + g * 16 + l16) * k3C + h * kD;
    qfh[g][0] = *(const bhalf8*)(&H[qrow + quad * 8]);
    qfh[g][1] = *(const bhalf8*)(&H[qrow + 32 + quad * 8]);
    qfl[g][0] = *(const bhalf8*)(&L[qrow + quad * 8]);
    qfl[g][1] = *(const bhalf8*)(&L[qrow + 32 + quad * 8]);
  }

  f32x4 acc_o[2][4] = {};
  float lpart[2][4] = {};

  uint4 sk0, sk1, sv0, sv1;            // staging regs
  int mcur[4], mnext[4];

  auto pref = [&](int kt) {
    sk0 = *(const uint4*)(&H[(size_t)(b * kN + kt + row0) * k3C + kC + h * kD + col0]);
    sk1 = *(const uint4*)(&H[(size_t)(b * kN + kt + row1) * k3C + kC + h * kD + col1]);
    sv0 = *(const uint4*)(&VTH[((size_t)bh * kD + row0) * kN + kt + col0]);
    sv1 = *(const uint4*)(&VTH[((size_t)bh * kD + row1) * kN + kt + col1]);
  };
  auto store_tile = [&](int bf) {
    *(uint4*)(&KtH[bf][row0 * P + col0]) = sk0;
    *(uint4*)(&KtH[bf][row1 * P + col1]) = sk1;
    *(uint4*)(&VtH[bf][row0 * P + col0]) = sv0;
    *(uint4*)(&VtH[bf][row1 * P + col1]) = sv1;
  };
  auto loadM = [&](int kt, int* m) {
    #pragma unroll
    for (int nt = 0; nt < 4; ++nt) m[nt] = mask[b * kN + kt + nt * 16 + l16];
  };

  // prologue: tile 0 -> buf0; issue tile 1 loads; one barrier
  pref(0);
  loadM(0, mcur);
  #pragma unroll
  for (int nt = 0; nt < 4; ++nt) mnext[nt] = mcur[nt];
  store_tile(0);                       // compiler inserts vmcnt for sk/sv deps
  pref(64);                            // tile 1 in flight across the barrier
  __syncthreads();

  for (int i = 0; i < 32; ++i) {
    const int cur = i & 1;
    const int kt = i * 64;
    if (i < 31) loadM(kt + 64, mnext);

    // S = (Qh+Ql)Kh ; p = flag*2^s -> Pt (C-layout -> A-layout)
    #pragma unroll
    for (int nt = 0; nt < 4; ++nt) {
      const int kr = (nt * 16 + l16) * P + quad * 8;
      const bhalf8 kh0 = *(const bhalf8*)(&KtH[cur][kr]);
      const bhalf8 kh1 = *(const bhalf8*)(&KtH[cur][kr + 32]);
      const float flag = mcur[nt] ? 1.0f : 0.0f;
      #pragma unroll
      for (int g = 0; g < 2; ++g) {
        f32x4 s = {};
        s = __builtin_amdgcn_mfma_f32_16x16x32_bf16(qfh[g][0], kh0, s, 0, 0, 0);
        s = __builtin_amdgcn_mfma_f32_16x16x32_bf16(qfh[g][1], kh1, s, 0, 0, 0);
        s = __builtin_amdgcn_mfma_f32_16x16x32_bf16(qfl[g][0], kh0, s, 0, 0, 0);
        s = __builtin_amdgcn_mfma_f32_16x16x32_bf16(qfl[g][1], kh1, s, 0, 0, 0);
        #pragma unroll
        for (int r = 0; r < 4; ++r) {
          const float p = flag * fexp2(s[r]);   // s pre-scaled by log2e
          lpart[g][r] += p;
          Pt[wave][(g * 16 + quad * 4 + r) * Ppt + nt * 16 + l16] = f2bf(p);
        }
      }
    }

    // O += P * Vh  (Pt per-wave: same-wave DS ordering, no barrier needed)
    #pragma unroll
    for (int kk = 0; kk < 2; ++kk) {
      const bhalf8 pa0 = *(const bhalf8*)(&Pt[wave][l16 * Ppt + kk * 32 + quad * 8]);
      const bhalf8 pa1 = *(const bhalf8*)(&Pt[wave][(16 + l16) * Ppt + kk * 32 + quad * 8]);
      #pragma unroll
      for (int dt = 0; dt < 4; ++dt) {
        const bhalf8 vb = *(const bhalf8*)(&VtH[cur][(dt * 16 + l16) * P + kk * 32 + quad * 8]);
        acc_o[0][dt] = __builtin_amdgcn_mfma_f32_16x16x32_bf16(pa0, vb, acc_o[0][dt], 0, 0, 0);
        acc_o[1][dt] = __builtin_amdgcn_mfma_f32_16x16x32_bf16(pa1, vb, acc_o[1][dt], 0, 0, 0);
      }
    }

    if (i < 31) {
      store_tile(cur ^ 1);             // tile i+1 into the other buffer
      if (i < 30) pref(kt + 128);      // tile i+2 in flight across barrier
      __syncthreads();                 // single barrier per iteration
      #pragma unroll
      for (int nt = 0; nt < 4; ++nt) mcur[nt] = mnext[nt];
    }
  }

  // final l reduction + normalize + store hi/lo into q-slice
  #pragma unroll
  for (int g = 0; g < 2; ++g)
    #pragma unroll
    for (int r = 0; r < 4; ++r) {
      float s = lpart[g][r];
      #pragma unroll
      for (int d = 1; d < 16; d <<= 1) s += __shfl_xor(s, d, 64);
      lpart[g][r] = s;
    }
  #pragma unroll
  for (int g = 0; g < 2; ++g)
    #pragma unroll
    for (int dt = 0; dt < 4; ++dt)
      #pragma unroll
      for (int r = 0; r < 4; ++r) {
        const int qrow = q0 + g * 16 + quad * 4 + r;
        const float inv = 1.0f / fmaxf(lpart[g][r], 1.0e-30f);
        const size_t off = (size_t)(b * kN + qrow) * k3C + h * kD + dt * 16 + l16;
        unsigned short hh, ll;
        split2(acc_o[g][dt][r] * inv, hh, ll);
        H[off] = hh; L[off] = ll;
      }
}

} // anonymous namespace

extern "C" void kernel_launch(void* const* d_in, const int* in_sizes, int n_in,
                              void* d_out, int out_size, void* d_ws, size_t ws_size,
                              hipStream_t stream)
{
  const float* x      = (const float*)d_in[0];
  const int*   maskp  = (const int*)d_in[1];
  const float* qkv_w  = (const float*)d_in[2];
  const float* qkv_b  = (const float*)d_in[3];
  const float* proj_w = (const float*)d_in[4];
  const float* proj_b = (const float*)d_in[5];
  const float* qn_w   = (const float*)d_in[6];
  const float* kn_w   = (const float*)d_in[7];
  float* out = (float*)d_out;

  unsigned short* qH = (unsigned short*)d_ws;      // qkv hi plane
  unsigned short* qL = qH + kPS;                   // qkv lo plane
  unsigned short* R1 = qL + kPS;                   // x planes -> later VT plane
  unsigned short* R2 = R1 + 2 * kXE;               // qkv_w planes -> later proj_w planes
  unsigned short* xH = R1,  *xL = R1 + kXE;
  unsigned short* VTH = R1;                        // reuse after gemm1
  unsigned short* wqH = R2, *wqL = R2 + kWQ;
  unsigned short* wpH = R2, *wpL = R2 + kWP;

  // 1) fused prep: split x + qkv_w (one launch; 4096 + 3072 blocks)
  prep_split<<<(int)((kXE + kWQ) / 4 / 256), 256, 0, stream>>>(
      x, qkv_w, xH, xL, wqH, wqL);

  // 2) qkv = x @ qkv_w^T + qkv_b, RMSNorm(q,k) fused; lo written for q only
  gemm_qkv256<<<dim3(kTok / 256, k3C / 256), 512, 0, stream>>>(
      xH, xL, wqH, wqL, qkv_b, qH, qL, qn_w, kn_w);

  // 3) fused: V^T pre-transpose (2048 blocks) + proj_w split (1024 blocks)
  vt_and_split<<<3072, 256, 0, stream>>>(qH, VTH, proj_w, wpH, wpL);

  // 4) masked flash attention (XCD-swizzled 1-D grid, 512 blocks)
  attn_kernel<<<dim3(512), 256, 0, stream>>>(qH, qL, VTH, maskp);

  // 5) out = attn @ proj_w^T + proj_b
  gemm_planes<true, false><<<dim3(kTok / 128, kC / 128), 256, 0, stream>>>(
      qH, qL, k3C, wpH, wpL, proj_b, out, nullptr, nullptr, nullptr, nullptr, kC, kC);
}

// Round 9
// 282.140 us; speedup vs baseline: 1.1350x; 1.0256x over previous
//
#include <hip/hip_runtime.h>
#include <hip/hip_bf16.h>
#include <stdint.h>
#include <math.h>

namespace {

constexpr int kB = 2;
constexpr int kN = 2048;
constexpr int kC = 1024;
constexpr int kH = 16;
constexpr int kD = 64;
constexpr int kTok = kB * kN;               // 4096
constexpr int k3C  = 3 * kC;                // 3072
constexpr size_t kPS = (size_t)kTok * k3C;  // qkv plane elems
constexpr size_t kXE = (size_t)kTok * kC;   // x / VT plane elems
constexpr size_t kWQ = (size_t)k3C * kC;    // qkv_w elems
constexpr size_t kWP = (size_t)kC * kC;     // proj_w elems

using bhalf8 = __attribute__((ext_vector_type(8))) __bf16;
using f32x4  = __attribute__((ext_vector_type(4))) float;

__device__ inline unsigned short f2bf(float f) {
  __hip_bfloat16 h = __float2bfloat16(f);
  return *reinterpret_cast<unsigned short*>(&h);
}
__device__ inline float bf2f(unsigned short u) {
  __hip_bfloat16 h;
  *reinterpret_cast<unsigned short*>(&h) = u;
  return __bfloat162float(h);
}
__device__ inline void split2(float v, unsigned short& h, unsigned short& l) {
  const unsigned short hb = f2bf(v);
  h = hb;
  l = f2bf(v - bf2f(hb));
}

// raw hardware 2^x (compiler-managed TRANS hazards). Verified round 7:
// libm exp2f's OCML path cost +10pt VALUBusy / +10us on attn.
#if __has_builtin(__builtin_amdgcn_exp2f)
__device__ inline float fexp2(float x) { return __builtin_amdgcn_exp2f(x); }
#else
__device__ inline float fexp2(float x) { return __expf(x * 0.6931471805599453f); }
#endif

// async global->LDS, 16B per lane; LDS dest must be wave-uniform base + lane*16
__device__ inline void glds16(const unsigned short* g, unsigned short* l) {
  __builtin_amdgcn_global_load_lds(
      (const __attribute__((address_space(1))) void*)g,
      (__attribute__((address_space(3))) void*)l, 16, 0, 0);
}

__device__ inline void split4(const float4 v, ushort4& hh, ushort4& ll) {
  split2(v.x, hh.x, ll.x); split2(v.y, hh.y, ll.y);
  split2(v.z, hh.z, ll.z); split2(v.w, hh.w, ll.w);
}

// ---- fused prep: split x AND qkv_w fp32 -> bf16 hi/lo planes (1 launch) ----
__global__ __launch_bounds__(256)
void prep_split(const float* __restrict__ x, const float* __restrict__ wq,
                unsigned short* __restrict__ xH, unsigned short* __restrict__ xL,
                unsigned short* __restrict__ wqH, unsigned short* __restrict__ wqL)
{
  constexpr int nX = (int)(kXE / 4);       // 1048576 f4 units (4096 blocks)
  int i = blockIdx.x * 256 + threadIdx.x;
  const float* src;
  unsigned short *H, *L;
  if (i < nX) { src = x;  H = xH;  L = xL; }
  else        { i -= nX; src = wq; H = wqH; L = wqL; }
  const float4 v = ((const float4*)src)[i];
  ushort4 hh, ll;
  split4(v, hh, ll);
  ((ushort4*)H)[i] = hh;
  ((ushort4*)L)[i] = ll;
}

// ---- fused: V^T pre-transpose (blocks 0..2047) + proj_w split (2048..3071) ----
__global__ __launch_bounds__(256)
void vt_and_split(const unsigned short* __restrict__ H,
                  unsigned short* __restrict__ VTH,
                  const float* __restrict__ wp,
                  unsigned short* __restrict__ wpH,
                  unsigned short* __restrict__ wpL)
{
  if (blockIdx.x < 2048) {
    const int gw   = blockIdx.x * 4 + (threadIdx.x >> 6);  // 0..8191
    const int lane = threadIdx.x & 63;                     // = d
    const int bh   = gw >> 8;
    const int oct  = gw & 255;
    const int b = bh >> 4, h = bh & 15;
    const int tok0 = oct * 8;
    union { unsigned short u[8]; uint4 v; } ph;
    #pragma unroll
    for (int e = 0; e < 8; ++e) {
      const size_t g = (size_t)(b * kN + tok0 + e) * k3C + 2 * kC + h * kD + lane;
      ph.u[e] = H[g];
    }
    *(uint4*)(&VTH[((size_t)bh * kD + lane) * kN + tok0]) = ph.v;
  } else {
    const int i = (blockIdx.x - 2048) * 256 + threadIdx.x;  // < kWP/4 = 262144
    const float4 v = ((const float4*)wp)[i];
    ushort4 hh, ll;
    split4(v, hh, ll);
    ((ushort4*)wpH)[i] = hh;
    ((ushort4*)wpL)[i] = ll;
  }
}

// ============================================================================
// QKV GEMM, 256x256 tile, 8 waves (2x4), BK=32, double-buffered LDS.
// Term-split 3-phase schedule (verified rounds 2-8, ~897 TF effective).
// ============================================================================
__global__ __launch_bounds__(512)
void gemm_qkv256(const unsigned short* __restrict__ AH,
                 const unsigned short* __restrict__ AL,
                 const unsigned short* __restrict__ WH,
                 const unsigned short* __restrict__ WL,
                 const float* __restrict__ bias,
                 unsigned short* __restrict__ OutH,
                 unsigned short* __restrict__ OutL,
                 const float* __restrict__ qn,
                 const float* __restrict__ kn)
{
  constexpr int BK = 32;
  constexpr int NT = kC / BK;   // 32 K-tiles

  // [buf][plane(hi/lo)][256 rows x 32 cols u16] = 128 KiB total
  __shared__ __align__(16) unsigned short sA[2][2][256 * 32];
  __shared__ __align__(16) unsigned short sB[2][2][256 * 32];

  const int tt   = threadIdx.x;        // 0..511
  const int wave = tt >> 6;            // 0..7
  const int lane = tt & 63;
  const int quad = lane >> 4;
  const int l16  = lane & 15;
  const int bm = blockIdx.x * 256;
  const int bn = blockIdx.y * 256;
  const int wm = (wave >> 2) * 128;    // wave row: 0/128
  const int wn = (wave & 3) * 64;      // wave col: 0/64/128/192

  // staging geometry: unit u = r*512 + tt; row = u>>2; swizzled col-group
  int srow[2], scol[2];
  #pragma unroll
  for (int r = 0; r < 2; ++r) {
    const int u = r * 512 + tt;
    srow[r] = u >> 2;
    scol[r] = ((u & 3) ^ ((srow[r] >> 1) & 3)) * 8;
  }

  // unit: 0=AH 1=WH 2=WL 3=AL (issue order!)
  auto stageU = [&](int bf, int k0, int which) {
    const unsigned short* src = (which == 0) ? AH : (which == 1) ? WH
                              : (which == 2) ? WL : AL;
    const int base = (which == 0 || which == 3) ? bm : bn;
    unsigned short* dst = (which == 0) ? &sA[bf][0][0]
                        : (which == 3) ? &sA[bf][1][0]
                        : (which == 1) ? &sB[bf][0][0] : &sB[bf][1][0];
    #pragma unroll
    for (int r = 0; r < 2; ++r)
      glds16(&src[(size_t)(base + srow[r]) * kC + k0 + scol[r]],
             &dst[(r * 512 + tt) * 8]);
  };

  auto rdA = [&](int bf, int pl, int row) -> bhalf8 {
    return *(const bhalf8*)(&sA[bf][pl][row * 32 + ((quad ^ ((row >> 1) & 3)) * 8)]);
  };
  auto rdB = [&](int bf, int pl, int row) -> bhalf8 {
    return *(const bhalf8*)(&sB[bf][pl][row * 32 + ((quad ^ ((row >> 1) & 3)) * 8)]);
  };

  f32x4 acc[8][4] = {};
  bhalf8 ah[8], bh_[4], bl_[4];

  // ---- prologue: stage all 4 units of tile 0; wait AH0,WH0 ----
  stageU(0, 0, 0); stageU(0, 0, 1); stageU(0, 0, 2); stageU(0, 0, 3);
  asm volatile("s_waitcnt vmcnt(4)" ::: "memory");
  __builtin_amdgcn_sched_barrier(0);
  asm volatile("s_barrier" ::: "memory");

  for (int t = 0; t < NT - 1; ++t) {
    const int buf  = t & 1;
    const int nbuf = buf ^ 1;
    const int nk0  = (t + 1) * BK;

    // ---- P01: hh term ----
    #pragma unroll
    for (int i = 0; i < 8; ++i) ah[i]  = rdA(buf, 0, wm + i * 16 + l16);
    #pragma unroll
    for (int j = 0; j < 4; ++j) bh_[j] = rdB(buf, 0, wn + j * 16 + l16);
    stageU(nbuf, nk0, 0);                 // AH(t+1)
    stageU(nbuf, nk0, 1);                 // WH(t+1)
    asm volatile("s_waitcnt vmcnt(6)" ::: "memory");   // drain WL(t)
    __builtin_amdgcn_sched_barrier(0);
    asm volatile("s_barrier" ::: "memory");
    __builtin_amdgcn_s_setprio(1);
    #pragma unroll
    for (int i = 0; i < 8; ++i)
      #pragma unroll
      for (int j = 0; j < 4; ++j)
        acc[i][j] = __builtin_amdgcn_mfma_f32_16x16x32_bf16(ah[i], bh_[j], acc[i][j], 0, 0, 0);
    __builtin_amdgcn_s_setprio(0);

    // ---- P2: hl term ----
    #pragma unroll
    for (int j = 0; j < 4; ++j) bl_[j] = rdB(buf, 1, wn + j * 16 + l16);
    stageU(nbuf, nk0, 2);                 // WL(t+1)
    asm volatile("s_waitcnt vmcnt(6)" ::: "memory");   // drain AL(t)
    __builtin_amdgcn_sched_barrier(0);
    asm volatile("s_barrier" ::: "memory");
    __builtin_amdgcn_s_setprio(1);
    #pragma unroll
    for (int i = 0; i < 8; ++i)
      #pragma unroll
      for (int j = 0; j < 4; ++j)
        acc[i][j] = __builtin_amdgcn_mfma_f32_16x16x32_bf16(ah[i], bl_[j], acc[i][j], 0, 0, 0);
    __builtin_amdgcn_s_setprio(0);

    // ---- P3: lh term ----
    stageU(nbuf, nk0, 3);                 // AL(t+1)
    asm volatile("s_waitcnt vmcnt(4)" ::: "memory");   // drain AH,WH(t+1)
    __builtin_amdgcn_sched_barrier(0);
    asm volatile("s_barrier" ::: "memory");
    __builtin_amdgcn_s_setprio(1);
    {
      bhalf8 al0[4];
      #pragma unroll
      for (int i = 0; i < 4; ++i) al0[i] = rdA(buf, 1, wm + i * 16 + l16);
      #pragma unroll
      for (int i = 0; i < 4; ++i)
        #pragma unroll
        for (int j = 0; j < 4; ++j)
          acc[i][j] = __builtin_amdgcn_mfma_f32_16x16x32_bf16(al0[i], bh_[j], acc[i][j], 0, 0, 0);
      bhalf8 al1[4];
      #pragma unroll
      for (int i = 0; i < 4; ++i) al1[i] = rdA(buf, 1, wm + (4 + i) * 16 + l16);
      #pragma unroll
      for (int i = 0; i < 4; ++i)
        #pragma unroll
        for (int j = 0; j < 4; ++j)
          acc[4 + i][j] = __builtin_amdgcn_mfma_f32_16x16x32_bf16(al1[i], bh_[j], acc[4 + i][j], 0, 0, 0);
    }
    __builtin_amdgcn_s_setprio(0);
    asm volatile("s_barrier" ::: "memory");   // end-of-tile lockstep
  }

  // ---- peeled last tile (no prefetch) ----
  {
    const int buf = (NT - 1) & 1;
    #pragma unroll
    for (int i = 0; i < 8; ++i) ah[i]  = rdA(buf, 0, wm + i * 16 + l16);
    #pragma unroll
    for (int j = 0; j < 4; ++j) bh_[j] = rdB(buf, 0, wn + j * 16 + l16);
    __builtin_amdgcn_s_setprio(1);
    #pragma unroll
    for (int i = 0; i < 8; ++i)
      #pragma unroll
      for (int j = 0; j < 4; ++j)
        acc[i][j] = __builtin_amdgcn_mfma_f32_16x16x32_bf16(ah[i], bh_[j], acc[i][j], 0, 0, 0);
    __builtin_amdgcn_s_setprio(0);

    asm volatile("s_waitcnt vmcnt(2)" ::: "memory");   // drain WL(last)
    __builtin_amdgcn_sched_barrier(0);
    asm volatile("s_barrier" ::: "memory");
    #pragma unroll
    for (int j = 0; j < 4; ++j) bl_[j] = rdB(buf, 1, wn + j * 16 + l16);
    __builtin_amdgcn_s_setprio(1);
    #pragma unroll
    for (int i = 0; i < 8; ++i)
      #pragma unroll
      for (int j = 0; j < 4; ++j)
        acc[i][j] = __builtin_amdgcn_mfma_f32_16x16x32_bf16(ah[i], bl_[j], acc[i][j], 0, 0, 0);
    __builtin_amdgcn_s_setprio(0);

    asm volatile("s_waitcnt vmcnt(0)" ::: "memory");   // drain AL(last)
    __builtin_amdgcn_sched_barrier(0);
    asm volatile("s_barrier" ::: "memory");
    __builtin_amdgcn_s_setprio(1);
    {
      bhalf8 al0[4];
      #pragma unroll
      for (int i = 0; i < 4; ++i) al0[i] = rdA(buf, 1, wm + i * 16 + l16);
      #pragma unroll
      for (int i = 0; i < 4; ++i)
        #pragma unroll
        for (int j = 0; j < 4; ++j)
          acc[i][j] = __builtin_amdgcn_mfma_f32_16x16x32_bf16(al0[i], bh_[j], acc[i][j], 0, 0, 0);
      bhalf8 al1[4];
      #pragma unroll
      for (int i = 0; i < 4; ++i) al1[i] = rdA(buf, 1, wm + (4 + i) * 16 + l16);
      #pragma unroll
      for (int i = 0; i < 4; ++i)
        #pragma unroll
        for (int j = 0; j < 4; ++j)
          acc[4 + i][j] = __builtin_amdgcn_mfma_f32_16x16x32_bf16(al1[i], bh_[j], acc[4 + i][j], 0, 0, 0);
    }
    __builtin_amdgcn_s_setprio(0);
  }

  // epilogue: C/D layout col=lane&15, row=quad*4+reg; fused RMSNorm on q,k
  const int slice = bn >> 10;          // 0=q,1=k,2=v (bn multiple of 256)
  const bool writeL = (slice == 0);
  float bv[4], wv[4];
  #pragma unroll
  for (int j = 0; j < 4; ++j) {
    bv[j] = bias[bn + wn + j * 16 + l16];
    if (slice < 2) wv[j] = (slice ? kn : qn)[j * 16 + l16];  // d = j*16+l16
  }

  #pragma unroll
  for (int i = 0; i < 8; ++i) {
    float val[4][4];
    #pragma unroll
    for (int j = 0; j < 4; ++j)
      #pragma unroll
      for (int r = 0; r < 4; ++r)
        val[j][r] = acc[i][j][r] + bv[j];

    if (slice < 2) {
      #pragma unroll
      for (int r = 0; r < 4; ++r) {
        float ss = val[0][r] * val[0][r];
        #pragma unroll
        for (int j = 1; j < 4; ++j) ss += val[j][r] * val[j][r];
        #pragma unroll
        for (int d = 1; d < 16; d <<= 1) ss += __shfl_xor(ss, d, 64);
        float rinv = rsqrtf(ss * (1.0f / 64.0f) + 1e-6f);
        // q * D^-0.5 * log2(e): attn uses hardware 2^x
        if (slice == 0) rinv *= 0.18033688011112042f;
        #pragma unroll
        for (int j = 0; j < 4; ++j) val[j][r] = wv[j] * (val[j][r] * rinv);
      }
    }

    #pragma unroll
    for (int j = 0; j < 4; ++j) {
      const int n = bn + wn + j * 16 + l16;
      #pragma unroll
      for (int r = 0; r < 4; ++r) {
        const int m = bm + wm + i * 16 + quad * 4 + r;
        unsigned short hh, ll;
        split2(val[j][r], hh, ll);
        OutH[(size_t)m * k3C + n] = hh;
        if (writeL) OutL[(size_t)m * k3C + n] = ll;
      }
    }
  }
}

// ============================================================================
// PROJ GEMM, 128x128 tile, 4 waves (2x2), BK=32 — the SAME term-split 3-phase
// counted-vmcnt schedule as gemm_qkv256 (each stage-unit is still 2 loads per
// thread: 8KB unit / 256 threads / 16B), so the vmcnt ledger carries over
// verbatim (4 / 6,6,4 / 2,0). Replaces the m97 2-barrier gemm_planes which ran
// at 1 block/CU with no latency cover. A stride = k3C (q-slice), fp32 out.
// ============================================================================
__global__ __launch_bounds__(256)
void gemm_proj128(const unsigned short* __restrict__ AH,
                  const unsigned short* __restrict__ AL,
                  const unsigned short* __restrict__ WH,
                  const unsigned short* __restrict__ WL,
                  const float* __restrict__ bias,
                  float* __restrict__ Out)
{
  constexpr int BK = 32;
  constexpr int NT = kC / BK;   // 32 K-tiles

  // [buf][plane(hi/lo)][128 rows x 32 cols u16] = 64 KiB total
  __shared__ __align__(16) unsigned short sA[2][2][128 * 32];
  __shared__ __align__(16) unsigned short sB[2][2][128 * 32];

  const int tt   = threadIdx.x;        // 0..255
  const int wave = tt >> 6;            // 0..3
  const int lane = tt & 63;
  const int quad = lane >> 4;
  const int l16  = lane & 15;
  const int bm = blockIdx.x * 128;
  const int bn = blockIdx.y * 128;
  const int wm = (wave >> 1) * 64;     // wave row: 0/64
  const int wn = (wave & 1) * 64;      // wave col: 0/64

  // staging geometry: chunk c = r*256 + tt; row = c>>2; swizzled col-group
  int srow[2], scol[2];
  #pragma unroll
  for (int r = 0; r < 2; ++r) {
    const int c = r * 256 + tt;
    srow[r] = c >> 2;
    scol[r] = ((c & 3) ^ ((srow[r] >> 1) & 3)) * 8;
  }

  // unit: 0=AH 1=WH 2=WL 3=AL (issue order!); A stride k3C, W stride kC
  auto stageU = [&](int bf, int k0, int which) {
    const unsigned short* src = (which == 0) ? AH : (which == 1) ? WH
                              : (which == 2) ? WL : AL;
    const bool isA = (which == 0 || which == 3);
    const int base = isA ? bm : bn;
    const int ld   = isA ? k3C : kC;
    unsigned short* dst = (which == 0) ? &sA[bf][0][0]
                        : (which == 3) ? &sA[bf][1][0]
                        : (which == 1) ? &sB[bf][0][0] : &sB[bf][1][0];
    #pragma unroll
    for (int r = 0; r < 2; ++r)
      glds16(&src[(size_t)(base + srow[r]) * ld + k0 + scol[r]],
             &dst[(r * 256 + tt) * 8]);
  };

  auto rdA = [&](int bf, int pl, int row) -> bhalf8 {
    return *(const bhalf8*)(&sA[bf][pl][row * 32 + ((quad ^ ((row >> 1) & 3)) * 8)]);
  };
  auto rdB = [&](int bf, int pl, int row) -> bhalf8 {
    return *(const bhalf8*)(&sB[bf][pl][row * 32 + ((quad ^ ((row >> 1) & 3)) * 8)]);
  };

  f32x4 acc[4][4] = {};
  bhalf8 ah[4], bh_[4], bl_[4];

  // ---- prologue: stage all 4 units of tile 0; wait AH0,WH0 ----
  stageU(0, 0, 0); stageU(0, 0, 1); stageU(0, 0, 2); stageU(0, 0, 3);
  asm volatile("s_waitcnt vmcnt(4)" ::: "memory");
  __builtin_amdgcn_sched_barrier(0);
  asm volatile("s_barrier" ::: "memory");

  for (int t = 0; t < NT - 1; ++t) {
    const int buf  = t & 1;
    const int nbuf = buf ^ 1;
    const int nk0  = (t + 1) * BK;

    // ---- P01: hh term ----
    #pragma unroll
    for (int i = 0; i < 4; ++i) ah[i]  = rdA(buf, 0, wm + i * 16 + l16);
    #pragma unroll
    for (int j = 0; j < 4; ++j) bh_[j] = rdB(buf, 0, wn + j * 16 + l16);
    stageU(nbuf, nk0, 0);                 // AH(t+1)
    stageU(nbuf, nk0, 1);                 // WH(t+1)
    asm volatile("s_waitcnt vmcnt(6)" ::: "memory");   // drain WL(t)
    __builtin_amdgcn_sched_barrier(0);
    asm volatile("s_barrier" ::: "memory");
    __builtin_amdgcn_s_setprio(1);
    #pragma unroll
    for (int i = 0; i < 4; ++i)
      #pragma unroll
      for (int j = 0; j < 4; ++j)
        acc[i][j] = __builtin_amdgcn_mfma_f32_16x16x32_bf16(ah[i], bh_[j], acc[i][j], 0, 0, 0);
    __builtin_amdgcn_s_setprio(0);

    // ---- P2: hl term ----
    #pragma unroll
    for (int j = 0; j < 4; ++j) bl_[j] = rdB(buf, 1, wn + j * 16 + l16);
    stageU(nbuf, nk0, 2);                 // WL(t+1)
    asm volatile("s_waitcnt vmcnt(6)" ::: "memory");   // drain AL(t)
    __builtin_amdgcn_sched_barrier(0);
    asm volatile("s_barrier" ::: "memory");
    __builtin_amdgcn_s_setprio(1);
    #pragma unroll
    for (int i = 0; i < 4; ++i)
      #pragma unroll
      for (int j = 0; j < 4; ++j)
        acc[i][j] = __builtin_amdgcn_mfma_f32_16x16x32_bf16(ah[i], bl_[j], acc[i][j], 0, 0, 0);
    __builtin_amdgcn_s_setprio(0);

    // ---- P3: lh term ----
    stageU(nbuf, nk0, 3);                 // AL(t+1)
    asm volatile("s_waitcnt vmcnt(4)" ::: "memory");   // drain AH,WH(t+1)
    __builtin_amdgcn_sched_barrier(0);
    asm volatile("s_barrier" ::: "memory");
    __builtin_amdgcn_s_setprio(1);
    {
      bhalf8 al0[4];
      #pragma unroll
      for (int i = 0; i < 4; ++i) al0[i] = rdA(buf, 1, wm + i * 16 + l16);
      #pragma unroll
      for (int i = 0; i < 4; ++i)
        #pragma unroll
        for (int j = 0; j < 4; ++j)
          acc[i][j] = __builtin_amdgcn_mfma_f32_16x16x32_bf16(al0[i], bh_[j], acc[i][j], 0, 0, 0);
    }
    __builtin_amdgcn_s_setprio(0);
    asm volatile("s_barrier" ::: "memory");   // end-of-tile lockstep
  }

  // ---- peeled last tile (no prefetch) ----
  {
    const int buf = (NT - 1) & 1;
    #pragma unroll
    for (int i = 0; i < 4; ++i) ah[i]  = rdA(buf, 0, wm + i * 16 + l16);
    #pragma unroll
    for (int j = 0; j < 4; ++j) bh_[j] = rdB(buf, 0, wn + j * 16 + l16);
    __builtin_amdgcn_s_setprio(1);
    #pragma unroll
    for (int i = 0; i < 4; ++i)
      #pragma unroll
      for (int j = 0; j < 4; ++j)
        acc[i][j] = __builtin_amdgcn_mfma_f32_16x16x32_bf16(ah[i], bh_[j], acc[i][j], 0, 0, 0);
    __builtin_amdgcn_s_setprio(0);

    asm volatile("s_waitcnt vmcnt(2)" ::: "memory");   // drain WL(last)
    __builtin_amdgcn_sched_barrier(0);
    asm volatile("s_barrier" ::: "memory");
    #pragma unroll
    for (int j = 0; j < 4; ++j) bl_[j] = rdB(buf, 1, wn + j * 16 + l16);
    __builtin_amdgcn_s_setprio(1);
    #pragma unroll
    for (int i = 0; i < 4; ++i)
      #pragma unroll
      for (int j = 0; j < 4; ++j)
        acc[i][j] = __builtin_amdgcn_mfma_f32_16x16x32_bf16(ah[i], bl_[j], acc[i][j], 0, 0, 0);
    __builtin_amdgcn_s_setprio(0);

    asm volatile("s_waitcnt vmcnt(0)" ::: "memory");   // drain AL(last)
    __builtin_amdgcn_sched_barrier(0);
    asm volatile("s_barrier" ::: "memory");
    __builtin_amdgcn_s_setprio(1);
    {
      bhalf8 al0[4];
      #pragma unroll
      for (int i = 0; i < 4; ++i) al0[i] = rdA(buf, 1, wm + i * 16 + l16);
      #pragma unroll
      for (int i = 0; i < 4; ++i)
        #pragma unroll
        for (int j = 0; j < 4; ++j)
          acc[i][j] = __builtin_amdgcn_mfma_f32_16x16x32_bf16(al0[i], bh_[j], acc[i][j], 0, 0, 0);
    }
    __builtin_amdgcn_s_setprio(0);
  }

  // epilogue: fp32 out + bias; C/D layout col=lane&15, row=quad*4+reg
  float bv[4];
  #pragma unroll
  for (int j = 0; j < 4; ++j) bv[j] = bias[bn + wn + j * 16 + l16];

  #pragma unroll
  for (int i = 0; i < 4; ++i)
    #pragma unroll
    for (int j = 0; j < 4; ++j) {
      const int n = bn + wn + j * 16 + l16;
      #pragma unroll
      for (int r = 0; r < 4; ++r) {
        const int m = bm + wm + i * 16 + quad * 4 + r;
        Out[(size_t)m * kC + n] = acc[i][j][r] + bv[j];
      }
    }
}

// ---- flash attention v11 (verified round 7): dbuf K/V, one barrier/iter,
// Pt pitch 68, hardware v_exp_f32 via builtin. ----
__global__ __launch_bounds__(256)
void attn_kernel(unsigned short* __restrict__ H, unsigned short* __restrict__ L,
                 const unsigned short* __restrict__ VTH,
                 const int* __restrict__ mask)
{
  constexpr int P   = 72;  // K/V pitch: bank-start 4*((row+col16)%8) — balanced
  constexpr int Ppt = 68;  // Pt pitch: quad groups land on distinct banks
  __shared__ __align__(16) unsigned short KtH[2][64 * P];   // 18.4 KB dbuf
  __shared__ __align__(16) unsigned short VtH[2][64 * P];   // 18.4 KB dbuf
  __shared__ __align__(16) unsigned short Pt[4][32 * Ppt];  // 17.4 KB per-wave

  const int t    = threadIdx.x;
  const int wave = t >> 6;
  const int lane = t & 63;
  const int quad = lane >> 4;
  const int l16  = lane & 15;

  // XCD swizzle: lin%8 = XCD (dispatch round-robin); 4 bh per XCD.
  const int lin  = blockIdx.x;          // 0..511
  const int xcd  = lin & 7;
  const int slot = lin >> 3;            // 0..63
  const int bh   = xcd + 8 * (slot >> 4);
  const int qblk = slot & 15;
  const int b  = bh >> 4;
  const int h  = bh & 15;
  const int q0 = qblk * 128 + wave * 32;  // 32 q-rows/wave

  // staging geometry: 2 chunks of 8 u16 per thread per tile
  const int row0 = t >> 3,         col0 = (t & 7) * 8;
  const int row1 = (256 + t) >> 3, col1 = ((256 + t) & 7) * 8;

  // Q fragments, both groups (A-layout: m=l16, k=quad*8+j)
  bhalf8 qfh[2][2], qfl[2][2];
  #pragma unroll
  for (int g = 0; g < 2; ++g) {
    const size_t qrow = (size_t)(b * kN + q0 + g * 16 + l16) * k3C + h * kD;
    qfh[g][0] = *(const bhalf8*)(&H[qrow + quad * 8]);
    qfh[g][1] = *(const bhalf8*)(&H[qrow + 32 + quad * 8]);
    qfl[g][0] = *(const bhalf8*)(&L[qrow + quad * 8]);
    qfl[g][1] = *(const bhalf8*)(&L[qrow + 32 + quad * 8]);
  }

  f32x4 acc_o[2][4] = {};
  float lpart[2][4] = {};

  uint4 sk0, sk1, sv0, sv1;            // staging regs
  int mcur[4], mnext[4];

  auto pref = [&](int kt) {
    sk0 = *(const uint4*)(&H[(size_t)(b * kN + kt + row0) * k3C + kC + h * kD + col0]);
    sk1 = *(const uint4*)(&H[(size_t)(b * kN + kt + row1) * k3C + kC + h * kD + col1]);
    sv0 = *(const uint4*)(&VTH[((size_t)bh * kD + row0) * kN + kt + col0]);
    sv1 = *(const uint4*)(&VTH[((size_t)bh * kD + row1) * kN + kt + col1]);
  };
  auto store_tile = [&](int bf) {
    *(uint4*)(&KtH[bf][row0 * P + col0]) = sk0;
    *(uint4*)(&KtH[bf][row1 * P + col1]) = sk1;
    *(uint4*)(&VtH[bf][row0 * P + col0]) = sv0;
    *(uint4*)(&VtH[bf][row1 * P + col1]) = sv1;
  };
  auto loadM = [&](int kt, int* m) {
    #pragma unroll
    for (int nt = 0; nt < 4; ++nt) m[nt] = mask[b * kN + kt + nt * 16 + l16];
  };

  // prologue: tile 0 -> buf0; issue tile 1 loads; one barrier
  pref(0);
  loadM(0, mcur);
  #pragma unroll
  for (int nt = 0; nt < 4; ++nt) mnext[nt] = mcur[nt];
  store_tile(0);                       // compiler inserts vmcnt for sk/sv deps
  pref(64);                            // tile 1 in flight across the barrier
  __syncthreads();

  for (int i = 0; i < 32; ++i) {
    const int cur = i & 1;
    const int kt = i * 64;
    if (i < 31) loadM(kt + 64, mnext);

    // S = (Qh+Ql)Kh ; p = flag*2^s -> Pt (C-layout -> A-layout)
    #pragma unroll
    for (int nt = 0; nt < 4; ++nt) {
      const int kr = (nt * 16 + l16) * P + quad * 8;
      const bhalf8 kh0 = *(const bhalf8*)(&KtH[cur][kr]);
      const bhalf8 kh1 = *(const bhalf8*)(&KtH[cur][kr + 32]);
      const float flag = mcur[nt] ? 1.0f : 0.0f;
      #pragma unroll
      for (int g = 0; g < 2; ++g) {
        f32x4 s = {};
        s = __builtin_amdgcn_mfma_f32_16x16x32_bf16(qfh[g][0], kh0, s, 0, 0, 0);
        s = __builtin_amdgcn_mfma_f32_16x16x32_bf16(qfh[g][1], kh1, s, 0, 0, 0);
        s = __builtin_amdgcn_mfma_f32_16x16x32_bf16(qfl[g][0], kh0, s, 0, 0, 0);
        s = __builtin_amdgcn_mfma_f32_16x16x32_bf16(qfl[g][1], kh1, s, 0, 0, 0);
        #pragma unroll
        for (int r = 0; r < 4; ++r) {
          const float p = flag * fexp2(s[r]);   // s pre-scaled by log2e
          lpart[g][r] += p;
          Pt[wave][(g * 16 + quad * 4 + r) * Ppt + nt * 16 + l16] = f2bf(p);
        }
      }
    }

    // O += P * Vh  (Pt per-wave: same-wave DS ordering, no barrier needed)
    #pragma unroll
    for (int kk = 0; kk < 2; ++kk) {
      const bhalf8 pa0 = *(const bhalf8*)(&Pt[wave][l16 * Ppt + kk * 32 + quad * 8]);
      const bhalf8 pa1 = *(const bhalf8*)(&Pt[wave][(16 + l16) * Ppt + kk * 32 + quad * 8]);
      #pragma unroll
      for (int dt = 0; dt < 4; ++dt) {
        const bhalf8 vb = *(const bhalf8*)(&VtH[cur][(dt * 16 + l16) * P + kk * 32 + quad * 8]);
        acc_o[0][dt] = __builtin_amdgcn_mfma_f32_16x16x32_bf16(pa0, vb, acc_o[0][dt], 0, 0, 0);
        acc_o[1][dt] = __builtin_amdgcn_mfma_f32_16x16x32_bf16(pa1, vb, acc_o[1][dt], 0, 0, 0);
      }
    }

    if (i < 31) {
      store_tile(cur ^ 1);             // tile i+1 into the other buffer
      if (i < 30) pref(kt + 128);      // tile i+2 in flight across barrier
      __syncthreads();                 // single barrier per iteration
      #pragma unroll
      for (int nt = 0; nt < 4; ++nt) mcur[nt] = mnext[nt];
    }
  }

  // final l reduction + normalize + store hi/lo into q-slice
  #pragma unroll
  for (int g = 0; g < 2; ++g)
    #pragma unroll
    for (int r = 0; r < 4; ++r) {
      float s = lpart[g][r];
      #pragma unroll
      for (int d = 1; d < 16; d <<= 1) s += __shfl_xor(s, d, 64);
      lpart[g][r] = s;
    }
  #pragma unroll
  for (int g = 0; g < 2; ++g)
    #pragma unroll
    for (int dt = 0; dt < 4; ++dt)
      #pragma unroll
      for (int r = 0; r < 4; ++r) {
        const int qrow = q0 + g * 16 + quad * 4 + r;
        const float inv = 1.0f / fmaxf(lpart[g][r], 1.0e-30f);
        const size_t off = (size_t)(b * kN + qrow) * k3C + h * kD + dt * 16 + l16;
        unsigned short hh, ll;
        split2(acc_o[g][dt][r] * inv, hh, ll);
        H[off] = hh; L[off] = ll;
      }
}

} // anonymous namespace

extern "C" void kernel_launch(void* const* d_in, const int* in_sizes, int n_in,
                              void* d_out, int out_size, void* d_ws, size_t ws_size,
                              hipStream_t stream)
{
  const float* x      = (const float*)d_in[0];
  const int*   maskp  = (const int*)d_in[1];
  const float* qkv_w  = (const float*)d_in[2];
  const float* qkv_b  = (const float*)d_in[3];
  const float* proj_w = (const float*)d_in[4];
  const float* proj_b = (const float*)d_in[5];
  const float* qn_w   = (const float*)d_in[6];
  const float* kn_w   = (const float*)d_in[7];
  float* out = (float*)d_out;

  unsigned short* qH = (unsigned short*)d_ws;      // qkv hi plane
  unsigned short* qL = qH + kPS;                   // qkv lo plane
  unsigned short* R1 = qL + kPS;                   // x planes -> later VT plane
  unsigned short* R2 = R1 + 2 * kXE;               // qkv_w planes -> later proj_w planes
  unsigned short* xH = R1,  *xL = R1 + kXE;
  unsigned short* VTH = R1;                        // reuse after gemm1
  unsigned short* wqH = R2, *wqL = R2 + kWQ;
  unsigned short* wpH = R2, *wpL = R2 + kWP;

  // 1) fused prep: split x + qkv_w (one launch; 4096 + 3072 blocks)
  prep_split<<<(int)((kXE + kWQ) / 4 / 256), 256, 0, stream>>>(
      x, qkv_w, xH, xL, wqH, wqL);

  // 2) qkv = x @ qkv_w^T + qkv_b, RMSNorm(q,k) fused; lo written for q only
  gemm_qkv256<<<dim3(kTok / 256, k3C / 256), 512, 0, stream>>>(
      xH, xL, wqH, wqL, qkv_b, qH, qL, qn_w, kn_w);

  // 3) fused: V^T pre-transpose (2048 blocks) + proj_w split (1024 blocks)
  vt_and_split<<<3072, 256, 0, stream>>>(qH, VTH, proj_w, wpH, wpL);

  // 4) masked flash attention (XCD-swizzled 1-D grid, 512 blocks)
  attn_kernel<<<dim3(512), 256, 0, stream>>>(qH, qL, VTH, maskp);

  // 5) out = attn @ proj_w^T + proj_b  (term-split 3-phase, grid 32x8=256)
  gemm_proj128<<<dim3(kTok / 128, kC / 128), 256, 0, stream>>>(
      qH, qL, wpH, wpL, proj_b, out);
}

// Round 10
// 272.975 us; speedup vs baseline: 1.1731x; 1.0336x over previous
//
#include <hip/hip_runtime.h>
#include <hip/hip_bf16.h>
#include <stdint.h>
#include <math.h>

namespace {

constexpr int kB = 2;
constexpr int kN = 2048;
constexpr int kC = 1024;
constexpr int kH = 16;
constexpr int kD = 64;
constexpr int kTok = kB * kN;               // 4096
constexpr int k3C  = 3 * kC;                // 3072
constexpr size_t kPS = (size_t)kTok * k3C;  // qkv plane elems
constexpr size_t kXE = (size_t)kTok * kC;   // x / VT plane elems
constexpr size_t kWQ = (size_t)k3C * kC;    // qkv_w elems
constexpr size_t kWP = (size_t)kC * kC;     // proj_w elems

using bhalf8 = __attribute__((ext_vector_type(8))) __bf16;
using f32x4  = __attribute__((ext_vector_type(4))) float;

__device__ inline unsigned short f2bf(float f) {
  __hip_bfloat16 h = __float2bfloat16(f);
  return *reinterpret_cast<unsigned short*>(&h);
}
__device__ inline float bf2f(unsigned short u) {
  __hip_bfloat16 h;
  *reinterpret_cast<unsigned short*>(&h) = u;
  return __bfloat162float(h);
}
__device__ inline void split2(float v, unsigned short& h, unsigned short& l) {
  const unsigned short hb = f2bf(v);
  h = hb;
  l = f2bf(v - bf2f(hb));
}

// raw hardware 2^x (compiler-managed TRANS hazards). Verified round 7:
// libm exp2f's OCML path cost +10pt VALUBusy / +10us on attn.
#if __has_builtin(__builtin_amdgcn_exp2f)
__device__ inline float fexp2(float x) { return __builtin_amdgcn_exp2f(x); }
#else
__device__ inline float fexp2(float x) { return __expf(x * 0.6931471805599453f); }
#endif

// async global->LDS, 16B per lane; LDS dest must be wave-uniform base + lane*16
__device__ inline void glds16(const unsigned short* g, unsigned short* l) {
  __builtin_amdgcn_global_load_lds(
      (const __attribute__((address_space(1))) void*)g,
      (__attribute__((address_space(3))) void*)l, 16, 0, 0);
}

__device__ inline void split4(const float4 v, ushort4& hh, ushort4& ll) {
  split2(v.x, hh.x, ll.x); split2(v.y, hh.y, ll.y);
  split2(v.z, hh.z, ll.z); split2(v.w, hh.w, ll.w);
}

// ---- fused prep: split x AND qkv_w fp32 -> bf16 hi/lo planes (1 launch) ----
__global__ __launch_bounds__(256)
void prep_split(const float* __restrict__ x, const float* __restrict__ wq,
                unsigned short* __restrict__ xH, unsigned short* __restrict__ xL,
                unsigned short* __restrict__ wqH, unsigned short* __restrict__ wqL)
{
  constexpr int nX = (int)(kXE / 4);       // 1048576 f4 units (4096 blocks)
  int i = blockIdx.x * 256 + threadIdx.x;
  const float* src;
  unsigned short *H, *L;
  if (i < nX) { src = x;  H = xH;  L = xL; }
  else        { i -= nX; src = wq; H = wqH; L = wqL; }
  const float4 v = ((const float4*)src)[i];
  ushort4 hh, ll;
  split4(v, hh, ll);
  ((ushort4*)H)[i] = hh;
  ((ushort4*)L)[i] = ll;
}

// ---- fused: V^T pre-transpose (blocks 0..2047) + proj_w split (2048..3071) ----
__global__ __launch_bounds__(256)
void vt_and_split(const unsigned short* __restrict__ H,
                  unsigned short* __restrict__ VTH,
                  const float* __restrict__ wp,
                  unsigned short* __restrict__ wpH,
                  unsigned short* __restrict__ wpL)
{
  if (blockIdx.x < 2048) {
    const int gw   = blockIdx.x * 4 + (threadIdx.x >> 6);  // 0..8191
    const int lane = threadIdx.x & 63;                     // = d
    const int bh   = gw >> 8;
    const int oct  = gw & 255;
    const int b = bh >> 4, h = bh & 15;
    const int tok0 = oct * 8;
    union { unsigned short u[8]; uint4 v; } ph;
    #pragma unroll
    for (int e = 0; e < 8; ++e) {
      const size_t g = (size_t)(b * kN + tok0 + e) * k3C + 2 * kC + h * kD + lane;
      ph.u[e] = H[g];
    }
    *(uint4*)(&VTH[((size_t)bh * kD + lane) * kN + tok0]) = ph.v;
  } else {
    const int i = (blockIdx.x - 2048) * 256 + threadIdx.x;  // < kWP/4 = 262144
    const float4 v = ((const float4*)wp)[i];
    ushort4 hh, ll;
    split4(v, hh, ll);
    ((ushort4*)wpH)[i] = hh;
    ((ushort4*)wpL)[i] = ll;
  }
}

// ============================================================================
// QKV GEMM, 256x192 tile -> grid 16x16 = 256 blocks = FULL CU coverage (the
// 256x256 tile gave 192 blocks = 64 idle CUs, 25% of the chip).
// 8 waves stacked in M (wave tile 32x192 — head-aligned so RMSNorm stays
// per-wave). Same term-split 3-phase counted-vmcnt schedule.
// Staging: A-units = 2 loads/thread on all 8 waves (ledger 4 / 6,6,4 / 2,0
// verbatim). W-units = 192x32 = 768 chunks -> waves 0-5 stage 2 each; waves
// 6-7 stage none and use their own wave-uniform ledger:
//   prologue vmcnt(2); steady P3 vmcnt(2) (drains AL(T)+AH(T+1), 2-ph cover);
//   peel vmcnt(0). Visibility: frag reads at P01-top are covered by T-1's
//   P3 drains + end-of-tile barrier for BOTH wave groups.
// ============================================================================
__global__ __launch_bounds__(512)
void gemm_qkv256(const unsigned short* __restrict__ AH,
                 const unsigned short* __restrict__ AL,
                 const unsigned short* __restrict__ WH,
                 const unsigned short* __restrict__ WL,
                 const float* __restrict__ bias,
                 unsigned short* __restrict__ OutH,
                 unsigned short* __restrict__ OutL,
                 const float* __restrict__ qn,
                 const float* __restrict__ kn)
{
  constexpr int BK = 32;
  constexpr int NT = kC / BK;   // 32 K-tiles

  // A: [buf][pl][256x32] = 64 KiB ; B: [buf][pl][192x32] = 48 KiB ; 112 total
  __shared__ __align__(16) unsigned short sA[2][2][256 * 32];
  __shared__ __align__(16) unsigned short sB[2][2][192 * 32];

  const int tt   = threadIdx.x;        // 0..511
  const int wave = tt >> 6;            // 0..7
  const int lane = tt & 63;
  const int quad = lane >> 4;
  const int l16  = lane & 15;
  const int bm = blockIdx.x * 256;
  const int bn = blockIdx.y * 192;
  const int wm = wave * 32;            // 8 waves stacked in M
  const bool wstg = (wave < 6);        // waves 0-5 stage W units

  // A staging: unit u = r*512 + tt; row = u>>2; swizzled col-group
  int srow[2], scol[2];
  #pragma unroll
  for (int r = 0; r < 2; ++r) {
    const int u = r * 512 + tt;
    srow[r] = u >> 2;
    scol[r] = ((u & 3) ^ ((srow[r] >> 1) & 3)) * 8;
  }
  // W staging: chunk c = r*384 + tt (tt<384); row = c>>2
  int wrow[2], wcol[2];
  #pragma unroll
  for (int r = 0; r < 2; ++r) {
    const int c = r * 384 + tt;
    wrow[r] = c >> 2;
    wcol[r] = ((c & 3) ^ ((wrow[r] >> 1) & 3)) * 8;
  }

  auto stageA = [&](int bf, int k0, int pl) {   // pl 0=hi 1=lo
    const unsigned short* src = pl ? AL : AH;
    #pragma unroll
    for (int r = 0; r < 2; ++r)
      glds16(&src[(size_t)(bm + srow[r]) * kC + k0 + scol[r]],
             &sA[bf][pl][(r * 512 + tt) * 8]);
  };
  auto stageW = [&](int bf, int k0, int pl) {
    if (!wstg) return;
    const unsigned short* src = pl ? WL : WH;
    #pragma unroll
    for (int r = 0; r < 2; ++r)
      glds16(&src[(size_t)(bn + wrow[r]) * kC + k0 + wcol[r]],
             &sB[bf][pl][(r * 384 + tt) * 8]);
  };

  auto rdA = [&](int bf, int pl, int row) -> bhalf8 {
    return *(const bhalf8*)(&sA[bf][pl][row * 32 + ((quad ^ ((row >> 1) & 3)) * 8)]);
  };
  auto rdB = [&](int bf, int pl, int row) -> bhalf8 {
    return *(const bhalf8*)(&sB[bf][pl][row * 32 + ((quad ^ ((row >> 1) & 3)) * 8)]);
  };

  f32x4 acc[2][12] = {};
  bhalf8 ah[2], al[2], b4[4];

  // ---- prologue: stage tile 0 (A: AH,WH order interleaved to match ledger) ----
  stageA(0, 0, 0);          // AH0 (2)
  stageW(0, 0, 0);          // WH0 (2, waves 0-5)
  stageW(0, 0, 1);          // WL0 (2, waves 0-5)
  stageA(0, 0, 1);          // AL0 (2)
  if (wstg) { asm volatile("s_waitcnt vmcnt(4)" ::: "memory"); }   // drain AH0,WH0
  else      { asm volatile("s_waitcnt vmcnt(2)" ::: "memory"); }   // drain AH0
  __builtin_amdgcn_sched_barrier(0);
  asm volatile("s_barrier" ::: "memory");

  for (int t = 0; t < NT - 1; ++t) {
    const int buf  = t & 1;
    const int nbuf = buf ^ 1;
    const int nk0  = (t + 1) * BK;

    // ---- P01: hh term ----
    ah[0] = rdA(buf, 0, wm + l16);
    ah[1] = rdA(buf, 0, wm + 16 + l16);
    stageA(nbuf, nk0, 0);                 // AH(t+1)
    stageW(nbuf, nk0, 0);                 // WH(t+1)
    if (wstg) asm volatile("s_waitcnt vmcnt(6)" ::: "memory");   // drain WL(t)
    __builtin_amdgcn_sched_barrier(0);
    asm volatile("s_barrier" ::: "memory");
    __builtin_amdgcn_s_setprio(1);
    #pragma unroll
    for (int jj = 0; jj < 3; ++jj) {
      #pragma unroll
      for (int j = 0; j < 4; ++j) b4[j] = rdB(buf, 0, jj * 64 + j * 16 + l16);
      #pragma unroll
      for (int i = 0; i < 2; ++i)
        #pragma unroll
        for (int j = 0; j < 4; ++j)
          acc[i][jj * 4 + j] = __builtin_amdgcn_mfma_f32_16x16x32_bf16(ah[i], b4[j], acc[i][jj * 4 + j], 0, 0, 0);
    }
    __builtin_amdgcn_s_setprio(0);

    // ---- P2: hl term ----
    stageW(nbuf, nk0, 1);                 // WL(t+1)
    if (wstg) asm volatile("s_waitcnt vmcnt(6)" ::: "memory");   // drain AL(t)
    __builtin_amdgcn_sched_barrier(0);
    asm volatile("s_barrier" ::: "memory");
    __builtin_amdgcn_s_setprio(1);
    #pragma unroll
    for (int jj = 0; jj < 3; ++jj) {
      #pragma unroll
      for (int j = 0; j < 4; ++j) b4[j] = rdB(buf, 1, jj * 64 + j * 16 + l16);
      #pragma unroll
      for (int i = 0; i < 2; ++i)
        #pragma unroll
        for (int j = 0; j < 4; ++j)
          acc[i][jj * 4 + j] = __builtin_amdgcn_mfma_f32_16x16x32_bf16(ah[i], b4[j], acc[i][jj * 4 + j], 0, 0, 0);
    }
    __builtin_amdgcn_s_setprio(0);

    // ---- P3: lh term ----
    stageA(nbuf, nk0, 1);                 // AL(t+1)
    if (wstg) { asm volatile("s_waitcnt vmcnt(4)" ::: "memory"); }  // drain AH,WH(t+1)
    else      { asm volatile("s_waitcnt vmcnt(2)" ::: "memory"); }  // drain AL(t)+AH(t+1)
    __builtin_amdgcn_sched_barrier(0);
    asm volatile("s_barrier" ::: "memory");
    __builtin_amdgcn_s_setprio(1);
    al[0] = rdA(buf, 1, wm + l16);
    al[1] = rdA(buf, 1, wm + 16 + l16);
    #pragma unroll
    for (int jj = 0; jj < 3; ++jj) {
      #pragma unroll
      for (int j = 0; j < 4; ++j) b4[j] = rdB(buf, 0, jj * 64 + j * 16 + l16);
      #pragma unroll
      for (int i = 0; i < 2; ++i)
        #pragma unroll
        for (int j = 0; j < 4; ++j)
          acc[i][jj * 4 + j] = __builtin_amdgcn_mfma_f32_16x16x32_bf16(al[i], b4[j], acc[i][jj * 4 + j], 0, 0, 0);
    }
    __builtin_amdgcn_s_setprio(0);
    asm volatile("s_barrier" ::: "memory");   // end-of-tile lockstep
  }

  // ---- peeled last tile (no prefetch) ----
  {
    const int buf = (NT - 1) & 1;
    ah[0] = rdA(buf, 0, wm + l16);
    ah[1] = rdA(buf, 0, wm + 16 + l16);
    __builtin_amdgcn_s_setprio(1);
    #pragma unroll
    for (int jj = 0; jj < 3; ++jj) {
      #pragma unroll
      for (int j = 0; j < 4; ++j) b4[j] = rdB(buf, 0, jj * 64 + j * 16 + l16);
      #pragma unroll
      for (int i = 0; i < 2; ++i)
        #pragma unroll
        for (int j = 0; j < 4; ++j)
          acc[i][jj * 4 + j] = __builtin_amdgcn_mfma_f32_16x16x32_bf16(ah[i], b4[j], acc[i][jj * 4 + j], 0, 0, 0);
    }
    __builtin_amdgcn_s_setprio(0);

    if (wstg) asm volatile("s_waitcnt vmcnt(2)" ::: "memory");   // drain WL(last)
    __builtin_amdgcn_sched_barrier(0);
    asm volatile("s_barrier" ::: "memory");
    __builtin_amdgcn_s_setprio(1);
    #pragma unroll
    for (int jj = 0; jj < 3; ++jj) {
      #pragma unroll
      for (int j = 0; j < 4; ++j) b4[j] = rdB(buf, 1, jj * 64 + j * 16 + l16);
      #pragma unroll
      for (int i = 0; i < 2; ++i)
        #pragma unroll
        for (int j = 0; j < 4; ++j)
          acc[i][jj * 4 + j] = __builtin_amdgcn_mfma_f32_16x16x32_bf16(ah[i], b4[j], acc[i][jj * 4 + j], 0, 0, 0);
    }
    __builtin_amdgcn_s_setprio(0);

    asm volatile("s_waitcnt vmcnt(0)" ::: "memory");   // drain AL(last), both groups
    __builtin_amdgcn_sched_barrier(0);
    asm volatile("s_barrier" ::: "memory");
    __builtin_amdgcn_s_setprio(1);
    al[0] = rdA(buf, 1, wm + l16);
    al[1] = rdA(buf, 1, wm + 16 + l16);
    #pragma unroll
    for (int jj = 0; jj < 3; ++jj) {
      #pragma unroll
      for (int j = 0; j < 4; ++j) b4[j] = rdB(buf, 0, jj * 64 + j * 16 + l16);
      #pragma unroll
      for (int i = 0; i < 2; ++i)
        #pragma unroll
        for (int j = 0; j < 4; ++j)
          acc[i][jj * 4 + j] = __builtin_amdgcn_mfma_f32_16x16x32_bf16(al[i], b4[j], acc[i][jj * 4 + j], 0, 0, 0);
    }
    __builtin_amdgcn_s_setprio(0);
  }

  // epilogue: per-head (jj) slice logic; C/D layout col=lane&15, row=quad*4+r
  #pragma unroll
  for (int i = 0; i < 2; ++i) {
    #pragma unroll
    for (int jj = 0; jj < 3; ++jj) {
      const int n0 = bn + jj * 64;       // head-aligned; heads never cross slices
      const int slice = n0 >> 10;        // 0=q,1=k,2=v
      const bool writeL = (slice == 0);
      float val[4][4], wv[4];
      #pragma unroll
      for (int u = 0; u < 4; ++u) {
        const float bv = bias[n0 + u * 16 + l16];
        #pragma unroll
        for (int r = 0; r < 4; ++r) val[u][r] = acc[i][jj * 4 + u][r] + bv;
        if (slice < 2) wv[u] = (slice ? kn : qn)[u * 16 + l16];  // d = u*16+l16
      }

      if (slice < 2) {
        #pragma unroll
        for (int r = 0; r < 4; ++r) {
          float ss = val[0][r] * val[0][r];
          #pragma unroll
          for (int u = 1; u < 4; ++u) ss += val[u][r] * val[u][r];
          #pragma unroll
          for (int d = 1; d < 16; d <<= 1) ss += __shfl_xor(ss, d, 64);
          float rinv = rsqrtf(ss * (1.0f / 64.0f) + 1e-6f);
          // q * D^-0.5 * log2(e): attn uses hardware 2^x
          if (slice == 0) rinv *= 0.18033688011112042f;
          #pragma unroll
          for (int u = 0; u < 4; ++u) val[u][r] = wv[u] * (val[u][r] * rinv);
        }
      }

      #pragma unroll
      for (int u = 0; u < 4; ++u) {
        const int n = n0 + u * 16 + l16;
        #pragma unroll
        for (int r = 0; r < 4; ++r) {
          const int m = bm + wm + i * 16 + quad * 4 + r;
          unsigned short hh, ll;
          split2(val[u][r], hh, ll);
          OutH[(size_t)m * k3C + n] = hh;
          if (writeL) OutL[(size_t)m * k3C + n] = ll;
        }
      }
    }
  }
}

// ============================================================================
// PROJ GEMM, 128x128 tile, 4 waves (2x2), BK=32 — term-split 3-phase schedule
// (verified round 9). A stride = k3C (q-slice), fp32 out + bias.
// ============================================================================
__global__ __launch_bounds__(256)
void gemm_proj128(const unsigned short* __restrict__ AH,
                  const unsigned short* __restrict__ AL,
                  const unsigned short* __restrict__ WH,
                  const unsigned short* __restrict__ WL,
                  const float* __restrict__ bias,
                  float* __restrict__ Out)
{
  constexpr int BK = 32;
  constexpr int NT = kC / BK;   // 32 K-tiles

  __shared__ __align__(16) unsigned short sA[2][2][128 * 32];
  __shared__ __align__(16) unsigned short sB[2][2][128 * 32];

  const int tt   = threadIdx.x;        // 0..255
  const int wave = tt >> 6;            // 0..3
  const int lane = tt & 63;
  const int quad = lane >> 4;
  const int l16  = lane & 15;
  const int bm = blockIdx.x * 128;
  const int bn = blockIdx.y * 128;
  const int wm = (wave >> 1) * 64;     // wave row: 0/64
  const int wn = (wave & 1) * 64;      // wave col: 0/64

  int srow[2], scol[2];
  #pragma unroll
  for (int r = 0; r < 2; ++r) {
    const int c = r * 256 + tt;
    srow[r] = c >> 2;
    scol[r] = ((c & 3) ^ ((srow[r] >> 1) & 3)) * 8;
  }

  // unit: 0=AH 1=WH 2=WL 3=AL (issue order!); A stride k3C, W stride kC
  auto stageU = [&](int bf, int k0, int which) {
    const unsigned short* src = (which == 0) ? AH : (which == 1) ? WH
                              : (which == 2) ? WL : AL;
    const bool isA = (which == 0 || which == 3);
    const int base = isA ? bm : bn;
    const int ld   = isA ? k3C : kC;
    unsigned short* dst = (which == 0) ? &sA[bf][0][0]
                        : (which == 3) ? &sA[bf][1][0]
                        : (which == 1) ? &sB[bf][0][0] : &sB[bf][1][0];
    #pragma unroll
    for (int r = 0; r < 2; ++r)
      glds16(&src[(size_t)(base + srow[r]) * ld + k0 + scol[r]],
             &dst[(r * 256 + tt) * 8]);
  };

  auto rdA = [&](int bf, int pl, int row) -> bhalf8 {
    return *(const bhalf8*)(&sA[bf][pl][row * 32 + ((quad ^ ((row >> 1) & 3)) * 8)]);
  };
  auto rdB = [&](int bf, int pl, int row) -> bhalf8 {
    return *(const bhalf8*)(&sB[bf][pl][row * 32 + ((quad ^ ((row >> 1) & 3)) * 8)]);
  };

  f32x4 acc[4][4] = {};
  bhalf8 ah[4], bh_[4], bl_[4];

  stageU(0, 0, 0); stageU(0, 0, 1); stageU(0, 0, 2); stageU(0, 0, 3);
  asm volatile("s_waitcnt vmcnt(4)" ::: "memory");
  __builtin_amdgcn_sched_barrier(0);
  asm volatile("s_barrier" ::: "memory");

  for (int t = 0; t < NT - 1; ++t) {
    const int buf  = t & 1;
    const int nbuf = buf ^ 1;
    const int nk0  = (t + 1) * BK;

    // ---- P01: hh ----
    #pragma unroll
    for (int i = 0; i < 4; ++i) ah[i]  = rdA(buf, 0, wm + i * 16 + l16);
    #pragma unroll
    for (int j = 0; j < 4; ++j) bh_[j] = rdB(buf, 0, wn + j * 16 + l16);
    stageU(nbuf, nk0, 0);
    stageU(nbuf, nk0, 1);
    asm volatile("s_waitcnt vmcnt(6)" ::: "memory");
    __builtin_amdgcn_sched_barrier(0);
    asm volatile("s_barrier" ::: "memory");
    __builtin_amdgcn_s_setprio(1);
    #pragma unroll
    for (int i = 0; i < 4; ++i)
      #pragma unroll
      for (int j = 0; j < 4; ++j)
        acc[i][j] = __builtin_amdgcn_mfma_f32_16x16x32_bf16(ah[i], bh_[j], acc[i][j], 0, 0, 0);
    __builtin_amdgcn_s_setprio(0);

    // ---- P2: hl ----
    #pragma unroll
    for (int j = 0; j < 4; ++j) bl_[j] = rdB(buf, 1, wn + j * 16 + l16);
    stageU(nbuf, nk0, 2);
    asm volatile("s_waitcnt vmcnt(6)" ::: "memory");
    __builtin_amdgcn_sched_barrier(0);
    asm volatile("s_barrier" ::: "memory");
    __builtin_amdgcn_s_setprio(1);
    #pragma unroll
    for (int i = 0; i < 4; ++i)
      #pragma unroll
      for (int j = 0; j < 4; ++j)
        acc[i][j] = __builtin_amdgcn_mfma_f32_16x16x32_bf16(ah[i], bl_[j], acc[i][j], 0, 0, 0);
    __builtin_amdgcn_s_setprio(0);

    // ---- P3: lh ----
    stageU(nbuf, nk0, 3);
    asm volatile("s_waitcnt vmcnt(4)" ::: "memory");
    __builtin_amdgcn_sched_barrier(0);
    asm volatile("s_barrier" ::: "memory");
    __builtin_amdgcn_s_setprio(1);
    {
      bhalf8 al0[4];
      #pragma unroll
      for (int i = 0; i < 4; ++i) al0[i] = rdA(buf, 1, wm + i * 16 + l16);
      #pragma unroll
      for (int i = 0; i < 4; ++i)
        #pragma unroll
        for (int j = 0; j < 4; ++j)
          acc[i][j] = __builtin_amdgcn_mfma_f32_16x16x32_bf16(al0[i], bh_[j], acc[i][j], 0, 0, 0);
    }
    __builtin_amdgcn_s_setprio(0);
    asm volatile("s_barrier" ::: "memory");
  }

  {
    const int buf = (NT - 1) & 1;
    #pragma unroll
    for (int i = 0; i < 4; ++i) ah[i]  = rdA(buf, 0, wm + i * 16 + l16);
    #pragma unroll
    for (int j = 0; j < 4; ++j) bh_[j] = rdB(buf, 0, wn + j * 16 + l16);
    __builtin_amdgcn_s_setprio(1);
    #pragma unroll
    for (int i = 0; i < 4; ++i)
      #pragma unroll
      for (int j = 0; j < 4; ++j)
        acc[i][j] = __builtin_amdgcn_mfma_f32_16x16x32_bf16(ah[i], bh_[j], acc[i][j], 0, 0, 0);
    __builtin_amdgcn_s_setprio(0);

    asm volatile("s_waitcnt vmcnt(2)" ::: "memory");
    __builtin_amdgcn_sched_barrier(0);
    asm volatile("s_barrier" ::: "memory");
    #pragma unroll
    for (int j = 0; j < 4; ++j) bl_[j] = rdB(buf, 1, wn + j * 16 + l16);
    __builtin_amdgcn_s_setprio(1);
    #pragma unroll
    for (int i = 0; i < 4; ++i)
      #pragma unroll
      for (int j = 0; j < 4; ++j)
        acc[i][j] = __builtin_amdgcn_mfma_f32_16x16x32_bf16(ah[i], bl_[j], acc[i][j], 0, 0, 0);
    __builtin_amdgcn_s_setprio(0);

    asm volatile("s_waitcnt vmcnt(0)" ::: "memory");
    __builtin_amdgcn_sched_barrier(0);
    asm volatile("s_barrier" ::: "memory");
    __builtin_amdgcn_s_setprio(1);
    {
      bhalf8 al0[4];
      #pragma unroll
      for (int i = 0; i < 4; ++i) al0[i] = rdA(buf, 1, wm + i * 16 + l16);
      #pragma unroll
      for (int i = 0; i < 4; ++i)
        #pragma unroll
        for (int j = 0; j < 4; ++j)
          acc[i][j] = __builtin_amdgcn_mfma_f32_16x16x32_bf16(al0[i], bh_[j], acc[i][j], 0, 0, 0);
    }
    __builtin_amdgcn_s_setprio(0);
  }

  float bv[4];
  #pragma unroll
  for (int j = 0; j < 4; ++j) bv[j] = bias[bn + wn + j * 16 + l16];

  #pragma unroll
  for (int i = 0; i < 4; ++i)
    #pragma unroll
    for (int j = 0; j < 4; ++j) {
      const int n = bn + wn + j * 16 + l16;
      #pragma unroll
      for (int r = 0; r < 4; ++r) {
        const int m = bm + wm + i * 16 + quad * 4 + r;
        Out[(size_t)m * kC + n] = acc[i][j][r] + bv[j];
      }
    }
}

// ---- flash attention v11 (verified round 7): dbuf K/V, one barrier/iter,
// Pt pitch 68, hardware v_exp_f32 via builtin. ----
__global__ __launch_bounds__(256)
void attn_kernel(unsigned short* __restrict__ H, unsigned short* __restrict__ L,
                 const unsigned short* __restrict__ VTH,
                 const int* __restrict__ mask)
{
  constexpr int P   = 72;  // K/V pitch: bank-start 4*((row+col16)%8) — balanced
  constexpr int Ppt = 68;  // Pt pitch: quad groups land on distinct banks
  __shared__ __align__(16) unsigned short KtH[2][64 * P];   // 18.4 KB dbuf
  __shared__ __align__(16) unsigned short VtH[2][64 * P];   // 18.4 KB dbuf
  __shared__ __align__(16) unsigned short Pt[4][32 * Ppt];  // 17.4 KB per-wave

  const int t    = threadIdx.x;
  const int wave = t >> 6;
  const int lane = t & 63;
  const int quad = lane >> 4;
  const int l16  = lane & 15;

  // XCD swizzle: lin%8 = XCD (dispatch round-robin); 4 bh per XCD.
  const int lin  = blockIdx.x;          // 0..511
  const int xcd  = lin & 7;
  const int slot = lin >> 3;            // 0..63
  const int bh   = xcd + 8 * (slot >> 4);
  const int qblk = slot & 15;
  const int b  = bh >> 4;
  const int h  = bh & 15;
  const int q0 = qblk * 128 + wave * 32;  // 32 q-rows/wave

  // staging geometry: 2 chunks of 8 u16 per thread per tile
  const int row0 = t >> 3,         col0 = (t & 7) * 8;
  const int row1 = (256 + t) >> 3, col1 = ((256 + t) & 7) * 8;

  // Q fragments, both groups (A-layout: m=l16, k=quad*8+j)
  bhalf8 qfh[2][2], qfl[2][2];
  #pragma unroll
  for (int g = 0; g < 2; ++g) {
    const size_t qrow = (size_t)(b * kN + q0 + g * 16 + l16) * k3C + h * kD;
    qfh[g][0] = *(const bhalf8*)(&H[qrow + quad * 8]);
    qfh[g][1] = *(const bhalf8*)(&H[qrow + 32 + quad * 8]);
    qfl[g][0] = *(const bhalf8*)(&L[qrow + quad * 8]);
    qfl[g][1] = *(const bhalf8*)(&L[qrow + 32 + quad * 8]);
  }

  f32x4 acc_o[2][4] = {};
  float lpart[2][4] = {};

  uint4 sk0, sk1, sv0, sv1;            // staging regs
  int mcur[4], mnext[4];

  auto pref = [&](int kt) {
    sk0 = *(const uint4*)(&H[(size_t)(b * kN + kt + row0) * k3C + kC + h * kD + col0]);
    sk1 = *(const uint4*)(&H[(size_t)(b * kN + kt + row1) * k3C + kC + h * kD + col1]);
    sv0 = *(const uint4*)(&VTH[((size_t)bh * kD + row0) * kN + kt + col0]);
    sv1 = *(const uint4*)(&VTH[((size_t)bh * kD + row1) * kN + kt + col1]);
  };
  auto store_tile = [&](int bf) {
    *(uint4*)(&KtH[bf][row0 * P + col0]) = sk0;
    *(uint4*)(&KtH[bf][row1 * P + col1]) = sk1;
    *(uint4*)(&VtH[bf][row0 * P + col0]) = sv0;
    *(uint4*)(&VtH[bf][row1 * P + col1]) = sv1;
  };
  auto loadM = [&](int kt, int* m) {
    #pragma unroll
    for (int nt = 0; nt < 4; ++nt) m[nt] = mask[b * kN + kt + nt * 16 + l16];
  };

  // prologue: tile 0 -> buf0; issue tile 1 loads; one barrier
  pref(0);
  loadM(0, mcur);
  #pragma unroll
  for (int nt = 0; nt < 4; ++nt) mnext[nt] = mcur[nt];
  store_tile(0);                       // compiler inserts vmcnt for sk/sv deps
  pref(64);                            // tile 1 in flight across the barrier
  __syncthreads();

  for (int i = 0; i < 32; ++i) {
    const int cur = i & 1;
    const int kt = i * 64;
    if (i < 31) loadM(kt + 64, mnext);

    // S = (Qh+Ql)Kh ; p = flag*2^s -> Pt (C-layout -> A-layout)
    #pragma unroll
    for (int nt = 0; nt < 4; ++nt) {
      const int kr = (nt * 16 + l16) * P + quad * 8;
      const bhalf8 kh0 = *(const bhalf8*)(&KtH[cur][kr]);
      const bhalf8 kh1 = *(const bhalf8*)(&KtH[cur][kr + 32]);
      const float flag = mcur[nt] ? 1.0f : 0.0f;
      #pragma unroll
      for (int g = 0; g < 2; ++g) {
        f32x4 s = {};
        s = __builtin_amdgcn_mfma_f32_16x16x32_bf16(qfh[g][0], kh0, s, 0, 0, 0);
        s = __builtin_amdgcn_mfma_f32_16x16x32_bf16(qfh[g][1], kh1, s, 0, 0, 0);
        s = __builtin_amdgcn_mfma_f32_16x16x32_bf16(qfl[g][0], kh0, s, 0, 0, 0);
        s = __builtin_amdgcn_mfma_f32_16x16x32_bf16(qfl[g][1], kh1, s, 0, 0, 0);
        #pragma unroll
        for (int r = 0; r < 4; ++r) {
          const float p = flag * fexp2(s[r]);   // s pre-scaled by log2e
          lpart[g][r] += p;
          Pt[wave][(g * 16 + quad * 4 + r) * Ppt + nt * 16 + l16] = f2bf(p);
        }
      }
    }

    // O += P * Vh  (Pt per-wave: same-wave DS ordering, no barrier needed)
    #pragma unroll
    for (int kk = 0; kk < 2; ++kk) {
      const bhalf8 pa0 = *(const bhalf8*)(&Pt[wave][l16 * Ppt + kk * 32 + quad * 8]);
      const bhalf8 pa1 = *(const bhalf8*)(&Pt[wave][(16 + l16) * Ppt + kk * 32 + quad * 8]);
      #pragma unroll
      for (int dt = 0; dt < 4; ++dt) {
        const bhalf8 vb = *(const bhalf8*)(&VtH[cur][(dt * 16 + l16) * P + kk * 32 + quad * 8]);
        acc_o[0][dt] = __builtin_amdgcn_mfma_f32_16x16x32_bf16(pa0, vb, acc_o[0][dt], 0, 0, 0);
        acc_o[1][dt] = __builtin_amdgcn_mfma_f32_16x16x32_bf16(pa1, vb, acc_o[1][dt], 0, 0, 0);
      }
    }

    if (i < 31) {
      store_tile(cur ^ 1);             // tile i+1 into the other buffer
      if (i < 30) pref(kt + 128);      // tile i+2 in flight across barrier
      __syncthreads();                 // single barrier per iteration
      #pragma unroll
      for (int nt = 0; nt < 4; ++nt) mcur[nt] = mnext[nt];
    }
  }

  // final l reduction + normalize + store hi/lo into q-slice
  #pragma unroll
  for (int g = 0; g < 2; ++g)
    #pragma unroll
    for (int r = 0; r < 4; ++r) {
      float s = lpart[g][r];
      #pragma unroll
      for (int d = 1; d < 16; d <<= 1) s += __shfl_xor(s, d, 64);
      lpart[g][r] = s;
    }
  #pragma unroll
  for (int g = 0; g < 2; ++g)
    #pragma unroll
    for (int dt = 0; dt < 4; ++dt)
      #pragma unroll
      for (int r = 0; r < 4; ++r) {
        const int qrow = q0 + g * 16 + quad * 4 + r;
        const float inv = 1.0f / fmaxf(lpart[g][r], 1.0e-30f);
        const size_t off = (size_t)(b * kN + qrow) * k3C + h * kD + dt * 16 + l16;
        unsigned short hh, ll;
        split2(acc_o[g][dt][r] * inv, hh, ll);
        H[off] = hh; L[off] = ll;
      }
}

} // anonymous namespace

extern "C" void kernel_launch(void* const* d_in, const int* in_sizes, int n_in,
                              void* d_out, int out_size, void* d_ws, size_t ws_size,
                              hipStream_t stream)
{
  const float* x      = (const float*)d_in[0];
  const int*   maskp  = (const int*)d_in[1];
  const float* qkv_w  = (const float*)d_in[2];
  const float* qkv_b  = (const float*)d_in[3];
  const float* proj_w = (const float*)d_in[4];
  const float* proj_b = (const float*)d_in[5];
  const float* qn_w   = (const float*)d_in[6];
  const float* kn_w   = (const float*)d_in[7];
  float* out = (float*)d_out;

  unsigned short* qH = (unsigned short*)d_ws;      // qkv hi plane
  unsigned short* qL = qH + kPS;                   // qkv lo plane
  unsigned short* R1 = qL + kPS;                   // x planes -> later VT plane
  unsigned short* R2 = R1 + 2 * kXE;               // qkv_w planes -> later proj_w planes
  unsigned short* xH = R1,  *xL = R1 + kXE;
  unsigned short* VTH = R1;                        // reuse after gemm1
  unsigned short* wqH = R2, *wqL = R2 + kWQ;
  unsigned short* wpH = R2, *wpL = R2 + kWP;

  // 1) fused prep: split x + qkv_w (one launch; 4096 + 3072 blocks)
  prep_split<<<(int)((kXE + kWQ) / 4 / 256), 256, 0, stream>>>(
      x, qkv_w, xH, xL, wqH, wqL);

  // 2) qkv = x @ qkv_w^T + qkv_b, RMSNorm(q,k) fused; grid 16x16 = 256 blocks
  gemm_qkv256<<<dim3(kTok / 256, k3C / 192), 512, 0, stream>>>(
      xH, xL, wqH, wqL, qkv_b, qH, qL, qn_w, kn_w);

  // 3) fused: V^T pre-transpose (2048 blocks) + proj_w split (1024 blocks)
  vt_and_split<<<3072, 256, 0, stream>>>(qH, VTH, proj_w, wpH, wpL);

  // 4) masked flash attention (XCD-swizzled 1-D grid, 512 blocks)
  attn_kernel<<<dim3(512), 256, 0, stream>>>(qH, qL, VTH, maskp);

  // 5) out = attn @ proj_w^T + proj_b  (term-split 3-phase, grid 32x8=256)
  gemm_proj128<<<dim3(kTok / 128, kC / 128), 256, 0, stream>>>(
      qH, qL, wpH, wpL, proj_b, out);
}